// Round 10
// baseline (3239.320 us; speedup 1.0000x reference)
//
#include <hip/hip_runtime.h>
#include <hip/hip_bf16.h>
#include <math.h>

#define N_NODES 2000
#define N_EDGES 32000
#define H 300
#define CH 75             // H/4 float4 chunks per row
#define HP 320            // padded H for MFMA K/N
#define NLAYERS 30
#define NH (N_NODES * H)     // 600000
#define NODE_ROWS_PAD 2048
#define WMAT (HP * HP)
#define NREP 32              // stat replicas
#define RSTRIDE 608          // replica row stride (sum | sumsq at +304)
#define SSTRIDE 304
#define NEB 500              // edge-finalize blocks (32000/64)
#define NUB 147              // node_update blocks (1024 chunks each)
#define NMB 1000             // node_msg gather blocks (2 nodes each)

typedef short bf16x8 __attribute__((ext_vector_type(8)));
typedef float f32x4 __attribute__((ext_vector_type(4)));
typedef __hip_bfloat16 bf16;

__device__ __forceinline__ float sigm(float x) { return 1.f / (1.f + __expf(-x)); }

// ---------------------------------------------------------------- utilities
__global__ __launch_bounds__(256) void zero_buf(float* __restrict__ p, int n) {
    int i = blockIdx.x * blockDim.x + threadIdx.x;
    if (i < n) p[i] = 0.f;
}

// --------------------- weights -> bf16 transposed, LDS-tiled (coalesced both ways)
__global__ __launch_bounds__(256) void convert_weights_t(const float* __restrict__ eU,
                                                         const float* __restrict__ eW,
                                                         const float* __restrict__ nU,
                                                         const float* __restrict__ nV,
                                                         bf16* __restrict__ Wt) {
    __shared__ float tile[32][33];
    int b = blockIdx.x;                 // 120 mats x 100 tiles
    int m = b / 100;
    int rem = b % 100;
    int kt = rem / 10, nt = rem % 10;
    int k0 = kt * 32, n0 = nt * 32;
    int grp = m / NLAYERS, l = m % NLAYERS;
    const float* S = (grp == 0) ? eU : (grp == 1) ? eW : (grp == 2) ? nU : nV;
    const float* Sl = S + (size_t)l * H * H;
    int t = threadIdx.x;
    int tn = t & 31, tk = t >> 5;
#pragma unroll
    for (int p = 0; p < 4; ++p) {
        int k = tk + p * 8;
        int gk = k0 + k, gn = n0 + tn;
        tile[k][tn] = (gk < H && gn < H) ? Sl[(size_t)gk * H + gn] : 0.f;
    }
    __syncthreads();
    bf16* D = Wt + (size_t)m * WMAT;
    int tk2 = t & 31, tn2 = t >> 5;
#pragma unroll
    for (int p = 0; p < 4; ++p) {
        int n = tn2 + p * 8;
        D[(size_t)(n0 + n) * HP + k0 + tk2] = __float2bfloat16(tile[tk2][n]);
    }
}

// ------------------------------------------------------------- CSR by dst
__global__ __launch_bounds__(256) void csr_hist(const int* __restrict__ dst,
                                                int* __restrict__ counts) {
    int i = blockIdx.x * 256 + threadIdx.x;
    if (i < N_EDGES) atomicAdd(&counts[dst[i]], 1);
}

__global__ __launch_bounds__(256) void csr_scan(const int* __restrict__ counts,
                                                int* __restrict__ offs,
                                                int* __restrict__ woff) {
    __shared__ int part[256];
    int t = threadIdx.x;
    int base = t * 8;
    int local[8];
    int s = 0;
#pragma unroll
    for (int j = 0; j < 8; ++j) {
        int c = (base + j < N_NODES) ? counts[base + j] : 0;
        local[j] = s;
        s += c;
    }
    part[t] = s;
    __syncthreads();
    for (int off = 1; off < 256; off <<= 1) {
        int v = (t >= off) ? part[t - off] : 0;
        __syncthreads();
        part[t] += v;
        __syncthreads();
    }
    int pre = (t == 0) ? 0 : part[t - 1];
#pragma unroll
    for (int j = 0; j < 8; ++j) {
        int idx = base + j;
        if (idx < N_NODES) { int v = pre + local[j]; offs[idx] = v; woff[idx] = v; }
    }
    if (t == 255) offs[N_NODES] = part[255];
}

__global__ __launch_bounds__(256) void csr_scatter(const int* __restrict__ src,
                                                   const int* __restrict__ dst,
                                                   int* __restrict__ woff,
                                                   int* __restrict__ eidx,
                                                   int* __restrict__ msrc) {
    int i = blockIdx.x * 256 + threadIdx.x;
    if (i < N_EDGES) {
        int p = atomicAdd(&woff[dst[i]], 1);
        eidx[p] = i;
        msrc[p] = src[i];
    }
}

// ---------------------------------------------------------------- embeddings
__global__ __launch_bounds__(256) void node_embed(const float* __restrict__ x,
                                                  const float* __restrict__ W,
                                                  const float* __restrict__ b,
                                                  float* __restrict__ node,
                                                  bf16* __restrict__ node_bf) {
    int i = blockIdx.x * blockDim.x + threadIdx.x;
    if (i >= NH) return;
    int n = i / H, h = i % H;
    float acc = b[h];
#pragma unroll
    for (int k = 0; k < 4; ++k) acc += x[n * 4 + k] * W[k * H + h];
    node[i] = acc;
    node_bf[(size_t)n * HP + h] = __float2bfloat16(acc);
}

// edge embedding, bf16 only, col-chunk ownership; sigmoid colsum -> RS0
__global__ __launch_bounds__(256) void edge_embed(const float* __restrict__ ea,
                                                  const float* __restrict__ dW,
                                                  const float* __restrict__ db,
                                                  const float* __restrict__ tW,
                                                  const float* __restrict__ tb,
                                                  bf16* __restrict__ edge_bf,
                                                  float* __restrict__ RS0) {
    __shared__ float s_s[SSTRIDE];
    int t = threadIdx.x;
    for (int i = t; i < SSTRIDE; i += 256) s_s[i] = 0.f;
    __syncthreads();
    int hc = t % 80, rgrp = t / 80;
    int col0 = hc * 4;
    float ss[4] = {0.f, 0.f, 0.f, 0.f};
    if (hc < CH && rgrp < 3) {
        float wv[4], bv[4];
#pragma unroll
        for (int j = 0; j < 4; ++j) {
            int col = col0 + j;
            wv[j] = (col < 150) ? dW[col] : tW[col - 150];
            bv[j] = (col < 150) ? db[col] : tb[col - 150];
        }
        int e0 = blockIdx.x * 64;
        for (int r = rgrp; r < 64; r += 3) {
            int e = e0 + r;
            float d = ea[2 * e], tt = ea[2 * e + 1];
            union { ushort4 u; bf16 b[4]; } ob;
#pragma unroll
            for (int j = 0; j < 4; ++j) {
                int col = col0 + j;
                float v = ((col < 150) ? d : tt) * wv[j] + bv[j];
                ob.b[j] = __float2bfloat16(v);
                ss[j] += sigm(__bfloat162float(ob.b[j]));
            }
            *(ushort4*)(edge_bf + (size_t)e * HP + col0) = ob.u;
        }
#pragma unroll
        for (int j = 0; j < 4; ++j) atomicAdd(&s_s[col0 + j], ss[j]);
    }
    __syncthreads();
    float* rs = RS0 + (size_t)(blockIdx.x & (NREP - 1)) * SSTRIDE;
    for (int i = t; i < H; i += 256) atomicAdd(&rs[i], s_s[i]);
}

// ---- K1: node GEMMs (1500 one-wave blocks) + 5 blocks: invS from RScur, zero RSnxt
__global__ __launch_bounds__(64) void gemm_node(const bf16* __restrict__ node_bf,
                                                const bf16* __restrict__ Wt_all,
                                                const float* __restrict__ eU_b,
                                                const float* __restrict__ nV_b,
                                                const float* __restrict__ nU_b,
                                                int layer,
                                                float* __restrict__ nodeU,
                                                float* __restrict__ nodeV,
                                                float* __restrict__ nodeUn,
                                                const float* __restrict__ RScur,
                                                float* __restrict__ RSnxt,
                                                float* __restrict__ invS) {
    int bx = blockIdx.x;
    int lane = threadIdx.x;
    if (bx >= 1500) {
        int idx = bx - 1500;               // 0..4
        int c = idx * 64 + lane;           // 0..319
        if (c < H) {
            float ssr = 0.f;
#pragma unroll 8
            for (int r = 0; r < NREP; ++r) ssr += RScur[r * SSTRIDE + c];
            invS[c] = 1.f / (ssr + 1e-20f);
        }
        for (int i = idx * 64 + lane; i < NREP * SSTRIDE; i += 320) RSnxt[i] = 0.f;
        return;
    }
    int mat = bx / 500;
    int rem = bx % 500;
    int rt0 = rem >> 2, ct4 = rem & 3;
    const bf16* Bt; const float* bias; float* out;
    if (mat == 0)      { Bt = Wt_all + (size_t)(0 + layer) * WMAT;  bias = eU_b + layer * H; out = nodeU; }
    else if (mat == 1) { Bt = Wt_all + (size_t)(90 + layer) * WMAT; bias = nV_b + layer * H; out = nodeV; }
    else               { Bt = Wt_all + (size_t)(60 + layer) * WMAT; bias = nU_b + layer * H; out = nodeUn; }
    int row0 = rt0 * 16, c0 = ct4 * 80;
    int rlo = lane & 15, khi = lane >> 4;
    f32x4 acc[5];
#pragma unroll
    for (int ct = 0; ct < 5; ++ct) acc[ct] = (f32x4)0.f;
#pragma unroll 2
    for (int ks = 0; ks < 10; ++ks) {
        int kk = ks * 32 + khi * 8;
        bf16x8 a, b[5];
        a = *(const bf16x8*)(node_bf + (size_t)(row0 + rlo) * HP + kk);
#pragma unroll
        for (int ct = 0; ct < 5; ++ct)
            b[ct] = *(const bf16x8*)(Bt + (size_t)(c0 + ct * 16 + rlo) * HP + kk);
#pragma unroll
        for (int ct = 0; ct < 5; ++ct)
            acc[ct] = __builtin_amdgcn_mfma_f32_16x16x32_bf16(a, b[ct], acc[ct], 0, 0, 0);
    }
    int rhi = lane >> 4;
#pragma unroll
    for (int ct = 0; ct < 5; ++ct) {
        int col = c0 + ct * 16 + rlo;
        if (col >= H) continue;
        float bv = bias[col];
#pragma unroll
        for (int j = 0; j < 4; ++j) {
            int r = row0 + rhi * 4 + j;
            out[(size_t)r * H + col] = acc[ct][j] + bv;
        }
    }
}

// ------ K2: PURE edge gate GEMM, 2000 one-wave blocks, 32r x 160c, no LDS
__global__ __launch_bounds__(64) void gemm_edge(const bf16* __restrict__ edge_bf,
                                                const bf16* __restrict__ Bt,
                                                bf16* __restrict__ gate_bf) {
    int bx = blockIdx.x;               // 0..1999
    int lane = threadIdx.x;
    int row0 = (bx >> 1) * 32;
    int c0 = (bx & 1) * 160;
    int rlo = lane & 15, khi = lane >> 4;
    f32x4 acc[2][10];
#pragma unroll
    for (int rt = 0; rt < 2; ++rt)
#pragma unroll
        for (int ct = 0; ct < 10; ++ct) acc[rt][ct] = (f32x4)0.f;
#pragma unroll 2
    for (int ks = 0; ks < 10; ++ks) {
        int kk = ks * 32 + khi * 8;
        bf16x8 a[2], b[10];
#pragma unroll
        for (int rt = 0; rt < 2; ++rt)
            a[rt] = *(const bf16x8*)(edge_bf + (size_t)(row0 + rt * 16 + rlo) * HP + kk);
#pragma unroll
        for (int ct = 0; ct < 10; ++ct)
            b[ct] = *(const bf16x8*)(Bt + (size_t)(c0 + ct * 16 + rlo) * HP + kk);
#pragma unroll
        for (int rt = 0; rt < 2; ++rt)
#pragma unroll
            for (int ct = 0; ct < 10; ++ct)
                acc[rt][ct] = __builtin_amdgcn_mfma_f32_16x16x32_bf16(a[rt], b[ct], acc[rt][ct], 0, 0, 0);
    }
    int rhi = lane >> 4;
#pragma unroll
    for (int rt = 0; rt < 2; ++rt)
#pragma unroll
        for (int ct = 0; ct < 10; ++ct) {
            int col = c0 + ct * 16 + rlo;
            if (col >= H) continue;
#pragma unroll
            for (int j = 0; j < 4; ++j) {
                int r = row0 + rt * 16 + rhi * 4 + j;
                gate_bf[(size_t)r * H + col] = __float2bfloat16(acc[rt][ct][j]);
            }
        }
}

// ---- K3: CSR gather (bx<NMB, 2 nodes/block) || gate-finish+stats (bx>=NMB)
__global__ __launch_bounds__(320) void node_msg(const bf16* __restrict__ edge_bf,
                                                const float* __restrict__ nodeV,
                                                const float* __restrict__ nodeUn,
                                                const int* __restrict__ offs,
                                                const int* __restrict__ eidx,
                                                const int* __restrict__ msrc,
                                                const float* __restrict__ invS,
                                                float* __restrict__ RN,
                                                float* __restrict__ aggv,
                                                bf16* __restrict__ gate_bf,
                                                const float* __restrict__ nodeU,
                                                const int* __restrict__ src,
                                                const int* __restrict__ dst,
                                                float* __restrict__ REc) {
    __shared__ float s1[SSTRIDE], s2[SSTRIDE];
    int t = threadIdx.x;
    int bx = blockIdx.x;
    if (bx < NMB) {
        if (t >= H) return;
        float inv = invS[t];
        float st1 = 0.f, st2 = 0.f;
        int n0 = bx * 2;
#pragma unroll
        for (int k = 0; k < 2; ++k) {
            int n = n0 + k;
            int beg = offs[n], end = offs[n + 1];
            float a = 0.f;
            for (int i = beg; i < end; ++i) {
                int e = eidx[i];
                int s = msrc[i];
                a += sigm(__bfloat162float(edge_bf[(size_t)e * HP + t])) * nodeV[(size_t)s * H + t];
            }
            float v = nodeUn[(size_t)n * H + t] + a * inv;
            aggv[(size_t)n * H + t] = v;
            st1 += v; st2 += v * v;
        }
        float* rn = RN + (size_t)(bx & (NREP - 1)) * RSTRIDE;
        atomicAdd(&rn[t], st1);
        atomicAdd(&rn[SSTRIDE + t], st2);
    } else {
        // gate[e][h] = gate_mfma[e][h] + nodeU[src][h] + nodeU[dst][h]; col stats
        int eb = bx - NMB;                 // 0..499
        for (int i = t; i < SSTRIDE; i += 320) { s1[i] = 0.f; s2[i] = 0.f; }
        __syncthreads();
        int hc = t % 80, rgrp = t / 80;    // 4 row groups x 80 col chunks
        int col0 = hc * 4;
        float cs[4] = {0.f, 0.f, 0.f, 0.f};
        float cq[4] = {0.f, 0.f, 0.f, 0.f};
        if (hc < CH) {
            int e0 = eb * 64;
            for (int r = rgrp; r < 64; r += 4) {
                int e = e0 + r;
                int se = src[e], de = dst[e];
                union { ushort4 u; bf16 b[4]; } gm, ob;
                gm.u = *(const ushort4*)(gate_bf + (size_t)e * H + col0);
                float4 u1 = *(const float4*)(nodeU + (size_t)se * H + col0);
                float4 u2 = *(const float4*)(nodeU + (size_t)de * H + col0);
                const float* u1p = (const float*)&u1;
                const float* u2p = (const float*)&u2;
#pragma unroll
                for (int j = 0; j < 4; ++j) {
                    float g = __bfloat162float(gm.b[j]) + u1p[j] + u2p[j];
                    ob.b[j] = __float2bfloat16(g);
                    cs[j] += g;
                    cq[j] += g * g;
                }
                *(ushort4*)(gate_bf + (size_t)e * H + col0) = ob.u;
            }
#pragma unroll
            for (int j = 0; j < 4; ++j) {
                atomicAdd(&s1[col0 + j], cs[j]);
                atomicAdd(&s2[col0 + j], cq[j]);
            }
        }
        __syncthreads();
        float* re = REc + (size_t)(eb & (NREP - 1)) * RSTRIDE;
        for (int i = t; i < H; i += 320) {
            atomicAdd(&re[i], s1[i]);
            atomicAdd(&re[SSTRIDE + i], s2[i]);
        }
    }
}

// ------------- K4: edge_finalize (bx<NEB) || node_update (bx>=NEB), bf16 residual
__global__ __launch_bounds__(256) void fused_final(bf16* __restrict__ edge_bf,
                                                   const bf16* __restrict__ gate_bf,
                                                   const float* __restrict__ REc,
                                                   float* __restrict__ REo,
                                                   const float* __restrict__ RNc,
                                                   float* __restrict__ RNo,
                                                   float* __restrict__ RSnext,
                                                   const float* __restrict__ eg,
                                                   const float* __restrict__ ebt,
                                                   const float* __restrict__ ng,
                                                   const float* __restrict__ nbt,
                                                   float* __restrict__ node,
                                                   bf16* __restrict__ node_bf,
                                                   const float* __restrict__ aggv) {
    __shared__ float sc_s[SSTRIDE], of_s[SSTRIDE], s_s[SSTRIDE];
    int bx = blockIdx.x, t = threadIdx.x;
    if (bx < NEB) {
        const float invE = 1.f / N_EDGES;
        for (int i = t; i < SSTRIDE; i += 256) {
            s_s[i] = 0.f;
            if (i < H) {
                float gs = 0.f, gq = 0.f;
#pragma unroll 8
                for (int r = 0; r < NREP; ++r) {
                    gs += REc[r * RSTRIDE + i];
                    gq += REc[r * RSTRIDE + SSTRIDE + i];
                }
                float mean = gs * invE;
                float var = fmaxf(gq * invE - mean * mean, 0.f);
                float rstd = rsqrtf(var + 1e-5f);
                float sc = rstd * eg[i];
                sc_s[i] = sc;
                of_s[i] = ebt[i] - mean * sc;
            }
        }
        __syncthreads();
        int hc = t % 80, rgrp = t / 80;
        bool act = (hc < CH) && (rgrp < 3);
        float ss[4] = {0.f, 0.f, 0.f, 0.f};
        int col0 = hc * 4;
        if (act) {
            float sc[4], of[4];
#pragma unroll
            for (int j = 0; j < 4; ++j) { sc[j] = sc_s[col0 + j]; of[j] = of_s[col0 + j]; }
            int e0 = bx * 64;
            for (int r = rgrp; r < 64; r += 3) {
                int e = e0 + r;
                union { ushort4 u; bf16 b[4]; } eb, gv, ob;
                eb.u = *(const ushort4*)(edge_bf + (size_t)e * HP + col0);
                gv.u = *(const ushort4*)(gate_bf + (size_t)e * H + col0);
#pragma unroll
                for (int j = 0; j < 4; ++j) {
                    float g = __bfloat162float(gv.b[j]);
                    float val = fmaxf(fmaf(g, sc[j], of[j]), 0.f);
                    float nv = __bfloat162float(eb.b[j]) + val;
                    ob.b[j] = __float2bfloat16(nv);
                    ss[j] += sigm(__bfloat162float(ob.b[j]));
                }
                *(ushort4*)(edge_bf + (size_t)e * HP + col0) = ob.u;
            }
#pragma unroll
            for (int j = 0; j < 4; ++j) atomicAdd(&s_s[col0 + j], ss[j]);
        }
        __syncthreads();
        float* rs = RSnext + (size_t)(bx & (NREP - 1)) * SSTRIDE;
        for (int i = t; i < H; i += 256) atomicAdd(&rs[i], s_s[i]);
    } else {
        int idx = bx - NEB;                // 0..NUB-1
        if (idx < NREP) {
            for (int i = t; i < RSTRIDE; i += 256) {
                REo[(size_t)idx * RSTRIDE + i] = 0.f;
                RNo[(size_t)idx * RSTRIDE + i] = 0.f;
            }
        }
        const float invN = 1.f / N_NODES;
        for (int i = t; i < H; i += 256) {
            float ns = 0.f, nq = 0.f;
#pragma unroll 8
            for (int r = 0; r < NREP; ++r) {
                ns += RNc[r * RSTRIDE + i];
                nq += RNc[r * RSTRIDE + SSTRIDE + i];
            }
            float mean = ns * invN;
            float var = fmaxf(nq * invN - mean * mean, 0.f);
            float rstd = rsqrtf(var + 1e-5f);
            float sc = rstd * ng[i];
            sc_s[i] = sc;
            of_s[i] = nbt[i] - mean * sc;
        }
        __syncthreads();
#pragma unroll
        for (int it = 0; it < 4; ++it) {
            int c = idx * 1024 + it * 256 + t;
            if (c >= NH / 4) break;
            int n = c / CH, hc = c % CH, col0 = hc * 4;
            float4 v4 = ((const float4*)aggv)[c];
            float4 nd = ((const float4*)node)[c];
            const float* v4p = (const float*)&v4;
            const float* ndp = (const float*)&nd;
            union { ushort4 u; bf16 b[4]; } ob;
            float outv[4];
#pragma unroll
            for (int j = 0; j < 4; ++j) {
                float g = fmaf(v4p[j], sc_s[col0 + j], of_s[col0 + j]);
                outv[j] = ndp[j] + fmaxf(g, 0.f);
                ob.b[j] = __float2bfloat16(outv[j]);
            }
            ((float4*)node)[c] = make_float4(outv[0], outv[1], outv[2], outv[3]);
            *(ushort4*)(node_bf + (size_t)n * HP + col0) = ob.u;
        }
    }
}

// ------------------------------------------------------- classifier + loss
__global__ __launch_bounds__(256) void classify_loss(const bf16* __restrict__ edge_bf,
                                                     const float* __restrict__ clsW,
                                                     const float* __restrict__ clsb,
                                                     const int* __restrict__ src,
                                                     const int* __restrict__ dst,
                                                     const float* __restrict__ y,
                                                     float* __restrict__ out) {
    __shared__ float wl[4];
    int lane = threadIdx.x & 63;
    int wid = threadIdx.x >> 6;
    int gw = blockIdx.x * 4 + wid;
    float lsum = 0.f;
    for (int e = gw; e < N_EDGES; e += 2000) {
        float acc = 0.f;
        for (int h = lane; h < H; h += 64)
            acc += __bfloat162float(edge_bf[(size_t)e * HP + h]) * clsW[h];
#pragma unroll
        for (int off = 32; off > 0; off >>= 1) acc += __shfl_down(acc, off, 64);
        if (lane == 0) {
            float z = acc + clsb[0];
            float p = 1.f / (1.f + __expf(-z));
            atomicAdd(&out[(size_t)src[e] * N_NODES + dst[e]], p);
            float pc = fminf(fmaxf(p, 1e-7f), 1.f - 1e-7f);
            lsum += -(y[e] * __logf(pc) + (1.f - y[e]) * log1pf(-pc));
        }
    }
    if (lane == 0) wl[wid] = lsum;
    __syncthreads();
    if (threadIdx.x == 0) {
        float t = wl[0] + wl[1] + wl[2] + wl[3];
        atomicAdd(&out[(size_t)N_NODES * N_NODES], t * (1.f / N_EDGES));
    }
}

// ---------------------------------------------------------------- launcher
extern "C" void kernel_launch(void* const* d_in, const int* in_sizes, int n_in,
                              void* d_out, int out_size, void* d_ws, size_t ws_size,
                              hipStream_t stream) {
    const float* x          = (const float*)d_in[0];
    const float* edge_attr  = (const float*)d_in[1];
    const int*   edge_index = (const int*)d_in[2];
    const float* y          = (const float*)d_in[3];
    const float* node_emb_W = (const float*)d_in[4];
    const float* node_emb_b = (const float*)d_in[5];
    const float* edge_d_W   = (const float*)d_in[6];
    const float* edge_d_b   = (const float*)d_in[7];
    const float* edge_t_W   = (const float*)d_in[8];
    const float* edge_t_b   = (const float*)d_in[9];
    const float* eU_W = (const float*)d_in[10];
    const float* eU_b = (const float*)d_in[11];
    const float* eW_W = (const float*)d_in[12];
    const float* nU_W = (const float*)d_in[14];
    const float* nU_b = (const float*)d_in[15];
    const float* nV_W = (const float*)d_in[16];
    const float* nV_b = (const float*)d_in[17];
    const float* bn_e_g = (const float*)d_in[18];
    const float* bn_e_b = (const float*)d_in[19];
    const float* bn_n_g = (const float*)d_in[20];
    const float* bn_n_b = (const float*)d_in[21];
    const float* cls_W = (const float*)d_in[22];
    const float* cls_b = (const float*)d_in[23];

    const int* src = edge_index;
    const int* dst = edge_index + N_EDGES;

    float* ws     = (float*)d_ws;
    float* node   = ws;                  // NH
    float* nodeU  = node + NH;           // NH
    float* nodeV  = nodeU + NH;          // NH
    float* nodeUn = nodeV + NH;          // NH
    float* aggv   = nodeUn + NH;         // NH
    float* RE2    = aggv + NH;           // 2 x 32*608   <-- zero region start
    float* RN2    = RE2 + 2 * NREP * RSTRIDE;
    float* RS2    = RN2 + 2 * NREP * RSTRIDE;  // 2 x 32*304
    float* invS   = RS2 + 2 * NREP * SSTRIDE;  // 304
    bf16* node_bf = (bf16*)(invS + SSTRIDE);              // 2048*320
    bf16* edge_bf = node_bf + (size_t)NODE_ROWS_PAD * HP; // 32000*320
    bf16* gate_bf = edge_bf + (size_t)N_EDGES * HP;       // 32000*300 (not zeroed)
    bf16* Wt_all  = gate_bf + (size_t)N_EDGES * H;        // 120*102400
    int* csr_counts = (int*)(Wt_all + (size_t)120 * WMAT);
    int* csr_offs   = csr_counts + 2048;
    int* csr_woff   = csr_offs + 2048;
    int* csr_eidx   = csr_woff + 2048;
    int* csr_msrc   = csr_eidx + N_EDGES;

    float* out = (float*)d_out;

    // zero: out, [RE2 | RN2 | RS2 | invS | node_bf | edge_bf], csr_counts
    int zstats = 4 * NREP * RSTRIDE + 2 * NREP * SSTRIDE + SSTRIDE;
    int zlen = zstats + (NODE_ROWS_PAD * HP + N_EDGES * HP) / 2;
    zero_buf<<<(N_NODES * N_NODES + 1 + 255) / 256, 256, 0, stream>>>(out, N_NODES * N_NODES + 1);
    zero_buf<<<(zlen + 255) / 256, 256, 0, stream>>>(RE2, zlen);
    zero_buf<<<8, 256, 0, stream>>>((float*)csr_counts, 2048);

    convert_weights_t<<<12000, 256, 0, stream>>>(eU_W, eW_W, nU_W, nV_W, Wt_all);
    csr_hist<<<(N_EDGES + 255) / 256, 256, 0, stream>>>(dst, csr_counts);
    csr_scan<<<1, 256, 0, stream>>>(csr_counts, csr_offs, csr_woff);
    csr_scatter<<<(N_EDGES + 255) / 256, 256, 0, stream>>>(src, dst, csr_woff, csr_eidx, csr_msrc);
    node_embed<<<(NH + 255) / 256, 256, 0, stream>>>(x, node_emb_W, node_emb_b, node, node_bf);
    edge_embed<<<NEB, 256, 0, stream>>>(edge_attr, edge_d_W, edge_d_b,
                                        edge_t_W, edge_t_b, edge_bf, RS2);

    for (int l = 0; l < NLAYERS; ++l) {
        float* REc = RE2 + (size_t)(l & 1) * NREP * RSTRIDE;
        float* REo = RE2 + (size_t)((l + 1) & 1) * NREP * RSTRIDE;
        float* RNc = RN2 + (size_t)(l & 1) * NREP * RSTRIDE;
        float* RNo = RN2 + (size_t)((l + 1) & 1) * NREP * RSTRIDE;
        float* RScur = RS2 + (size_t)(l & 1) * NREP * SSTRIDE;
        float* RSnxt = RS2 + (size_t)((l + 1) & 1) * NREP * SSTRIDE;
        const bf16* BtE = Wt_all + (size_t)(30 + l) * WMAT;

        gemm_node<<<1505, 64, 0, stream>>>(node_bf, Wt_all, eU_b, nV_b, nU_b, l,
                                           nodeU, nodeV, nodeUn, RScur, RSnxt, invS);
        gemm_edge<<<2000, 64, 0, stream>>>(edge_bf, BtE, gate_bf);
        node_msg<<<NMB + NEB, 320, 0, stream>>>(edge_bf, nodeV, nodeUn,
                                                csr_offs, csr_eidx, csr_msrc,
                                                invS, RNc, aggv,
                                                gate_bf, nodeU, src, dst, REc);
        fused_final<<<NEB + NUB, 256, 0, stream>>>(edge_bf, gate_bf,
                                                   REc, REo, RNc, RNo, RSnxt,
                                                   bn_e_g + l * H, bn_e_b + l * H,
                                                   bn_n_g + l * H, bn_n_b + l * H,
                                                   node, node_bf, aggv);
    }

    classify_loss<<<500, 256, 0, stream>>>(edge_bf, cls_W, cls_b, src, dst, y, out);
}

// Round 11
// 3163.613 us; speedup vs baseline: 1.0239x; 1.0239x over previous
//
#include <hip/hip_runtime.h>
#include <hip/hip_bf16.h>
#include <math.h>

#define N_NODES 2000
#define N_EDGES 32000
#define H 300
#define CH 75             // H/4 float4 chunks per row
#define HP 320            // padded H for MFMA K/N
#define NLAYERS 30
#define NH (N_NODES * H)     // 600000
#define NODE_ROWS_PAD 2048
#define WMAT (HP * HP)
#define NREP 32              // stat replicas
#define RSTRIDE 608          // replica row stride (sum | sumsq at +304)
#define SSTRIDE 304
#define NEB 500              // edge blocks (32000/64)
#define NUB 147              // node_update blocks (1024 chunks each)
#define NMB 1000             // node_msg gather blocks (2 nodes each)

typedef short bf16x8 __attribute__((ext_vector_type(8)));
typedef float f32x4 __attribute__((ext_vector_type(4)));
typedef __hip_bfloat16 bf16;

__device__ __forceinline__ float sigm(float x) { return 1.f / (1.f + __expf(-x)); }

// ---------------------------------------------------------------- utilities
__global__ __launch_bounds__(256) void zero_buf(float* __restrict__ p, int n) {
    int i = blockIdx.x * blockDim.x + threadIdx.x;
    if (i < n) p[i] = 0.f;
}

// --------------------- weights -> bf16 transposed, LDS-tiled (coalesced both ways)
__global__ __launch_bounds__(256) void convert_weights_t(const float* __restrict__ eU,
                                                         const float* __restrict__ eW,
                                                         const float* __restrict__ nU,
                                                         const float* __restrict__ nV,
                                                         bf16* __restrict__ Wt) {
    __shared__ float tile[32][33];
    int b = blockIdx.x;                 // 120 mats x 100 tiles
    int m = b / 100;
    int rem = b % 100;
    int kt = rem / 10, nt = rem % 10;
    int k0 = kt * 32, n0 = nt * 32;
    int grp = m / NLAYERS, l = m % NLAYERS;
    const float* S = (grp == 0) ? eU : (grp == 1) ? eW : (grp == 2) ? nU : nV;
    const float* Sl = S + (size_t)l * H * H;
    int t = threadIdx.x;
    int tn = t & 31, tk = t >> 5;
#pragma unroll
    for (int p = 0; p < 4; ++p) {
        int k = tk + p * 8;
        int gk = k0 + k, gn = n0 + tn;
        tile[k][tn] = (gk < H && gn < H) ? Sl[(size_t)gk * H + gn] : 0.f;
    }
    __syncthreads();
    bf16* D = Wt + (size_t)m * WMAT;
    int tk2 = t & 31, tn2 = t >> 5;
#pragma unroll
    for (int p = 0; p < 4; ++p) {
        int n = tn2 + p * 8;
        D[(size_t)(n0 + n) * HP + k0 + tk2] = __float2bfloat16(tile[tk2][n]);
    }
}

// ------------------------------------------------------------- CSR by dst
__global__ __launch_bounds__(256) void csr_hist(const int* __restrict__ dst,
                                                int* __restrict__ counts) {
    int i = blockIdx.x * 256 + threadIdx.x;
    if (i < N_EDGES) atomicAdd(&counts[dst[i]], 1);
}

__global__ __launch_bounds__(256) void csr_scan(const int* __restrict__ counts,
                                                int* __restrict__ offs,
                                                int* __restrict__ woff) {
    __shared__ int part[256];
    int t = threadIdx.x;
    int base = t * 8;
    int local[8];
    int s = 0;
#pragma unroll
    for (int j = 0; j < 8; ++j) {
        int c = (base + j < N_NODES) ? counts[base + j] : 0;
        local[j] = s;
        s += c;
    }
    part[t] = s;
    __syncthreads();
    for (int off = 1; off < 256; off <<= 1) {
        int v = (t >= off) ? part[t - off] : 0;
        __syncthreads();
        part[t] += v;
        __syncthreads();
    }
    int pre = (t == 0) ? 0 : part[t - 1];
#pragma unroll
    for (int j = 0; j < 8; ++j) {
        int idx = base + j;
        if (idx < N_NODES) { int v = pre + local[j]; offs[idx] = v; woff[idx] = v; }
    }
    if (t == 255) offs[N_NODES] = part[255];
}

__global__ __launch_bounds__(256) void csr_scatter(const int* __restrict__ src,
                                                   const int* __restrict__ dst,
                                                   int* __restrict__ woff,
                                                   int* __restrict__ eidx,
                                                   int* __restrict__ msrc) {
    int i = blockIdx.x * 256 + threadIdx.x;
    if (i < N_EDGES) {
        int p = atomicAdd(&woff[dst[i]], 1);
        eidx[p] = i;
        msrc[p] = src[i];
    }
}

// ---------------------------------------------------------------- embeddings
__global__ __launch_bounds__(256) void node_embed(const float* __restrict__ x,
                                                  const float* __restrict__ W,
                                                  const float* __restrict__ b,
                                                  float* __restrict__ node,
                                                  bf16* __restrict__ node_bf) {
    int i = blockIdx.x * blockDim.x + threadIdx.x;
    if (i >= NH) return;
    int n = i / H, h = i % H;
    float acc = b[h];
#pragma unroll
    for (int k = 0; k < 4; ++k) acc += x[n * 4 + k] * W[k * H + h];
    node[i] = acc;
    node_bf[(size_t)n * HP + h] = __float2bfloat16(acc);
}

// edge embedding, bf16 only, col-chunk ownership; sigmoid colsum -> RS0
__global__ __launch_bounds__(256) void edge_embed(const float* __restrict__ ea,
                                                  const float* __restrict__ dW,
                                                  const float* __restrict__ db,
                                                  const float* __restrict__ tW,
                                                  const float* __restrict__ tb,
                                                  bf16* __restrict__ edge_bf,
                                                  float* __restrict__ RS0) {
    __shared__ float s_s[SSTRIDE];
    int t = threadIdx.x;
    for (int i = t; i < SSTRIDE; i += 256) s_s[i] = 0.f;
    __syncthreads();
    int hc = t % 80, rgrp = t / 80;
    int col0 = hc * 4;
    float ss[4] = {0.f, 0.f, 0.f, 0.f};
    if (hc < CH && rgrp < 3) {
        float wv[4], bv[4];
#pragma unroll
        for (int j = 0; j < 4; ++j) {
            int col = col0 + j;
            wv[j] = (col < 150) ? dW[col] : tW[col - 150];
            bv[j] = (col < 150) ? db[col] : tb[col - 150];
        }
        int e0 = blockIdx.x * 64;
        for (int r = rgrp; r < 64; r += 3) {
            int e = e0 + r;
            float d = ea[2 * e], tt = ea[2 * e + 1];
            union { ushort4 u; bf16 b[4]; } ob;
#pragma unroll
            for (int j = 0; j < 4; ++j) {
                int col = col0 + j;
                float v = ((col < 150) ? d : tt) * wv[j] + bv[j];
                ob.b[j] = __float2bfloat16(v);
                ss[j] += sigm(__bfloat162float(ob.b[j]));
            }
            *(ushort4*)(edge_bf + (size_t)e * HP + col0) = ob.u;
        }
#pragma unroll
        for (int j = 0; j < 4; ++j) atomicAdd(&s_s[col0 + j], ss[j]);
    }
    __syncthreads();
    float* rs = RS0 + (size_t)(blockIdx.x & (NREP - 1)) * SSTRIDE;
    for (int i = t; i < H; i += 256) atomicAdd(&rs[i], s_s[i]);
}

// ---- K1: ALL GEMMs fused (independent): edge gate GEMM (bx<2000, pure) ||
//      node GEMMs (2000<=bx<3500) || invS/RSnxt housekeeping (bx>=3500)
__global__ __launch_bounds__(64) void gemm_all(const bf16* __restrict__ node_bf,
                                               const bf16* __restrict__ edge_bf,
                                               const bf16* __restrict__ Wt_all,
                                               const float* __restrict__ eU_b,
                                               const float* __restrict__ nV_b,
                                               const float* __restrict__ nU_b,
                                               int layer,
                                               float* __restrict__ nodeU,
                                               float* __restrict__ nodeV,
                                               float* __restrict__ nodeUn,
                                               bf16* __restrict__ gate_bf,
                                               const float* __restrict__ RScur,
                                               float* __restrict__ RSnxt,
                                               float* __restrict__ invS) {
    int bx = blockIdx.x;
    int lane = threadIdx.x;
    int rlo = lane & 15, khi = lane >> 4, rhi = lane >> 4;
    if (bx < 2000) {
        // -------- pure edge gate GEMM: 32r x 160c per wave
        const bf16* Bt = Wt_all + (size_t)(30 + layer) * WMAT;
        int row0 = (bx >> 1) * 32;
        int c0 = (bx & 1) * 160;
        f32x4 acc[2][10];
#pragma unroll
        for (int rt = 0; rt < 2; ++rt)
#pragma unroll
            for (int ct = 0; ct < 10; ++ct) acc[rt][ct] = (f32x4)0.f;
#pragma unroll 2
        for (int ks = 0; ks < 10; ++ks) {
            int kk = ks * 32 + khi * 8;
            bf16x8 a[2], b[10];
#pragma unroll
            for (int rt = 0; rt < 2; ++rt)
                a[rt] = *(const bf16x8*)(edge_bf + (size_t)(row0 + rt * 16 + rlo) * HP + kk);
#pragma unroll
            for (int ct = 0; ct < 10; ++ct)
                b[ct] = *(const bf16x8*)(Bt + (size_t)(c0 + ct * 16 + rlo) * HP + kk);
#pragma unroll
            for (int rt = 0; rt < 2; ++rt)
#pragma unroll
                for (int ct = 0; ct < 10; ++ct)
                    acc[rt][ct] = __builtin_amdgcn_mfma_f32_16x16x32_bf16(a[rt], b[ct], acc[rt][ct], 0, 0, 0);
        }
#pragma unroll
        for (int rt = 0; rt < 2; ++rt)
#pragma unroll
            for (int ct = 0; ct < 10; ++ct) {
                int col = c0 + ct * 16 + rlo;
                if (col >= H) continue;
#pragma unroll
                for (int j = 0; j < 4; ++j) {
                    int r = row0 + rt * 16 + rhi * 4 + j;
                    gate_bf[(size_t)r * H + col] = __float2bfloat16(acc[rt][ct][j]);
                }
            }
    } else if (bx < 3500) {
        // -------- node GEMMs: 16r x 80c per wave
        int idx = bx - 2000;
        int mat = idx / 500;
        int rem = idx % 500;
        int rt0 = rem >> 2, ct4 = rem & 3;
        const bf16* Bt; const float* bias; float* out;
        if (mat == 0)      { Bt = Wt_all + (size_t)(0 + layer) * WMAT;  bias = eU_b + layer * H; out = nodeU; }
        else if (mat == 1) { Bt = Wt_all + (size_t)(90 + layer) * WMAT; bias = nV_b + layer * H; out = nodeV; }
        else               { Bt = Wt_all + (size_t)(60 + layer) * WMAT; bias = nU_b + layer * H; out = nodeUn; }
        int row0 = rt0 * 16, c0 = ct4 * 80;
        f32x4 acc[5];
#pragma unroll
        for (int ct = 0; ct < 5; ++ct) acc[ct] = (f32x4)0.f;
#pragma unroll 2
        for (int ks = 0; ks < 10; ++ks) {
            int kk = ks * 32 + khi * 8;
            bf16x8 a, b[5];
            a = *(const bf16x8*)(node_bf + (size_t)(row0 + rlo) * HP + kk);
#pragma unroll
            for (int ct = 0; ct < 5; ++ct)
                b[ct] = *(const bf16x8*)(Bt + (size_t)(c0 + ct * 16 + rlo) * HP + kk);
#pragma unroll
            for (int ct = 0; ct < 5; ++ct)
                acc[ct] = __builtin_amdgcn_mfma_f32_16x16x32_bf16(a, b[ct], acc[ct], 0, 0, 0);
        }
#pragma unroll
        for (int ct = 0; ct < 5; ++ct) {
            int col = c0 + ct * 16 + rlo;
            if (col >= H) continue;
            float bv = bias[col];
#pragma unroll
            for (int j = 0; j < 4; ++j) {
                int r = row0 + rhi * 4 + j;
                out[(size_t)r * H + col] = acc[ct][j] + bv;
            }
        }
    } else {
        // -------- invS from RScur; zero RSnxt (5 blocks x 64)
        int idx = bx - 3500;               // 0..4
        int c = idx * 64 + lane;           // 0..319
        if (c < H) {
            float ssr = 0.f;
#pragma unroll 8
            for (int r = 0; r < NREP; ++r) ssr += RScur[r * SSTRIDE + c];
            invS[c] = 1.f / (ssr + 1e-20f);
        }
        for (int i = idx * 64 + lane; i < NREP * SSTRIDE; i += 320) RSnxt[i] = 0.f;
    }
}

// ---- K2: CSR gather (bx<NMB, 2 nodes/block) || gate-finish+stats (bx>=NMB)
__global__ __launch_bounds__(320) void node_msg(const bf16* __restrict__ edge_bf,
                                                const float* __restrict__ nodeV,
                                                const float* __restrict__ nodeUn,
                                                const int* __restrict__ offs,
                                                const int* __restrict__ eidx,
                                                const int* __restrict__ msrc,
                                                const float* __restrict__ invS,
                                                float* __restrict__ RN,
                                                float* __restrict__ aggv,
                                                bf16* __restrict__ gate_bf,
                                                const float* __restrict__ nodeU,
                                                const int* __restrict__ src,
                                                const int* __restrict__ dst,
                                                float* __restrict__ REc) {
    __shared__ float s1[SSTRIDE], s2[SSTRIDE];
    int t = threadIdx.x;
    int bx = blockIdx.x;
    if (bx < NMB) {
        if (t >= H) return;
        float inv = invS[t];
        float st1 = 0.f, st2 = 0.f;
        int n0 = bx * 2;
#pragma unroll
        for (int k = 0; k < 2; ++k) {
            int n = n0 + k;
            int beg = offs[n], end = offs[n + 1];
            float a = 0.f;
            for (int i = beg; i < end; ++i) {
                int e = eidx[i];
                int s = msrc[i];
                a += sigm(__bfloat162float(edge_bf[(size_t)e * HP + t])) * nodeV[(size_t)s * H + t];
            }
            float v = nodeUn[(size_t)n * H + t] + a * inv;
            aggv[(size_t)n * H + t] = v;
            st1 += v; st2 += v * v;
        }
        float* rn = RN + (size_t)(bx & (NREP - 1)) * RSTRIDE;
        atomicAdd(&rn[t], st1);
        atomicAdd(&rn[SSTRIDE + t], st2);
    } else {
        // gate[e][h] = gate_mfma[e][h] + nodeU[src][h] + nodeU[dst][h]; col stats
        int eb = bx - NMB;                 // 0..499
        for (int i = t; i < SSTRIDE; i += 320) { s1[i] = 0.f; s2[i] = 0.f; }
        __syncthreads();
        int hc = t % 80, rgrp = t / 80;    // 4 row groups x 80 col chunks
        int col0 = hc * 4;
        float cs[4] = {0.f, 0.f, 0.f, 0.f};
        float cq[4] = {0.f, 0.f, 0.f, 0.f};
        if (hc < CH) {
            int e0 = eb * 64;
            for (int r = rgrp; r < 64; r += 4) {
                int e = e0 + r;
                int se = src[e], de = dst[e];
                union { ushort4 u; bf16 b[4]; } gm, ob;
                gm.u = *(const ushort4*)(gate_bf + (size_t)e * H + col0);
                float4 u1 = *(const float4*)(nodeU + (size_t)se * H + col0);
                float4 u2 = *(const float4*)(nodeU + (size_t)de * H + col0);
                const float* u1p = (const float*)&u1;
                const float* u2p = (const float*)&u2;
#pragma unroll
                for (int j = 0; j < 4; ++j) {
                    float g = __bfloat162float(gm.b[j]) + u1p[j] + u2p[j];
                    ob.b[j] = __float2bfloat16(g);
                    cs[j] += g;
                    cq[j] += g * g;
                }
                *(ushort4*)(gate_bf + (size_t)e * H + col0) = ob.u;
            }
#pragma unroll
            for (int j = 0; j < 4; ++j) {
                atomicAdd(&s1[col0 + j], cs[j]);
                atomicAdd(&s2[col0 + j], cq[j]);
            }
        }
        __syncthreads();
        float* re = REc + (size_t)(eb & (NREP - 1)) * RSTRIDE;
        for (int i = t; i < H; i += 320) {
            atomicAdd(&re[i], s1[i]);
            atomicAdd(&re[SSTRIDE + i], s2[i]);
        }
    }
}

// ------------- K3: edge_finalize (bx<NEB) || node_update (bx>=NEB), bf16 residual
__global__ __launch_bounds__(256) void fused_final(bf16* __restrict__ edge_bf,
                                                   const bf16* __restrict__ gate_bf,
                                                   const float* __restrict__ REc,
                                                   float* __restrict__ REo,
                                                   const float* __restrict__ RNc,
                                                   float* __restrict__ RNo,
                                                   float* __restrict__ RSnext,
                                                   const float* __restrict__ eg,
                                                   const float* __restrict__ ebt,
                                                   const float* __restrict__ ng,
                                                   const float* __restrict__ nbt,
                                                   float* __restrict__ node,
                                                   bf16* __restrict__ node_bf,
                                                   const float* __restrict__ aggv) {
    __shared__ float sc_s[SSTRIDE], of_s[SSTRIDE], s_s[SSTRIDE];
    int bx = blockIdx.x, t = threadIdx.x;
    if (bx < NEB) {
        const float invE = 1.f / N_EDGES;
        for (int i = t; i < SSTRIDE; i += 256) {
            s_s[i] = 0.f;
            if (i < H) {
                float gs = 0.f, gq = 0.f;
#pragma unroll 8
                for (int r = 0; r < NREP; ++r) {
                    gs += REc[r * RSTRIDE + i];
                    gq += REc[r * RSTRIDE + SSTRIDE + i];
                }
                float mean = gs * invE;
                float var = fmaxf(gq * invE - mean * mean, 0.f);
                float rstd = rsqrtf(var + 1e-5f);
                float sc = rstd * eg[i];
                sc_s[i] = sc;
                of_s[i] = ebt[i] - mean * sc;
            }
        }
        __syncthreads();
        int hc = t % 80, rgrp = t / 80;
        bool act = (hc < CH) && (rgrp < 3);
        float ss[4] = {0.f, 0.f, 0.f, 0.f};
        int col0 = hc * 4;
        if (act) {
            float sc[4], of[4];
#pragma unroll
            for (int j = 0; j < 4; ++j) { sc[j] = sc_s[col0 + j]; of[j] = of_s[col0 + j]; }
            int e0 = bx * 64;
            for (int r = rgrp; r < 64; r += 3) {
                int e = e0 + r;
                union { ushort4 u; bf16 b[4]; } eb, gv, ob;
                eb.u = *(const ushort4*)(edge_bf + (size_t)e * HP + col0);
                gv.u = *(const ushort4*)(gate_bf + (size_t)e * H + col0);
#pragma unroll
                for (int j = 0; j < 4; ++j) {
                    float g = __bfloat162float(gv.b[j]);
                    float val = fmaxf(fmaf(g, sc[j], of[j]), 0.f);
                    float nv = __bfloat162float(eb.b[j]) + val;
                    ob.b[j] = __float2bfloat16(nv);
                    ss[j] += sigm(__bfloat162float(ob.b[j]));
                }
                *(ushort4*)(edge_bf + (size_t)e * HP + col0) = ob.u;
            }
#pragma unroll
            for (int j = 0; j < 4; ++j) atomicAdd(&s_s[col0 + j], ss[j]);
        }
        __syncthreads();
        float* rs = RSnext + (size_t)(bx & (NREP - 1)) * SSTRIDE;
        for (int i = t; i < H; i += 256) atomicAdd(&rs[i], s_s[i]);
    } else {
        int idx = bx - NEB;                // 0..NUB-1
        if (idx < NREP) {
            for (int i = t; i < RSTRIDE; i += 256) {
                REo[(size_t)idx * RSTRIDE + i] = 0.f;
                RNo[(size_t)idx * RSTRIDE + i] = 0.f;
            }
        }
        const float invN = 1.f / N_NODES;
        for (int i = t; i < H; i += 256) {
            float ns = 0.f, nq = 0.f;
#pragma unroll 8
            for (int r = 0; r < NREP; ++r) {
                ns += RNc[r * RSTRIDE + i];
                nq += RNc[r * RSTRIDE + SSTRIDE + i];
            }
            float mean = ns * invN;
            float var = fmaxf(nq * invN - mean * mean, 0.f);
            float rstd = rsqrtf(var + 1e-5f);
            float sc = rstd * ng[i];
            sc_s[i] = sc;
            of_s[i] = nbt[i] - mean * sc;
        }
        __syncthreads();
#pragma unroll
        for (int it = 0; it < 4; ++it) {
            int c = idx * 1024 + it * 256 + t;
            if (c >= NH / 4) break;
            int n = c / CH, hc = c % CH, col0 = hc * 4;
            float4 v4 = ((const float4*)aggv)[c];
            float4 nd = ((const float4*)node)[c];
            const float* v4p = (const float*)&v4;
            const float* ndp = (const float*)&nd;
            union { ushort4 u; bf16 b[4]; } ob;
            float outv[4];
#pragma unroll
            for (int j = 0; j < 4; ++j) {
                float g = fmaf(v4p[j], sc_s[col0 + j], of_s[col0 + j]);
                outv[j] = ndp[j] + fmaxf(g, 0.f);
                ob.b[j] = __float2bfloat16(outv[j]);
            }
            ((float4*)node)[c] = make_float4(outv[0], outv[1], outv[2], outv[3]);
            *(ushort4*)(node_bf + (size_t)n * HP + col0) = ob.u;
        }
    }
}

// ----------------- classifier + loss: 4 lanes/edge, vectorized, clsW in regs
__global__ __launch_bounds__(256) void classify_loss(const bf16* __restrict__ edge_bf,
                                                     const float* __restrict__ clsW,
                                                     const float* __restrict__ clsb,
                                                     const int* __restrict__ src,
                                                     const int* __restrict__ dst,
                                                     const float* __restrict__ y,
                                                     float* __restrict__ out) {
    __shared__ float wl[4];
    int lane = threadIdx.x & 63;
    int wid = threadIdx.x >> 6;
    int quad = lane >> 2;              // edge index within 16-edge group
    int ql = lane & 3;                 // 80-col chunk
    float w[80];
#pragma unroll
    for (int j = 0; j < 80; ++j) {
        int col = ql * 80 + j;
        w[j] = (col < H) ? clsW[col] : 0.f;
    }
    int g = blockIdx.x * 4 + wid;      // 0..1999, one 16-edge group per wave
    int e = g * 16 + quad;
    const bf16* row = edge_bf + (size_t)e * HP + ql * 80;   // pad cols are 0
    float acc = 0.f;
#pragma unroll
    for (int v = 0; v < 10; ++v) {
        bf16x8 bv = *(const bf16x8*)(row + v * 8);
#pragma unroll
        for (int j = 0; j < 8; ++j)
            acc += __bfloat162float(((const bf16*)&bv)[j]) * w[v * 8 + j];
    }
    acc += __shfl_xor(acc, 1, 64);
    acc += __shfl_xor(acc, 2, 64);
    float lsum = 0.f;
    if (ql == 0) {
        float z = acc + clsb[0];
        float p = 1.f / (1.f + __expf(-z));
        atomicAdd(&out[(size_t)src[e] * N_NODES + dst[e]], p);
        float pc = fminf(fmaxf(p, 1e-7f), 1.f - 1e-7f);
        lsum = -(y[e] * __logf(pc) + (1.f - y[e]) * log1pf(-pc));
    }
#pragma unroll
    for (int off = 32; off > 0; off >>= 1) lsum += __shfl_down(lsum, off, 64);
    if (lane == 0) wl[wid] = lsum;
    __syncthreads();
    if (threadIdx.x == 0) {
        float tt = wl[0] + wl[1] + wl[2] + wl[3];
        atomicAdd(&out[(size_t)N_NODES * N_NODES], tt * (1.f / N_EDGES));
    }
}

// ---------------------------------------------------------------- launcher
extern "C" void kernel_launch(void* const* d_in, const int* in_sizes, int n_in,
                              void* d_out, int out_size, void* d_ws, size_t ws_size,
                              hipStream_t stream) {
    const float* x          = (const float*)d_in[0];
    const float* edge_attr  = (const float*)d_in[1];
    const int*   edge_index = (const int*)d_in[2];
    const float* y          = (const float*)d_in[3];
    const float* node_emb_W = (const float*)d_in[4];
    const float* node_emb_b = (const float*)d_in[5];
    const float* edge_d_W   = (const float*)d_in[6];
    const float* edge_d_b   = (const float*)d_in[7];
    const float* edge_t_W   = (const float*)d_in[8];
    const float* edge_t_b   = (const float*)d_in[9];
    const float* eU_W = (const float*)d_in[10];
    const float* eU_b = (const float*)d_in[11];
    const float* eW_W = (const float*)d_in[12];
    const float* nU_W = (const float*)d_in[14];
    const float* nU_b = (const float*)d_in[15];
    const float* nV_W = (const float*)d_in[16];
    const float* nV_b = (const float*)d_in[17];
    const float* bn_e_g = (const float*)d_in[18];
    const float* bn_e_b = (const float*)d_in[19];
    const float* bn_n_g = (const float*)d_in[20];
    const float* bn_n_b = (const float*)d_in[21];
    const float* cls_W = (const float*)d_in[22];
    const float* cls_b = (const float*)d_in[23];

    const int* src = edge_index;
    const int* dst = edge_index + N_EDGES;

    float* ws     = (float*)d_ws;
    float* node   = ws;                  // NH
    float* nodeU  = node + NH;           // NH
    float* nodeV  = nodeU + NH;          // NH
    float* nodeUn = nodeV + NH;          // NH
    float* aggv   = nodeUn + NH;         // NH
    float* RE2    = aggv + NH;           // 2 x 32*608   <-- zero region start
    float* RN2    = RE2 + 2 * NREP * RSTRIDE;
    float* RS2    = RN2 + 2 * NREP * RSTRIDE;  // 2 x 32*304
    float* invS   = RS2 + 2 * NREP * SSTRIDE;  // 304
    bf16* node_bf = (bf16*)(invS + SSTRIDE);              // 2048*320
    bf16* edge_bf = node_bf + (size_t)NODE_ROWS_PAD * HP; // 32000*320
    bf16* gate_bf = edge_bf + (size_t)N_EDGES * HP;       // 32000*300 (not zeroed)
    bf16* Wt_all  = gate_bf + (size_t)N_EDGES * H;        // 120*102400
    int* csr_counts = (int*)(Wt_all + (size_t)120 * WMAT);
    int* csr_offs   = csr_counts + 2048;
    int* csr_woff   = csr_offs + 2048;
    int* csr_eidx   = csr_woff + 2048;
    int* csr_msrc   = csr_eidx + N_EDGES;

    float* out = (float*)d_out;

    // zero: out, [RE2 | RN2 | RS2 | invS | node_bf | edge_bf], csr_counts
    int zstats = 4 * NREP * RSTRIDE + 2 * NREP * SSTRIDE + SSTRIDE;
    int zlen = zstats + (NODE_ROWS_PAD * HP + N_EDGES * HP) / 2;
    zero_buf<<<(N_NODES * N_NODES + 1 + 255) / 256, 256, 0, stream>>>(out, N_NODES * N_NODES + 1);
    zero_buf<<<(zlen + 255) / 256, 256, 0, stream>>>(RE2, zlen);
    zero_buf<<<8, 256, 0, stream>>>((float*)csr_counts, 2048);

    convert_weights_t<<<12000, 256, 0, stream>>>(eU_W, eW_W, nU_W, nV_W, Wt_all);
    csr_hist<<<(N_EDGES + 255) / 256, 256, 0, stream>>>(dst, csr_counts);
    csr_scan<<<1, 256, 0, stream>>>(csr_counts, csr_offs, csr_woff);
    csr_scatter<<<(N_EDGES + 255) / 256, 256, 0, stream>>>(src, dst, csr_woff, csr_eidx, csr_msrc);
    node_embed<<<(NH + 255) / 256, 256, 0, stream>>>(x, node_emb_W, node_emb_b, node, node_bf);
    edge_embed<<<NEB, 256, 0, stream>>>(edge_attr, edge_d_W, edge_d_b,
                                        edge_t_W, edge_t_b, edge_bf, RS2);

    for (int l = 0; l < NLAYERS; ++l) {
        float* REc = RE2 + (size_t)(l & 1) * NREP * RSTRIDE;
        float* REo = RE2 + (size_t)((l + 1) & 1) * NREP * RSTRIDE;
        float* RNc = RN2 + (size_t)(l & 1) * NREP * RSTRIDE;
        float* RNo = RN2 + (size_t)((l + 1) & 1) * NREP * RSTRIDE;
        float* RScur = RS2 + (size_t)(l & 1) * NREP * SSTRIDE;
        float* RSnxt = RS2 + (size_t)((l + 1) & 1) * NREP * SSTRIDE;

        gemm_all<<<3505, 64, 0, stream>>>(node_bf, edge_bf, Wt_all,
                                          eU_b, nV_b, nU_b, l,
                                          nodeU, nodeV, nodeUn, gate_bf,
                                          RScur, RSnxt, invS);
        node_msg<<<NMB + NEB, 320, 0, stream>>>(edge_bf, nodeV, nodeUn,
                                                csr_offs, csr_eidx, csr_msrc,
                                                invS, RNc, aggv,
                                                gate_bf, nodeU, src, dst, REc);
        fused_final<<<NEB + NUB, 256, 0, stream>>>(edge_bf, gate_bf,
                                                   REc, REo, RNc, RNo, RSnxt,
                                                   bn_e_g + l * H, bn_e_b + l * H,
                                                   bn_n_g + l * H, bn_n_b + l * H,
                                                   node, node_bf, aggv);
    }

    classify_loss<<<500, 256, 0, stream>>>(edge_bf, cls_W, cls_b, src, dst, y, out);
}

// Round 12
// 3050.666 us; speedup vs baseline: 1.0618x; 1.0370x over previous
//
#include <hip/hip_runtime.h>
#include <hip/hip_bf16.h>
#include <math.h>

#define N_NODES 2000
#define N_EDGES 32000
#define H 300
#define CH 75             // H/4 float4 chunks per row
#define HP 320            // padded H for MFMA K/N
#define NLAYERS 30
#define NH (N_NODES * H)     // 600000
#define NODE_ROWS_PAD 2048
#define WMAT (HP * HP)
#define NREP 32              // stat replicas
#define RSTRIDE 608          // replica row stride (sum | sumsq at +304)
#define SSTRIDE 304
#define NEB 500              // edge-finalize blocks (32000/64)
#define NUB 147              // node_update blocks (1024 chunks each)

typedef short bf16x8 __attribute__((ext_vector_type(8)));
typedef float f32x4 __attribute__((ext_vector_type(4)));
typedef __hip_bfloat16 bf16;

__device__ __forceinline__ float sigm(float x) { return 1.f / (1.f + __expf(-x)); }

// ---------------------------------------------------------------- utilities
__global__ __launch_bounds__(256) void zero_buf(float* __restrict__ p, int n) {
    int i = blockIdx.x * blockDim.x + threadIdx.x;
    if (i < n) p[i] = 0.f;
}

// --------------------- weights -> bf16 transposed, LDS-tiled (coalesced both ways)
__global__ __launch_bounds__(256) void convert_weights_t(const float* __restrict__ eU,
                                                         const float* __restrict__ eW,
                                                         const float* __restrict__ nU,
                                                         const float* __restrict__ nV,
                                                         bf16* __restrict__ Wt) {
    __shared__ float tile[32][33];
    int b = blockIdx.x;                 // 120 mats x 100 tiles
    int m = b / 100;
    int rem = b % 100;
    int kt = rem / 10, nt = rem % 10;
    int k0 = kt * 32, n0 = nt * 32;
    int grp = m / NLAYERS, l = m % NLAYERS;
    const float* S = (grp == 0) ? eU : (grp == 1) ? eW : (grp == 2) ? nU : nV;
    const float* Sl = S + (size_t)l * H * H;
    int t = threadIdx.x;
    int tn = t & 31, tk = t >> 5;
#pragma unroll
    for (int p = 0; p < 4; ++p) {
        int k = tk + p * 8;
        int gk = k0 + k, gn = n0 + tn;
        tile[k][tn] = (gk < H && gn < H) ? Sl[(size_t)gk * H + gn] : 0.f;
    }
    __syncthreads();
    bf16* D = Wt + (size_t)m * WMAT;
    int tk2 = t & 31, tn2 = t >> 5;
#pragma unroll
    for (int p = 0; p < 4; ++p) {
        int n = tn2 + p * 8;
        D[(size_t)(n0 + n) * HP + k0 + tk2] = __float2bfloat16(tile[tk2][n]);
    }
}

// ---- eW weights repacked for LDS staging: WtK[l][ct4][kc][c][j] = Wt[30+l][(ct4*80+c)*HP + kc*8+j]
__global__ __launch_bounds__(256) void convert_wtk(const bf16* __restrict__ Wt,
                                                   bf16* __restrict__ WtK) {
    long long idx = (long long)blockIdx.x * 256 + threadIdx.x;
    if (idx >= 30LL * WMAT) return;
    int m = (int)(idx / WMAT);
    int rem = (int)(idx % WMAT);
    int ct4 = rem / 25600;
    int r2 = rem % 25600;
    int kc = r2 / 640;
    int r3 = r2 % 640;
    int c = r3 / 8, j = r3 % 8;
    WtK[idx] = Wt[(size_t)(30 + m) * WMAT + (size_t)(ct4 * 80 + c) * HP + kc * 8 + j];
}

// ------------------------------------------------------------- CSR by dst
__global__ __launch_bounds__(256) void csr_hist(const int* __restrict__ dst,
                                                int* __restrict__ counts) {
    int i = blockIdx.x * 256 + threadIdx.x;
    if (i < N_EDGES) atomicAdd(&counts[dst[i]], 1);
}

__global__ __launch_bounds__(256) void csr_scan(const int* __restrict__ counts,
                                                int* __restrict__ offs,
                                                int* __restrict__ woff) {
    __shared__ int part[256];
    int t = threadIdx.x;
    int base = t * 8;
    int local[8];
    int s = 0;
#pragma unroll
    for (int j = 0; j < 8; ++j) {
        int c = (base + j < N_NODES) ? counts[base + j] : 0;
        local[j] = s;
        s += c;
    }
    part[t] = s;
    __syncthreads();
    for (int off = 1; off < 256; off <<= 1) {
        int v = (t >= off) ? part[t - off] : 0;
        __syncthreads();
        part[t] += v;
        __syncthreads();
    }
    int pre = (t == 0) ? 0 : part[t - 1];
#pragma unroll
    for (int j = 0; j < 8; ++j) {
        int idx = base + j;
        if (idx < N_NODES) { int v = pre + local[j]; offs[idx] = v; woff[idx] = v; }
    }
    if (t == 255) offs[N_NODES] = part[255];
}

__global__ __launch_bounds__(256) void csr_scatter(const int* __restrict__ src,
                                                   const int* __restrict__ dst,
                                                   int* __restrict__ woff,
                                                   int* __restrict__ eidx,
                                                   int* __restrict__ msrc) {
    int i = blockIdx.x * 256 + threadIdx.x;
    if (i < N_EDGES) {
        int p = atomicAdd(&woff[dst[i]], 1);
        eidx[p] = i;
        msrc[p] = src[i];
    }
}

// ---------------------------------------------------------------- embeddings
__global__ __launch_bounds__(256) void node_embed(const float* __restrict__ x,
                                                  const float* __restrict__ W,
                                                  const float* __restrict__ b,
                                                  float* __restrict__ node,
                                                  bf16* __restrict__ node_bf) {
    int i = blockIdx.x * blockDim.x + threadIdx.x;
    if (i >= NH) return;
    int n = i / H, h = i % H;
    float acc = b[h];
#pragma unroll
    for (int k = 0; k < 4; ++k) acc += x[n * 4 + k] * W[k * H + h];
    node[i] = acc;
    node_bf[(size_t)n * HP + h] = __float2bfloat16(acc);
}

// edge embedding, bf16 only, col-chunk ownership; sigmoid colsum -> RS0
__global__ __launch_bounds__(256) void edge_embed(const float* __restrict__ ea,
                                                  const float* __restrict__ dW,
                                                  const float* __restrict__ db,
                                                  const float* __restrict__ tW,
                                                  const float* __restrict__ tb,
                                                  bf16* __restrict__ edge_bf,
                                                  float* __restrict__ RS0) {
    __shared__ float s_s[SSTRIDE];
    int t = threadIdx.x;
    for (int i = t; i < SSTRIDE; i += 256) s_s[i] = 0.f;
    __syncthreads();
    int hc = t % 80, rgrp = t / 80;
    int col0 = hc * 4;
    float ss[4] = {0.f, 0.f, 0.f, 0.f};
    if (hc < CH && rgrp < 3) {
        float wv[4], bv[4];
#pragma unroll
        for (int j = 0; j < 4; ++j) {
            int col = col0 + j;
            wv[j] = (col < 150) ? dW[col] : tW[col - 150];
            bv[j] = (col < 150) ? db[col] : tb[col - 150];
        }
        int e0 = blockIdx.x * 64;
        for (int r = rgrp; r < 64; r += 3) {
            int e = e0 + r;
            float d = ea[2 * e], tt = ea[2 * e + 1];
            union { ushort4 u; bf16 b[4]; } ob;
#pragma unroll
            for (int j = 0; j < 4; ++j) {
                int col = col0 + j;
                float v = ((col < 150) ? d : tt) * wv[j] + bv[j];
                ob.b[j] = __float2bfloat16(v);
                ss[j] += sigm(__bfloat162float(ob.b[j]));
            }
            *(ushort4*)(edge_bf + (size_t)e * HP + col0) = ob.u;
        }
#pragma unroll
        for (int j = 0; j < 4; ++j) atomicAdd(&s_s[col0 + j], ss[j]);
    }
    __syncthreads();
    float* rs = RS0 + (size_t)(blockIdx.x & (NREP - 1)) * SSTRIDE;
    for (int i = t; i < H; i += 256) atomicAdd(&rs[i], s_s[i]);
}

// ---- K1: node GEMMs (1500 one-wave blocks) + 5 blocks: invS from RScur, zero RSnxt
__global__ __launch_bounds__(64) void gemm_node(const bf16* __restrict__ node_bf,
                                                const bf16* __restrict__ Wt_all,
                                                const float* __restrict__ eU_b,
                                                const float* __restrict__ nV_b,
                                                const float* __restrict__ nU_b,
                                                int layer,
                                                float* __restrict__ nodeU,
                                                float* __restrict__ nodeV,
                                                float* __restrict__ nodeUn,
                                                const float* __restrict__ RScur,
                                                float* __restrict__ RSnxt,
                                                float* __restrict__ invS) {
    int bx = blockIdx.x;
    int lane = threadIdx.x;
    if (bx >= 1500) {
        int idx = bx - 1500;               // 0..4
        int c = idx * 64 + lane;           // 0..319
        if (c < H) {
            float ssr = 0.f;
#pragma unroll 8
            for (int r = 0; r < NREP; ++r) ssr += RScur[r * SSTRIDE + c];
            invS[c] = 1.f / (ssr + 1e-20f);
        }
        for (int i = idx * 64 + lane; i < NREP * SSTRIDE; i += 320) RSnxt[i] = 0.f;
        return;
    }
    int mat = bx / 500;
    int rem = bx % 500;
    int rt0 = rem >> 2, ct4 = rem & 3;
    const bf16* Bt; const float* bias; float* out;
    if (mat == 0)      { Bt = Wt_all + (size_t)(0 + layer) * WMAT;  bias = eU_b + layer * H; out = nodeU; }
    else if (mat == 1) { Bt = Wt_all + (size_t)(90 + layer) * WMAT; bias = nV_b + layer * H; out = nodeV; }
    else               { Bt = Wt_all + (size_t)(60 + layer) * WMAT; bias = nU_b + layer * H; out = nodeUn; }
    int row0 = rt0 * 16, c0 = ct4 * 80;
    int rlo = lane & 15, khi = lane >> 4;
    f32x4 acc[5];
#pragma unroll
    for (int ct = 0; ct < 5; ++ct) acc[ct] = (f32x4)0.f;
#pragma unroll 2
    for (int ks = 0; ks < 10; ++ks) {
        int kk = ks * 32 + khi * 8;
        bf16x8 a, b[5];
        a = *(const bf16x8*)(node_bf + (size_t)(row0 + rlo) * HP + kk);
#pragma unroll
        for (int ct = 0; ct < 5; ++ct)
            b[ct] = *(const bf16x8*)(Bt + (size_t)(c0 + ct * 16 + rlo) * HP + kk);
#pragma unroll
        for (int ct = 0; ct < 5; ++ct)
            acc[ct] = __builtin_amdgcn_mfma_f32_16x16x32_bf16(a, b[ct], acc[ct], 0, 0, 0);
    }
    int rhi = lane >> 4;
#pragma unroll
    for (int ct = 0; ct < 5; ++ct) {
        int col = c0 + ct * 16 + rlo;
        if (col >= H) continue;
        float bv = bias[col];
#pragma unroll
        for (int j = 0; j < 4; ++j) {
            int r = row0 + rhi * 4 + j;
            out[(size_t)r * H + col] = acc[ct][j] + bv;
        }
    }
}

// ------ K2: edge gate GEMM, 1000 blocks x 4 waves, 128r x 80c, LDS-staged B
__global__ __launch_bounds__(256) void gemm_edge(const bf16* __restrict__ edge_bf,
                                                 const bf16* __restrict__ WtK_l,
                                                 const float* __restrict__ nodeU,
                                                 const int* __restrict__ src,
                                                 const int* __restrict__ dst,
                                                 bf16* __restrict__ gate_bf,
                                                 float* __restrict__ REc) {
    __shared__ bf16 Bs[25600];             // 50 KB: [40 kc][80 col][8]
    int tid = threadIdx.x;
    int bx = blockIdx.x;                   // 0..999
    int wave = tid >> 6, lane = tid & 63;
    int row0 = (bx >> 2) * 128 + wave * 32;
    int c0 = (bx & 3) * 80;

    // stage B tile (coalesced: WtK is already in [kc][col][8] order per col-tile)
    const uint4* s4 = (const uint4*)(WtK_l + (size_t)(bx & 3) * 25600);
    uint4* d4 = (uint4*)Bs;
    for (int i = tid; i < 3200; i += 256) d4[i] = s4[i];
    __syncthreads();

    int rlo = lane & 15, khi = lane >> 4;
    f32x4 acc[2][5];
#pragma unroll
    for (int rt = 0; rt < 2; ++rt)
#pragma unroll
        for (int ct = 0; ct < 5; ++ct) acc[rt][ct] = (f32x4)0.f;
#pragma unroll 2
    for (int ks = 0; ks < 10; ++ks) {
        int kk = ks * 32 + khi * 8;
        int kcb = (ks * 4 + khi) * 80;     // LDS row base (in bf16x8 units)
        bf16x8 a[2], b[5];
#pragma unroll
        for (int rt = 0; rt < 2; ++rt)
            a[rt] = *(const bf16x8*)(edge_bf + (size_t)(row0 + rt * 16 + rlo) * HP + kk);
#pragma unroll
        for (int ct = 0; ct < 5; ++ct)
            b[ct] = *(const bf16x8*)(Bs + (size_t)(kcb + ct * 16 + rlo) * 8);
#pragma unroll
        for (int rt = 0; rt < 2; ++rt)
#pragma unroll
            for (int ct = 0; ct < 5; ++ct)
                acc[rt][ct] = __builtin_amdgcn_mfma_f32_16x16x32_bf16(a[rt], b[ct], acc[rt][ct], 0, 0, 0);
    }
    int rhi = lane >> 4;
    float csum[5], csq[5];
#pragma unroll
    for (int ct = 0; ct < 5; ++ct) { csum[ct] = 0.f; csq[ct] = 0.f; }
#pragma unroll
    for (int rt = 0; rt < 2; ++rt)
#pragma unroll
        for (int j = 0; j < 4; ++j) {
            int r = row0 + rt * 16 + rhi * 4 + j;
            int se = src[r], de = dst[r];
#pragma unroll
            for (int ct = 0; ct < 5; ++ct) {
                int col = c0 + ct * 16 + rlo;
                if (col < H) {
                    float g = acc[rt][ct][j] + nodeU[(size_t)se * H + col] + nodeU[(size_t)de * H + col];
                    gate_bf[(size_t)r * H + col] = __float2bfloat16(g);
                    csum[ct] += g;
                    csq[ct] += g * g;
                }
            }
        }
#pragma unroll
    for (int ct = 0; ct < 5; ++ct) {
        csum[ct] += __shfl_xor(csum[ct], 16, 64);
        csum[ct] += __shfl_xor(csum[ct], 32, 64);
        csq[ct]  += __shfl_xor(csq[ct], 16, 64);
        csq[ct]  += __shfl_xor(csq[ct], 32, 64);
    }
    if (khi == 0) {
        float* re = REc + (size_t)(bx & (NREP - 1)) * RSTRIDE;
#pragma unroll
        for (int ct = 0; ct < 5; ++ct) {
            int col = c0 + ct * 16 + rlo;
            if (col < H) {
                atomicAdd(&re[col], csum[ct]);
                atomicAdd(&re[SSTRIDE + col], csq[ct]);
            }
        }
    }
}

// ------------- K3: CSR gather (2 nodes/block), uses precomputed invS
__global__ __launch_bounds__(320) void node_msg(const bf16* __restrict__ edge_bf,
                                                const float* __restrict__ nodeV,
                                                const float* __restrict__ nodeUn,
                                                const int* __restrict__ offs,
                                                const int* __restrict__ eidx,
                                                const int* __restrict__ msrc,
                                                const float* __restrict__ invS,
                                                float* __restrict__ RN,
                                                float* __restrict__ aggv) {
    int t = threadIdx.x;
    int bx = blockIdx.x;
    if (t >= H) return;
    float inv = invS[t];
    float st1 = 0.f, st2 = 0.f;
    int n0 = bx * 2;
#pragma unroll
    for (int k = 0; k < 2; ++k) {
        int n = n0 + k;
        int beg = offs[n], end = offs[n + 1];
        float a = 0.f;
        for (int i = beg; i < end; ++i) {
            int e = eidx[i];
            int s = msrc[i];
            a += sigm(__bfloat162float(edge_bf[(size_t)e * HP + t])) * nodeV[(size_t)s * H + t];
        }
        float v = nodeUn[(size_t)n * H + t] + a * inv;
        aggv[(size_t)n * H + t] = v;
        st1 += v; st2 += v * v;
    }
    float* rn = RN + (size_t)(bx & (NREP - 1)) * RSTRIDE;
    atomicAdd(&rn[t], st1);
    atomicAdd(&rn[SSTRIDE + t], st2);
}

// ------------- K4: edge_finalize (bx<NEB) || node_update (bx>=NEB), bf16 residual
__global__ __launch_bounds__(256) void fused_final(bf16* __restrict__ edge_bf,
                                                   const bf16* __restrict__ gate_bf,
                                                   const float* __restrict__ REc,
                                                   float* __restrict__ REo,
                                                   const float* __restrict__ RNc,
                                                   float* __restrict__ RNo,
                                                   float* __restrict__ RSnext,
                                                   const float* __restrict__ eg,
                                                   const float* __restrict__ ebt,
                                                   const float* __restrict__ ng,
                                                   const float* __restrict__ nbt,
                                                   float* __restrict__ node,
                                                   bf16* __restrict__ node_bf,
                                                   const float* __restrict__ aggv) {
    __shared__ float sc_s[SSTRIDE], of_s[SSTRIDE], s_s[SSTRIDE];
    int bx = blockIdx.x, t = threadIdx.x;
    if (bx < NEB) {
        const float invE = 1.f / N_EDGES;
        for (int i = t; i < SSTRIDE; i += 256) {
            s_s[i] = 0.f;
            if (i < H) {
                float gs = 0.f, gq = 0.f;
#pragma unroll 8
                for (int r = 0; r < NREP; ++r) {
                    gs += REc[r * RSTRIDE + i];
                    gq += REc[r * RSTRIDE + SSTRIDE + i];
                }
                float mean = gs * invE;
                float var = fmaxf(gq * invE - mean * mean, 0.f);
                float rstd = rsqrtf(var + 1e-5f);
                float sc = rstd * eg[i];
                sc_s[i] = sc;
                of_s[i] = ebt[i] - mean * sc;
            }
        }
        __syncthreads();
        int hc = t % 80, rgrp = t / 80;
        bool act = (hc < CH) && (rgrp < 3);
        float ss[4] = {0.f, 0.f, 0.f, 0.f};
        int col0 = hc * 4;
        if (act) {
            float sc[4], of[4];
#pragma unroll
            for (int j = 0; j < 4; ++j) { sc[j] = sc_s[col0 + j]; of[j] = of_s[col0 + j]; }
            int e0 = bx * 64;
            for (int r = rgrp; r < 64; r += 3) {
                int e = e0 + r;
                union { ushort4 u; bf16 b[4]; } eb, gv, ob;
                eb.u = *(const ushort4*)(edge_bf + (size_t)e * HP + col0);
                gv.u = *(const ushort4*)(gate_bf + (size_t)e * H + col0);
#pragma unroll
                for (int j = 0; j < 4; ++j) {
                    float g = __bfloat162float(gv.b[j]);
                    float val = fmaxf(fmaf(g, sc[j], of[j]), 0.f);
                    float nv = __bfloat162float(eb.b[j]) + val;
                    ob.b[j] = __float2bfloat16(nv);
                    ss[j] += sigm(__bfloat162float(ob.b[j]));
                }
                *(ushort4*)(edge_bf + (size_t)e * HP + col0) = ob.u;
            }
#pragma unroll
            for (int j = 0; j < 4; ++j) atomicAdd(&s_s[col0 + j], ss[j]);
        }
        __syncthreads();
        float* rs = RSnext + (size_t)(bx & (NREP - 1)) * SSTRIDE;
        for (int i = t; i < H; i += 256) atomicAdd(&rs[i], s_s[i]);
    } else {
        int idx = bx - NEB;                // 0..NUB-1
        if (idx < NREP) {
            for (int i = t; i < RSTRIDE; i += 256) {
                REo[(size_t)idx * RSTRIDE + i] = 0.f;
                RNo[(size_t)idx * RSTRIDE + i] = 0.f;
            }
        }
        const float invN = 1.f / N_NODES;
        for (int i = t; i < H; i += 256) {
            float ns = 0.f, nq = 0.f;
#pragma unroll 8
            for (int r = 0; r < NREP; ++r) {
                ns += RNc[r * RSTRIDE + i];
                nq += RNc[r * RSTRIDE + SSTRIDE + i];
            }
            float mean = ns * invN;
            float var = fmaxf(nq * invN - mean * mean, 0.f);
            float rstd = rsqrtf(var + 1e-5f);
            float sc = rstd * ng[i];
            sc_s[i] = sc;
            of_s[i] = nbt[i] - mean * sc;
        }
        __syncthreads();
#pragma unroll
        for (int it = 0; it < 4; ++it) {
            int c = idx * 1024 + it * 256 + t;
            if (c >= NH / 4) break;
            int n = c / CH, hc = c % CH, col0 = hc * 4;
            float4 v4 = ((const float4*)aggv)[c];
            float4 nd = ((const float4*)node)[c];
            const float* v4p = (const float*)&v4;
            const float* ndp = (const float*)&nd;
            union { ushort4 u; bf16 b[4]; } ob;
            float outv[4];
#pragma unroll
            for (int j = 0; j < 4; ++j) {
                float g = fmaf(v4p[j], sc_s[col0 + j], of_s[col0 + j]);
                outv[j] = ndp[j] + fmaxf(g, 0.f);
                ob.b[j] = __float2bfloat16(outv[j]);
            }
            ((float4*)node)[c] = make_float4(outv[0], outv[1], outv[2], outv[3]);
            *(ushort4*)(node_bf + (size_t)n * HP + col0) = ob.u;
        }
    }
}

// ----------------- classifier + loss: 4 lanes/edge, vectorized, clsW in regs
__global__ __launch_bounds__(256) void classify_loss(const bf16* __restrict__ edge_bf,
                                                     const float* __restrict__ clsW,
                                                     const float* __restrict__ clsb,
                                                     const int* __restrict__ src,
                                                     const int* __restrict__ dst,
                                                     const float* __restrict__ y,
                                                     float* __restrict__ out) {
    __shared__ float wl[4];
    int lane = threadIdx.x & 63;
    int wid = threadIdx.x >> 6;
    int quad = lane >> 2;              // edge index within 16-edge group
    int ql = lane & 3;                 // 80-col chunk
    float w[80];
#pragma unroll
    for (int j = 0; j < 80; ++j) {
        int col = ql * 80 + j;
        w[j] = (col < H) ? clsW[col] : 0.f;
    }
    int g = blockIdx.x * 4 + wid;      // 0..1999, one 16-edge group per wave
    int e = g * 16 + quad;
    const bf16* row = edge_bf + (size_t)e * HP + ql * 80;   // pad cols are 0
    float acc = 0.f;
#pragma unroll
    for (int v = 0; v < 10; ++v) {
        bf16x8 bv = *(const bf16x8*)(row + v * 8);
#pragma unroll
        for (int j = 0; j < 8; ++j)
            acc += __bfloat162float(((const bf16*)&bv)[j]) * w[v * 8 + j];
    }
    acc += __shfl_xor(acc, 1, 64);
    acc += __shfl_xor(acc, 2, 64);
    float lsum = 0.f;
    if (ql == 0) {
        float z = acc + clsb[0];
        float p = 1.f / (1.f + __expf(-z));
        atomicAdd(&out[(size_t)src[e] * N_NODES + dst[e]], p);
        float pc = fminf(fmaxf(p, 1e-7f), 1.f - 1e-7f);
        lsum = -(y[e] * __logf(pc) + (1.f - y[e]) * log1pf(-pc));
    }
#pragma unroll
    for (int off = 32; off > 0; off >>= 1) lsum += __shfl_down(lsum, off, 64);
    if (lane == 0) wl[wid] = lsum;
    __syncthreads();
    if (threadIdx.x == 0) {
        float tt = wl[0] + wl[1] + wl[2] + wl[3];
        atomicAdd(&out[(size_t)N_NODES * N_NODES], tt * (1.f / N_EDGES));
    }
}

// ---------------------------------------------------------------- launcher
extern "C" void kernel_launch(void* const* d_in, const int* in_sizes, int n_in,
                              void* d_out, int out_size, void* d_ws, size_t ws_size,
                              hipStream_t stream) {
    const float* x          = (const float*)d_in[0];
    const float* edge_attr  = (const float*)d_in[1];
    const int*   edge_index = (const int*)d_in[2];
    const float* y          = (const float*)d_in[3];
    const float* node_emb_W = (const float*)d_in[4];
    const float* node_emb_b = (const float*)d_in[5];
    const float* edge_d_W   = (const float*)d_in[6];
    const float* edge_d_b   = (const float*)d_in[7];
    const float* edge_t_W   = (const float*)d_in[8];
    const float* edge_t_b   = (const float*)d_in[9];
    const float* eU_W = (const float*)d_in[10];
    const float* eU_b = (const float*)d_in[11];
    const float* eW_W = (const float*)d_in[12];
    const float* nU_W = (const float*)d_in[14];
    const float* nU_b = (const float*)d_in[15];
    const float* nV_W = (const float*)d_in[16];
    const float* nV_b = (const float*)d_in[17];
    const float* bn_e_g = (const float*)d_in[18];
    const float* bn_e_b = (const float*)d_in[19];
    const float* bn_n_g = (const float*)d_in[20];
    const float* bn_n_b = (const float*)d_in[21];
    const float* cls_W = (const float*)d_in[22];
    const float* cls_b = (const float*)d_in[23];

    const int* src = edge_index;
    const int* dst = edge_index + N_EDGES;

    float* ws     = (float*)d_ws;
    float* node   = ws;                  // NH
    float* nodeU  = node + NH;           // NH
    float* nodeV  = nodeU + NH;          // NH
    float* nodeUn = nodeV + NH;          // NH
    float* aggv   = nodeUn + NH;         // NH
    float* RE2    = aggv + NH;           // 2 x 32*608   <-- zero region start
    float* RN2    = RE2 + 2 * NREP * RSTRIDE;
    float* RS2    = RN2 + 2 * NREP * RSTRIDE;  // 2 x 32*304
    float* invS   = RS2 + 2 * NREP * SSTRIDE;  // 304
    bf16* node_bf = (bf16*)(invS + SSTRIDE);              // 2048*320
    bf16* edge_bf = node_bf + (size_t)NODE_ROWS_PAD * HP; // 32000*320
    bf16* gate_bf = edge_bf + (size_t)N_EDGES * HP;       // 32000*300 (not zeroed)
    bf16* Wt_all  = gate_bf + (size_t)N_EDGES * H;        // 120*102400
    bf16* WtK_all = Wt_all + (size_t)120 * WMAT;          // 30*102400
    int* csr_counts = (int*)(WtK_all + (size_t)30 * WMAT);
    int* csr_offs   = csr_counts + 2048;
    int* csr_woff   = csr_offs + 2048;
    int* csr_eidx   = csr_woff + 2048;
    int* csr_msrc   = csr_eidx + N_EDGES;

    float* out = (float*)d_out;

    // zero: out, [RE2 | RN2 | RS2 | invS | node_bf | edge_bf], csr_counts
    int zstats = 4 * NREP * RSTRIDE + 2 * NREP * SSTRIDE + SSTRIDE;
    int zlen = zstats + (NODE_ROWS_PAD * HP + N_EDGES * HP) / 2;
    zero_buf<<<(N_NODES * N_NODES + 1 + 255) / 256, 256, 0, stream>>>(out, N_NODES * N_NODES + 1);
    zero_buf<<<(zlen + 255) / 256, 256, 0, stream>>>(RE2, zlen);
    zero_buf<<<8, 256, 0, stream>>>((float*)csr_counts, 2048);

    convert_weights_t<<<12000, 256, 0, stream>>>(eU_W, eW_W, nU_W, nV_W, Wt_all);
    convert_wtk<<<(30 * WMAT + 255) / 256, 256, 0, stream>>>(Wt_all, WtK_all);
    csr_hist<<<(N_EDGES + 255) / 256, 256, 0, stream>>>(dst, csr_counts);
    csr_scan<<<1, 256, 0, stream>>>(csr_counts, csr_offs, csr_woff);
    csr_scatter<<<(N_EDGES + 255) / 256, 256, 0, stream>>>(src, dst, csr_woff, csr_eidx, csr_msrc);
    node_embed<<<(NH + 255) / 256, 256, 0, stream>>>(x, node_emb_W, node_emb_b, node, node_bf);
    edge_embed<<<NEB, 256, 0, stream>>>(edge_attr, edge_d_W, edge_d_b,
                                        edge_t_W, edge_t_b, edge_bf, RS2);

    for (int l = 0; l < NLAYERS; ++l) {
        float* REc = RE2 + (size_t)(l & 1) * NREP * RSTRIDE;
        float* REo = RE2 + (size_t)((l + 1) & 1) * NREP * RSTRIDE;
        float* RNc = RN2 + (size_t)(l & 1) * NREP * RSTRIDE;
        float* RNo = RN2 + (size_t)((l + 1) & 1) * NREP * RSTRIDE;
        float* RScur = RS2 + (size_t)(l & 1) * NREP * SSTRIDE;
        float* RSnxt = RS2 + (size_t)((l + 1) & 1) * NREP * SSTRIDE;
        const bf16* WtK_l = WtK_all + (size_t)l * WMAT;

        gemm_node<<<1505, 64, 0, stream>>>(node_bf, Wt_all, eU_b, nV_b, nU_b, l,
                                           nodeU, nodeV, nodeUn, RScur, RSnxt, invS);
        gemm_edge<<<1000, 256, 0, stream>>>(edge_bf, WtK_l, nodeU, src, dst,
                                            gate_bf, REc);
        node_msg<<<N_NODES / 2, 320, 0, stream>>>(edge_bf, nodeV, nodeUn,
                                                  csr_offs, csr_eidx, csr_msrc,
                                                  invS, RNc, aggv);
        fused_final<<<NEB + NUB, 256, 0, stream>>>(edge_bf, gate_bf,
                                                   REc, REo, RNc, RNo, RSnxt,
                                                   bn_e_g + l * H, bn_e_b + l * H,
                                                   bn_n_g + l * H, bn_n_b + l * H,
                                                   node, node_bf, aggv);
    }

    classify_loss<<<500, 256, 0, stream>>>(edge_bf, cls_W, cls_b, src, dst, y, out);
}

// Round 13
// 3017.583 us; speedup vs baseline: 1.0735x; 1.0110x over previous
//
#include <hip/hip_runtime.h>
#include <hip/hip_bf16.h>
#include <math.h>

#define N_NODES 2000
#define N_EDGES 32000
#define H 300
#define CH 75             // H/4 float4 chunks per row
#define HP 320            // padded H for MFMA K/N
#define NLAYERS 30
#define NH (N_NODES * H)     // 600000
#define NODE_ROWS_PAD 2048
#define WMAT (HP * HP)
#define NREP 32              // stat replicas
#define RSTRIDE 608          // replica row stride (sum | sumsq at +304)
#define SSTRIDE 304
#define NEB 500              // edge-finalize blocks (32000/64)
#define NUB 147              // node_update blocks (1024 chunks each)

typedef short bf16x8 __attribute__((ext_vector_type(8)));
typedef float f32x4 __attribute__((ext_vector_type(4)));
typedef __hip_bfloat16 bf16;

__device__ __forceinline__ float sigm(float x) { return 1.f / (1.f + __expf(-x)); }

// ---------------------------------------------------------------- utilities
__global__ __launch_bounds__(256) void zero_buf(float* __restrict__ p, int n) {
    int i = blockIdx.x * blockDim.x + threadIdx.x;
    if (i < n) p[i] = 0.f;
}

// --------------------- weights -> bf16 transposed, LDS-tiled (coalesced both ways)
__global__ __launch_bounds__(256) void convert_weights_t(const float* __restrict__ eU,
                                                         const float* __restrict__ eW,
                                                         const float* __restrict__ nU,
                                                         const float* __restrict__ nV,
                                                         bf16* __restrict__ Wt) {
    __shared__ float tile[32][33];
    int b = blockIdx.x;                 // 120 mats x 100 tiles
    int m = b / 100;
    int rem = b % 100;
    int kt = rem / 10, nt = rem % 10;
    int k0 = kt * 32, n0 = nt * 32;
    int grp = m / NLAYERS, l = m % NLAYERS;
    const float* S = (grp == 0) ? eU : (grp == 1) ? eW : (grp == 2) ? nU : nV;
    const float* Sl = S + (size_t)l * H * H;
    int t = threadIdx.x;
    int tn = t & 31, tk = t >> 5;
#pragma unroll
    for (int p = 0; p < 4; ++p) {
        int k = tk + p * 8;
        int gk = k0 + k, gn = n0 + tn;
        tile[k][tn] = (gk < H && gn < H) ? Sl[(size_t)gk * H + gn] : 0.f;
    }
    __syncthreads();
    bf16* D = Wt + (size_t)m * WMAT;
    int tk2 = t & 31, tn2 = t >> 5;
#pragma unroll
    for (int p = 0; p < 4; ++p) {
        int n = tn2 + p * 8;
        D[(size_t)(n0 + n) * HP + k0 + tk2] = __float2bfloat16(tile[tk2][n]);
    }
}

// ------------------------------------------------------------- CSR by dst
__global__ __launch_bounds__(256) void csr_hist(const int* __restrict__ dst,
                                                int* __restrict__ counts) {
    int i = blockIdx.x * 256 + threadIdx.x;
    if (i < N_EDGES) atomicAdd(&counts[dst[i]], 1);
}

__global__ __launch_bounds__(256) void csr_scan(const int* __restrict__ counts,
                                                int* __restrict__ offs,
                                                int* __restrict__ woff) {
    __shared__ int part[256];
    int t = threadIdx.x;
    int base = t * 8;
    int local[8];
    int s = 0;
#pragma unroll
    for (int j = 0; j < 8; ++j) {
        int c = (base + j < N_NODES) ? counts[base + j] : 0;
        local[j] = s;
        s += c;
    }
    part[t] = s;
    __syncthreads();
    for (int off = 1; off < 256; off <<= 1) {
        int v = (t >= off) ? part[t - off] : 0;
        __syncthreads();
        part[t] += v;
        __syncthreads();
    }
    int pre = (t == 0) ? 0 : part[t - 1];
#pragma unroll
    for (int j = 0; j < 8; ++j) {
        int idx = base + j;
        if (idx < N_NODES) { int v = pre + local[j]; offs[idx] = v; woff[idx] = v; }
    }
    if (t == 255) offs[N_NODES] = part[255];
}

__global__ __launch_bounds__(256) void csr_scatter(const int* __restrict__ src,
                                                   const int* __restrict__ dst,
                                                   int* __restrict__ woff,
                                                   int* __restrict__ eidx,
                                                   int* __restrict__ msrc) {
    int i = blockIdx.x * 256 + threadIdx.x;
    if (i < N_EDGES) {
        int p = atomicAdd(&woff[dst[i]], 1);
        eidx[p] = i;
        msrc[p] = src[i];
    }
}

// ---------------------------------------------------------------- embeddings
__global__ __launch_bounds__(256) void node_embed(const float* __restrict__ x,
                                                  const float* __restrict__ W,
                                                  const float* __restrict__ b,
                                                  float* __restrict__ node,
                                                  bf16* __restrict__ node_bf) {
    int i = blockIdx.x * blockDim.x + threadIdx.x;
    if (i >= NH) return;
    int n = i / H, h = i % H;
    float acc = b[h];
#pragma unroll
    for (int k = 0; k < 4; ++k) acc += x[n * 4 + k] * W[k * H + h];
    node[i] = acc;
    node_bf[(size_t)n * HP + h] = __float2bfloat16(acc);
}

// edge embedding, bf16 only, col-chunk ownership; sigmoid colsum -> RS0
__global__ __launch_bounds__(256) void edge_embed(const float* __restrict__ ea,
                                                  const float* __restrict__ dW,
                                                  const float* __restrict__ db,
                                                  const float* __restrict__ tW,
                                                  const float* __restrict__ tb,
                                                  bf16* __restrict__ edge_bf,
                                                  float* __restrict__ RS0) {
    __shared__ float s_s[SSTRIDE];
    int t = threadIdx.x;
    for (int i = t; i < SSTRIDE; i += 256) s_s[i] = 0.f;
    __syncthreads();
    int hc = t % 80, rgrp = t / 80;
    int col0 = hc * 4;
    float ss[4] = {0.f, 0.f, 0.f, 0.f};
    if (hc < CH && rgrp < 3) {
        float wv[4], bv[4];
#pragma unroll
        for (int j = 0; j < 4; ++j) {
            int col = col0 + j;
            wv[j] = (col < 150) ? dW[col] : tW[col - 150];
            bv[j] = (col < 150) ? db[col] : tb[col - 150];
        }
        int e0 = blockIdx.x * 64;
        for (int r = rgrp; r < 64; r += 3) {
            int e = e0 + r;
            float d = ea[2 * e], tt = ea[2 * e + 1];
            union { ushort4 u; bf16 b[4]; } ob;
#pragma unroll
            for (int j = 0; j < 4; ++j) {
                int col = col0 + j;
                float v = ((col < 150) ? d : tt) * wv[j] + bv[j];
                ob.b[j] = __float2bfloat16(v);
                ss[j] += sigm(__bfloat162float(ob.b[j]));
            }
            *(ushort4*)(edge_bf + (size_t)e * HP + col0) = ob.u;
        }
#pragma unroll
        for (int j = 0; j < 4; ++j) atomicAdd(&s_s[col0 + j], ss[j]);
    }
    __syncthreads();
    float* rs = RS0 + (size_t)(blockIdx.x & (NREP - 1)) * SSTRIDE;
    for (int i = t; i < H; i += 256) atomicAdd(&rs[i], s_s[i]);
}

// ---- K1: node GEMMs (1500 one-wave blocks) + 5 blocks: invS from RScur, zero RSnxt
__global__ __launch_bounds__(64) void gemm_node(const bf16* __restrict__ node_bf,
                                                const bf16* __restrict__ Wt_all,
                                                const float* __restrict__ eU_b,
                                                const float* __restrict__ nV_b,
                                                const float* __restrict__ nU_b,
                                                int layer,
                                                float* __restrict__ nodeU,
                                                float* __restrict__ nodeV,
                                                float* __restrict__ nodeUn,
                                                const float* __restrict__ RScur,
                                                float* __restrict__ RSnxt,
                                                float* __restrict__ invS) {
    int bx = blockIdx.x;
    int lane = threadIdx.x;
    if (bx >= 1500) {
        int idx = bx - 1500;               // 0..4
        int c = idx * 64 + lane;           // 0..319
        if (c < H) {
            float ssr = 0.f;
#pragma unroll 8
            for (int r = 0; r < NREP; ++r) ssr += RScur[r * SSTRIDE + c];
            invS[c] = 1.f / (ssr + 1e-20f);
        }
        for (int i = idx * 64 + lane; i < NREP * SSTRIDE; i += 320) RSnxt[i] = 0.f;
        return;
    }
    int mat = bx / 500;
    int rem = bx % 500;
    int rt0 = rem >> 2, ct4 = rem & 3;
    const bf16* Bt; const float* bias; float* out;
    if (mat == 0)      { Bt = Wt_all + (size_t)(0 + layer) * WMAT;  bias = eU_b + layer * H; out = nodeU; }
    else if (mat == 1) { Bt = Wt_all + (size_t)(90 + layer) * WMAT; bias = nV_b + layer * H; out = nodeV; }
    else               { Bt = Wt_all + (size_t)(60 + layer) * WMAT; bias = nU_b + layer * H; out = nodeUn; }
    int row0 = rt0 * 16, c0 = ct4 * 80;
    int rlo = lane & 15, khi = lane >> 4;
    f32x4 acc[5];
#pragma unroll
    for (int ct = 0; ct < 5; ++ct) acc[ct] = (f32x4)0.f;
#pragma unroll 2
    for (int ks = 0; ks < 10; ++ks) {
        int kk = ks * 32 + khi * 8;
        bf16x8 a, b[5];
        a = *(const bf16x8*)(node_bf + (size_t)(row0 + rlo) * HP + kk);
#pragma unroll
        for (int ct = 0; ct < 5; ++ct)
            b[ct] = *(const bf16x8*)(Bt + (size_t)(c0 + ct * 16 + rlo) * HP + kk);
#pragma unroll
        for (int ct = 0; ct < 5; ++ct)
            acc[ct] = __builtin_amdgcn_mfma_f32_16x16x32_bf16(a, b[ct], acc[ct], 0, 0, 0);
    }
    int rhi = lane >> 4;
#pragma unroll
    for (int ct = 0; ct < 5; ++ct) {
        int col = c0 + ct * 16 + rlo;
        if (col >= H) continue;
        float bv = bias[col];
#pragma unroll
        for (int j = 0; j < 4; ++j) {
            int r = row0 + rhi * 4 + j;
            out[(size_t)r * H + col] = acc[ct][j] + bv;
        }
    }
}

// ------ K2: edge gate GEMM: 1000 blocks x 4 waves, block = 32 edges x 320 cols.
// A (32x320, 20KB) staged ONCE in LDS (contiguous span, coalesced), XOR-swizzled.
// B from global (L2-hot). Wave w owns cols w*80..+80.
__global__ __launch_bounds__(256) void gemm_edge(const bf16* __restrict__ edge_bf,
                                                 const bf16* __restrict__ Bt,
                                                 const float* __restrict__ nodeU,
                                                 const int* __restrict__ src,
                                                 const int* __restrict__ dst,
                                                 bf16* __restrict__ gate_bf,
                                                 float* __restrict__ REc) {
    __shared__ bf16 smA[32 * 320];         // 20 KB
    int tid = threadIdx.x;
    int bx = blockIdx.x;                   // 0..999
    int wave = tid >> 6, lane = tid & 63;
    int row0 = bx * 32;
    int c0 = wave * 80;

    // stage A: 1280 uint4 chunks, fully coalesced (20480B contiguous)
    const uint4* Ag = (const uint4*)(edge_bf + (size_t)row0 * HP);
#pragma unroll
    for (int it = 0; it < 5; ++it) {
        int cid = it * 256 + tid;          // 0..1279
        int row = cid / 40, ch = cid % 40;
        uint4 v = Ag[cid];
        *(uint4*)(smA + row * 320 + ((ch ^ (row & 7)) << 3)) = v;
    }
    __syncthreads();

    int rlo = lane & 15, khi = lane >> 4;
    f32x4 acc[2][5];
#pragma unroll
    for (int rt = 0; rt < 2; ++rt)
#pragma unroll
        for (int ct = 0; ct < 5; ++ct) acc[rt][ct] = (f32x4)0.f;
#pragma unroll 2
    for (int ks = 0; ks < 10; ++ks) {
        int kk = ks * 32 + khi * 8;
        int c = ks * 4 + khi;              // chunk 0..39
        bf16x8 a[2], b[5];
#pragma unroll
        for (int rt = 0; rt < 2; ++rt) {
            int row = rt * 16 + rlo;
            a[rt] = *(const bf16x8*)(smA + row * 320 + ((c ^ (row & 7)) << 3));
        }
#pragma unroll
        for (int ct = 0; ct < 5; ++ct)
            b[ct] = *(const bf16x8*)(Bt + (size_t)(c0 + ct * 16 + rlo) * HP + kk);
#pragma unroll
        for (int rt = 0; rt < 2; ++rt)
#pragma unroll
            for (int ct = 0; ct < 5; ++ct)
                acc[rt][ct] = __builtin_amdgcn_mfma_f32_16x16x32_bf16(a[rt], b[ct], acc[rt][ct], 0, 0, 0);
    }
    int rhi = lane >> 4;
    float csum[5], csq[5];
#pragma unroll
    for (int ct = 0; ct < 5; ++ct) { csum[ct] = 0.f; csq[ct] = 0.f; }
#pragma unroll
    for (int rt = 0; rt < 2; ++rt)
#pragma unroll
        for (int j = 0; j < 4; ++j) {
            int r = row0 + rt * 16 + rhi * 4 + j;
            int se = src[r], de = dst[r];
#pragma unroll
            for (int ct = 0; ct < 5; ++ct) {
                int col = c0 + ct * 16 + rlo;
                if (col < H) {
                    float g = acc[rt][ct][j] + nodeU[(size_t)se * H + col] + nodeU[(size_t)de * H + col];
                    gate_bf[(size_t)r * H + col] = __float2bfloat16(g);
                    csum[ct] += g;
                    csq[ct] += g * g;
                }
            }
        }
#pragma unroll
    for (int ct = 0; ct < 5; ++ct) {
        csum[ct] += __shfl_xor(csum[ct], 16, 64);
        csum[ct] += __shfl_xor(csum[ct], 32, 64);
        csq[ct]  += __shfl_xor(csq[ct], 16, 64);
        csq[ct]  += __shfl_xor(csq[ct], 32, 64);
    }
    if (khi == 0) {
        float* re = REc + (size_t)(bx & (NREP - 1)) * RSTRIDE;
#pragma unroll
        for (int ct = 0; ct < 5; ++ct) {
            int col = c0 + ct * 16 + rlo;
            if (col < H) {
                atomicAdd(&re[col], csum[ct]);
                atomicAdd(&re[SSTRIDE + col], csq[ct]);
            }
        }
    }
}

// ------------- K3: CSR gather (2 nodes/block), uses precomputed invS
__global__ __launch_bounds__(320) void node_msg(const bf16* __restrict__ edge_bf,
                                                const float* __restrict__ nodeV,
                                                const float* __restrict__ nodeUn,
                                                const int* __restrict__ offs,
                                                const int* __restrict__ eidx,
                                                const int* __restrict__ msrc,
                                                const float* __restrict__ invS,
                                                float* __restrict__ RN,
                                                float* __restrict__ aggv) {
    int t = threadIdx.x;
    int bx = blockIdx.x;
    if (t >= H) return;
    float inv = invS[t];
    float st1 = 0.f, st2 = 0.f;
    int n0 = bx * 2;
#pragma unroll
    for (int k = 0; k < 2; ++k) {
        int n = n0 + k;
        int beg = offs[n], end = offs[n + 1];
        float a = 0.f;
        for (int i = beg; i < end; ++i) {
            int e = eidx[i];
            int s = msrc[i];
            a += sigm(__bfloat162float(edge_bf[(size_t)e * HP + t])) * nodeV[(size_t)s * H + t];
        }
        float v = nodeUn[(size_t)n * H + t] + a * inv;
        aggv[(size_t)n * H + t] = v;
        st1 += v; st2 += v * v;
    }
    float* rn = RN + (size_t)(bx & (NREP - 1)) * RSTRIDE;
    atomicAdd(&rn[t], st1);
    atomicAdd(&rn[SSTRIDE + t], st2);
}

// ------------- K4: edge_finalize (bx<NEB) || node_update (bx>=NEB), bf16 residual
__global__ __launch_bounds__(256) void fused_final(bf16* __restrict__ edge_bf,
                                                   const bf16* __restrict__ gate_bf,
                                                   const float* __restrict__ REc,
                                                   float* __restrict__ REo,
                                                   const float* __restrict__ RNc,
                                                   float* __restrict__ RNo,
                                                   float* __restrict__ RSnext,
                                                   const float* __restrict__ eg,
                                                   const float* __restrict__ ebt,
                                                   const float* __restrict__ ng,
                                                   const float* __restrict__ nbt,
                                                   float* __restrict__ node,
                                                   bf16* __restrict__ node_bf,
                                                   const float* __restrict__ aggv) {
    __shared__ float sc_s[SSTRIDE], of_s[SSTRIDE], s_s[SSTRIDE];
    int bx = blockIdx.x, t = threadIdx.x;
    if (bx < NEB) {
        const float invE = 1.f / N_EDGES;
        for (int i = t; i < SSTRIDE; i += 256) {
            s_s[i] = 0.f;
            if (i < H) {
                float gs = 0.f, gq = 0.f;
#pragma unroll 8
                for (int r = 0; r < NREP; ++r) {
                    gs += REc[r * RSTRIDE + i];
                    gq += REc[r * RSTRIDE + SSTRIDE + i];
                }
                float mean = gs * invE;
                float var = fmaxf(gq * invE - mean * mean, 0.f);
                float rstd = rsqrtf(var + 1e-5f);
                float sc = rstd * eg[i];
                sc_s[i] = sc;
                of_s[i] = ebt[i] - mean * sc;
            }
        }
        __syncthreads();
        int hc = t % 80, rgrp = t / 80;
        bool act = (hc < CH) && (rgrp < 3);
        float ss[4] = {0.f, 0.f, 0.f, 0.f};
        int col0 = hc * 4;
        if (act) {
            float sc[4], of[4];
#pragma unroll
            for (int j = 0; j < 4; ++j) { sc[j] = sc_s[col0 + j]; of[j] = of_s[col0 + j]; }
            int e0 = bx * 64;
            for (int r = rgrp; r < 64; r += 3) {
                int e = e0 + r;
                union { ushort4 u; bf16 b[4]; } eb, gv, ob;
                eb.u = *(const ushort4*)(edge_bf + (size_t)e * HP + col0);
                gv.u = *(const ushort4*)(gate_bf + (size_t)e * H + col0);
#pragma unroll
                for (int j = 0; j < 4; ++j) {
                    float g = __bfloat162float(gv.b[j]);
                    float val = fmaxf(fmaf(g, sc[j], of[j]), 0.f);
                    float nv = __bfloat162float(eb.b[j]) + val;
                    ob.b[j] = __float2bfloat16(nv);
                    ss[j] += sigm(__bfloat162float(ob.b[j]));
                }
                *(ushort4*)(edge_bf + (size_t)e * HP + col0) = ob.u;
            }
#pragma unroll
            for (int j = 0; j < 4; ++j) atomicAdd(&s_s[col0 + j], ss[j]);
        }
        __syncthreads();
        float* rs = RSnext + (size_t)(bx & (NREP - 1)) * SSTRIDE;
        for (int i = t; i < H; i += 256) atomicAdd(&rs[i], s_s[i]);
    } else {
        int idx = bx - NEB;                // 0..NUB-1
        if (idx < NREP) {
            for (int i = t; i < RSTRIDE; i += 256) {
                REo[(size_t)idx * RSTRIDE + i] = 0.f;
                RNo[(size_t)idx * RSTRIDE + i] = 0.f;
            }
        }
        const float invN = 1.f / N_NODES;
        for (int i = t; i < H; i += 256) {
            float ns = 0.f, nq = 0.f;
#pragma unroll 8
            for (int r = 0; r < NREP; ++r) {
                ns += RNc[r * RSTRIDE + i];
                nq += RNc[r * RSTRIDE + SSTRIDE + i];
            }
            float mean = ns * invN;
            float var = fmaxf(nq * invN - mean * mean, 0.f);
            float rstd = rsqrtf(var + 1e-5f);
            float sc = rstd * ng[i];
            sc_s[i] = sc;
            of_s[i] = nbt[i] - mean * sc;
        }
        __syncthreads();
#pragma unroll
        for (int it = 0; it < 4; ++it) {
            int c = idx * 1024 + it * 256 + t;
            if (c >= NH / 4) break;
            int n = c / CH, hc = c % CH, col0 = hc * 4;
            float4 v4 = ((const float4*)aggv)[c];
            float4 nd = ((const float4*)node)[c];
            const float* v4p = (const float*)&v4;
            const float* ndp = (const float*)&nd;
            union { ushort4 u; bf16 b[4]; } ob;
            float outv[4];
#pragma unroll
            for (int j = 0; j < 4; ++j) {
                float g = fmaf(v4p[j], sc_s[col0 + j], of_s[col0 + j]);
                outv[j] = ndp[j] + fmaxf(g, 0.f);
                ob.b[j] = __float2bfloat16(outv[j]);
            }
            ((float4*)node)[c] = make_float4(outv[0], outv[1], outv[2], outv[3]);
            *(ushort4*)(node_bf + (size_t)n * HP + col0) = ob.u;
        }
    }
}

// ----------------- classifier + loss: 4 lanes/edge, vectorized, clsW in regs
__global__ __launch_bounds__(256) void classify_loss(const bf16* __restrict__ edge_bf,
                                                     const float* __restrict__ clsW,
                                                     const float* __restrict__ clsb,
                                                     const int* __restrict__ src,
                                                     const int* __restrict__ dst,
                                                     const float* __restrict__ y,
                                                     float* __restrict__ out) {
    __shared__ float wl[4];
    int lane = threadIdx.x & 63;
    int wid = threadIdx.x >> 6;
    int quad = lane >> 2;              // edge index within 16-edge group
    int ql = lane & 3;                 // 80-col chunk
    float w[80];
#pragma unroll
    for (int j = 0; j < 80; ++j) {
        int col = ql * 80 + j;
        w[j] = (col < H) ? clsW[col] : 0.f;
    }
    int g = blockIdx.x * 4 + wid;      // 0..1999, one 16-edge group per wave
    int e = g * 16 + quad;
    const bf16* row = edge_bf + (size_t)e * HP + ql * 80;   // pad cols are 0
    float acc = 0.f;
#pragma unroll
    for (int v = 0; v < 10; ++v) {
        bf16x8 bv = *(const bf16x8*)(row + v * 8);
#pragma unroll
        for (int j = 0; j < 8; ++j)
            acc += __bfloat162float(((const bf16*)&bv)[j]) * w[v * 8 + j];
    }
    acc += __shfl_xor(acc, 1, 64);
    acc += __shfl_xor(acc, 2, 64);
    float lsum = 0.f;
    if (ql == 0) {
        float z = acc + clsb[0];
        float p = 1.f / (1.f + __expf(-z));
        atomicAdd(&out[(size_t)src[e] * N_NODES + dst[e]], p);
        float pc = fminf(fmaxf(p, 1e-7f), 1.f - 1e-7f);
        lsum = -(y[e] * __logf(pc) + (1.f - y[e]) * log1pf(-pc));
    }
#pragma unroll
    for (int off = 32; off > 0; off >>= 1) lsum += __shfl_down(lsum, off, 64);
    if (lane == 0) wl[wid] = lsum;
    __syncthreads();
    if (threadIdx.x == 0) {
        float tt = wl[0] + wl[1] + wl[2] + wl[3];
        atomicAdd(&out[(size_t)N_NODES * N_NODES], tt * (1.f / N_EDGES));
    }
}

// ---------------------------------------------------------------- launcher
extern "C" void kernel_launch(void* const* d_in, const int* in_sizes, int n_in,
                              void* d_out, int out_size, void* d_ws, size_t ws_size,
                              hipStream_t stream) {
    const float* x          = (const float*)d_in[0];
    const float* edge_attr  = (const float*)d_in[1];
    const int*   edge_index = (const int*)d_in[2];
    const float* y          = (const float*)d_in[3];
    const float* node_emb_W = (const float*)d_in[4];
    const float* node_emb_b = (const float*)d_in[5];
    const float* edge_d_W   = (const float*)d_in[6];
    const float* edge_d_b   = (const float*)d_in[7];
    const float* edge_t_W   = (const float*)d_in[8];
    const float* edge_t_b   = (const float*)d_in[9];
    const float* eU_W = (const float*)d_in[10];
    const float* eU_b = (const float*)d_in[11];
    const float* eW_W = (const float*)d_in[12];
    const float* nU_W = (const float*)d_in[14];
    const float* nU_b = (const float*)d_in[15];
    const float* nV_W = (const float*)d_in[16];
    const float* nV_b = (const float*)d_in[17];
    const float* bn_e_g = (const float*)d_in[18];
    const float* bn_e_b = (const float*)d_in[19];
    const float* bn_n_g = (const float*)d_in[20];
    const float* bn_n_b = (const float*)d_in[21];
    const float* cls_W = (const float*)d_in[22];
    const float* cls_b = (const float*)d_in[23];

    const int* src = edge_index;
    const int* dst = edge_index + N_EDGES;

    float* ws     = (float*)d_ws;
    float* node   = ws;                  // NH
    float* nodeU  = node + NH;           // NH
    float* nodeV  = nodeU + NH;          // NH
    float* nodeUn = nodeV + NH;          // NH
    float* aggv   = nodeUn + NH;         // NH
    float* RE2    = aggv + NH;           // 2 x 32*608   <-- zero region start
    float* RN2    = RE2 + 2 * NREP * RSTRIDE;
    float* RS2    = RN2 + 2 * NREP * RSTRIDE;  // 2 x 32*304
    float* invS   = RS2 + 2 * NREP * SSTRIDE;  // 304
    bf16* node_bf = (bf16*)(invS + SSTRIDE);              // 2048*320
    bf16* edge_bf = node_bf + (size_t)NODE_ROWS_PAD * HP; // 32000*320
    bf16* gate_bf = edge_bf + (size_t)N_EDGES * HP;       // 32000*300 (not zeroed)
    bf16* Wt_all  = gate_bf + (size_t)N_EDGES * H;        // 120*102400
    int* csr_counts = (int*)(Wt_all + (size_t)120 * WMAT);
    int* csr_offs   = csr_counts + 2048;
    int* csr_woff   = csr_offs + 2048;
    int* csr_eidx   = csr_woff + 2048;
    int* csr_msrc   = csr_eidx + N_EDGES;

    float* out = (float*)d_out;

    // zero: out, [RE2 | RN2 | RS2 | invS | node_bf | edge_bf], csr_counts
    int zstats = 4 * NREP * RSTRIDE + 2 * NREP * SSTRIDE + SSTRIDE;
    int zlen = zstats + (NODE_ROWS_PAD * HP + N_EDGES * HP) / 2;
    zero_buf<<<(N_NODES * N_NODES + 1 + 255) / 256, 256, 0, stream>>>(out, N_NODES * N_NODES + 1);
    zero_buf<<<(zlen + 255) / 256, 256, 0, stream>>>(RE2, zlen);
    zero_buf<<<8, 256, 0, stream>>>((float*)csr_counts, 2048);

    convert_weights_t<<<12000, 256, 0, stream>>>(eU_W, eW_W, nU_W, nV_W, Wt_all);
    csr_hist<<<(N_EDGES + 255) / 256, 256, 0, stream>>>(dst, csr_counts);
    csr_scan<<<1, 256, 0, stream>>>(csr_counts, csr_offs, csr_woff);
    csr_scatter<<<(N_EDGES + 255) / 256, 256, 0, stream>>>(src, dst, csr_woff, csr_eidx, csr_msrc);
    node_embed<<<(NH + 255) / 256, 256, 0, stream>>>(x, node_emb_W, node_emb_b, node, node_bf);
    edge_embed<<<NEB, 256, 0, stream>>>(edge_attr, edge_d_W, edge_d_b,
                                        edge_t_W, edge_t_b, edge_bf, RS2);

    for (int l = 0; l < NLAYERS; ++l) {
        float* REc = RE2 + (size_t)(l & 1) * NREP * RSTRIDE;
        float* REo = RE2 + (size_t)((l + 1) & 1) * NREP * RSTRIDE;
        float* RNc = RN2 + (size_t)(l & 1) * NREP * RSTRIDE;
        float* RNo = RN2 + (size_t)((l + 1) & 1) * NREP * RSTRIDE;
        float* RScur = RS2 + (size_t)(l & 1) * NREP * SSTRIDE;
        float* RSnxt = RS2 + (size_t)((l + 1) & 1) * NREP * SSTRIDE;
        const bf16* BtE = Wt_all + (size_t)(30 + l) * WMAT;

        gemm_node<<<1505, 64, 0, stream>>>(node_bf, Wt_all, eU_b, nV_b, nU_b, l,
                                           nodeU, nodeV, nodeUn, RScur, RSnxt, invS);
        gemm_edge<<<1000, 256, 0, stream>>>(edge_bf, BtE, nodeU, src, dst,
                                            gate_bf, REc);
        node_msg<<<N_NODES / 2, 320, 0, stream>>>(edge_bf, nodeV, nodeUn,
                                                  csr_offs, csr_eidx, csr_msrc,
                                                  invS, RNc, aggv);
        fused_final<<<NEB + NUB, 256, 0, stream>>>(edge_bf, gate_bf,
                                                   REc, REo, RNc, RNo, RSnxt,
                                                   bn_e_g + l * H, bn_e_b + l * H,
                                                   bn_n_g + l * H, bn_n_b + l * H,
                                                   node, node_bf, aggv);
    }

    classify_loss<<<500, 256, 0, stream>>>(edge_bf, cls_W, cls_b, src, dst, y, out);
}

// Round 14
// 2546.486 us; speedup vs baseline: 1.2721x; 1.1850x over previous
//
#include <hip/hip_runtime.h>
#include <hip/hip_bf16.h>
#include <math.h>

#define N_NODES 2000
#define N_EDGES 32000
#define H 300
#define CH 75             // H/4 float4 chunks per row
#define HP 320            // padded H for MFMA K/N
#define NLAYERS 30
#define NH (N_NODES * H)     // 600000
#define NODE_ROWS_PAD 2048
#define WMAT (HP * HP)
#define NREP 32              // stat replicas
#define RSTRIDE 608          // replica row stride (sum | sumsq at +304)
#define SSTRIDE 304
#define NEB 500              // edge-finalize blocks (32000/64)
#define NUB 147              // node_update blocks (1024 chunks each)

typedef short bf16x8 __attribute__((ext_vector_type(8)));
typedef float f32x4 __attribute__((ext_vector_type(4)));
typedef __hip_bfloat16 bf16;

__device__ __forceinline__ float sigm(float x) { return 1.f / (1.f + __expf(-x)); }

// ---------------------------------------------------------------- utilities
__global__ __launch_bounds__(256) void zero_buf(float* __restrict__ p, int n) {
    int i = blockIdx.x * blockDim.x + threadIdx.x;
    if (i < n) p[i] = 0.f;
}

// --------------------- weights -> bf16 transposed, LDS-tiled (coalesced both ways)
__global__ __launch_bounds__(256) void convert_weights_t(const float* __restrict__ eU,
                                                         const float* __restrict__ eW,
                                                         const float* __restrict__ nU,
                                                         const float* __restrict__ nV,
                                                         bf16* __restrict__ Wt) {
    __shared__ float tile[32][33];
    int b = blockIdx.x;                 // 120 mats x 100 tiles
    int m = b / 100;
    int rem = b % 100;
    int kt = rem / 10, nt = rem % 10;
    int k0 = kt * 32, n0 = nt * 32;
    int grp = m / NLAYERS, l = m % NLAYERS;
    const float* S = (grp == 0) ? eU : (grp == 1) ? eW : (grp == 2) ? nU : nV;
    const float* Sl = S + (size_t)l * H * H;
    int t = threadIdx.x;
    int tn = t & 31, tk = t >> 5;
#pragma unroll
    for (int p = 0; p < 4; ++p) {
        int k = tk + p * 8;
        int gk = k0 + k, gn = n0 + tn;
        tile[k][tn] = (gk < H && gn < H) ? Sl[(size_t)gk * H + gn] : 0.f;
    }
    __syncthreads();
    bf16* D = Wt + (size_t)m * WMAT;
    int tk2 = t & 31, tn2 = t >> 5;
#pragma unroll
    for (int p = 0; p < 4; ++p) {
        int n = tn2 + p * 8;
        D[(size_t)(n0 + n) * HP + k0 + tk2] = __float2bfloat16(tile[tk2][n]);
    }
}

// ---- eW weights K-packed: WtK[l][ct4][kc][c][8] = Wt[30+l][(ct4*80+c)*HP + kc*8+j]
__global__ __launch_bounds__(256) void convert_wtk(const bf16* __restrict__ Wt,
                                                   bf16* __restrict__ WtK) {
    long long idx = (long long)blockIdx.x * 256 + threadIdx.x;
    if (idx >= 30LL * WMAT) return;
    int m = (int)(idx / WMAT);
    int rem = (int)(idx % WMAT);
    int ct4 = rem / 25600;
    int r2 = rem % 25600;
    int kc = r2 / 640;
    int r3 = r2 % 640;
    int c = r3 / 8, j = r3 % 8;
    WtK[idx] = Wt[(size_t)(30 + m) * WMAT + (size_t)(ct4 * 80 + c) * HP + kc * 8 + j];
}

// ------------------------------------------------------------- CSR by dst
__global__ __launch_bounds__(256) void csr_hist(const int* __restrict__ dst,
                                                int* __restrict__ counts) {
    int i = blockIdx.x * 256 + threadIdx.x;
    if (i < N_EDGES) atomicAdd(&counts[dst[i]], 1);
}

__global__ __launch_bounds__(256) void csr_scan(const int* __restrict__ counts,
                                                int* __restrict__ offs,
                                                int* __restrict__ woff) {
    __shared__ int part[256];
    int t = threadIdx.x;
    int base = t * 8;
    int local[8];
    int s = 0;
#pragma unroll
    for (int j = 0; j < 8; ++j) {
        int c = (base + j < N_NODES) ? counts[base + j] : 0;
        local[j] = s;
        s += c;
    }
    part[t] = s;
    __syncthreads();
    for (int off = 1; off < 256; off <<= 1) {
        int v = (t >= off) ? part[t - off] : 0;
        __syncthreads();
        part[t] += v;
        __syncthreads();
    }
    int pre = (t == 0) ? 0 : part[t - 1];
#pragma unroll
    for (int j = 0; j < 8; ++j) {
        int idx = base + j;
        if (idx < N_NODES) { int v = pre + local[j]; offs[idx] = v; woff[idx] = v; }
    }
    if (t == 255) offs[N_NODES] = part[255];
}

__global__ __launch_bounds__(256) void csr_scatter(const int* __restrict__ src,
                                                   const int* __restrict__ dst,
                                                   int* __restrict__ woff,
                                                   int* __restrict__ eidx,
                                                   int* __restrict__ msrc) {
    int i = blockIdx.x * 256 + threadIdx.x;
    if (i < N_EDGES) {
        int p = atomicAdd(&woff[dst[i]], 1);
        eidx[p] = i;
        msrc[p] = src[i];
    }
}

// ---------------------------------------------------------------- embeddings
__global__ __launch_bounds__(256) void node_embed(const float* __restrict__ x,
                                                  const float* __restrict__ W,
                                                  const float* __restrict__ b,
                                                  float* __restrict__ node,
                                                  bf16* __restrict__ node_bf) {
    int i = blockIdx.x * blockDim.x + threadIdx.x;
    if (i >= NH) return;
    int n = i / H, h = i % H;
    float acc = b[h];
#pragma unroll
    for (int k = 0; k < 4; ++k) acc += x[n * 4 + k] * W[k * H + h];
    node[i] = acc;
    node_bf[(size_t)n * HP + h] = __float2bfloat16(acc);
}

// edge embedding, bf16 only, col-chunk ownership; sigmoid colsum -> RS0
__global__ __launch_bounds__(256) void edge_embed(const float* __restrict__ ea,
                                                  const float* __restrict__ dW,
                                                  const float* __restrict__ db,
                                                  const float* __restrict__ tW,
                                                  const float* __restrict__ tb,
                                                  bf16* __restrict__ edge_bf,
                                                  float* __restrict__ RS0) {
    __shared__ float s_s[SSTRIDE];
    int t = threadIdx.x;
    for (int i = t; i < SSTRIDE; i += 256) s_s[i] = 0.f;
    __syncthreads();
    int hc = t % 80, rgrp = t / 80;
    int col0 = hc * 4;
    float ss[4] = {0.f, 0.f, 0.f, 0.f};
    if (hc < CH && rgrp < 3) {
        float wv[4], bv[4];
#pragma unroll
        for (int j = 0; j < 4; ++j) {
            int col = col0 + j;
            wv[j] = (col < 150) ? dW[col] : tW[col - 150];
            bv[j] = (col < 150) ? db[col] : tb[col - 150];
        }
        int e0 = blockIdx.x * 64;
        for (int r = rgrp; r < 64; r += 3) {
            int e = e0 + r;
            float d = ea[2 * e], tt = ea[2 * e + 1];
            union { ushort4 u; bf16 b[4]; } ob;
#pragma unroll
            for (int j = 0; j < 4; ++j) {
                int col = col0 + j;
                float v = ((col < 150) ? d : tt) * wv[j] + bv[j];
                ob.b[j] = __float2bfloat16(v);
                ss[j] += sigm(__bfloat162float(ob.b[j]));
            }
            *(ushort4*)(edge_bf + (size_t)e * HP + col0) = ob.u;
        }
#pragma unroll
        for (int j = 0; j < 4; ++j) atomicAdd(&s_s[col0 + j], ss[j]);
    }
    __syncthreads();
    float* rs = RS0 + (size_t)(blockIdx.x & (NREP - 1)) * SSTRIDE;
    for (int i = t; i < H; i += 256) atomicAdd(&rs[i], s_s[i]);
}

// ---- K1: node GEMMs (1500 one-wave blocks) + 5 blocks: invS from RScur, zero RSnxt
__global__ __launch_bounds__(64) void gemm_node(const bf16* __restrict__ node_bf,
                                                const bf16* __restrict__ Wt_all,
                                                const float* __restrict__ eU_b,
                                                const float* __restrict__ nV_b,
                                                const float* __restrict__ nU_b,
                                                int layer,
                                                float* __restrict__ nodeU,
                                                float* __restrict__ nodeV,
                                                float* __restrict__ nodeUn,
                                                const float* __restrict__ RScur,
                                                float* __restrict__ RSnxt,
                                                float* __restrict__ invS) {
    int bx = blockIdx.x;
    int lane = threadIdx.x;
    if (bx >= 1500) {
        int idx = bx - 1500;               // 0..4
        int c = idx * 64 + lane;           // 0..319
        if (c < H) {
            float ssr = 0.f;
#pragma unroll 8
            for (int r = 0; r < NREP; ++r) ssr += RScur[r * SSTRIDE + c];
            invS[c] = 1.f / (ssr + 1e-20f);
        }
        for (int i = idx * 64 + lane; i < NREP * SSTRIDE; i += 320) RSnxt[i] = 0.f;
        return;
    }
    int mat = bx / 500;
    int rem = bx % 500;
    int rt0 = rem >> 2, ct4 = rem & 3;
    const bf16* Bt; const float* bias; float* out;
    if (mat == 0)      { Bt = Wt_all + (size_t)(0 + layer) * WMAT;  bias = eU_b + layer * H; out = nodeU; }
    else if (mat == 1) { Bt = Wt_all + (size_t)(90 + layer) * WMAT; bias = nV_b + layer * H; out = nodeV; }
    else               { Bt = Wt_all + (size_t)(60 + layer) * WMAT; bias = nU_b + layer * H; out = nodeUn; }
    int row0 = rt0 * 16, c0 = ct4 * 80;
    int rlo = lane & 15, khi = lane >> 4;
    f32x4 acc[5];
#pragma unroll
    for (int ct = 0; ct < 5; ++ct) acc[ct] = (f32x4)0.f;
#pragma unroll 2
    for (int ks = 0; ks < 10; ++ks) {
        int kk = ks * 32 + khi * 8;
        bf16x8 a, b[5];
        a = *(const bf16x8*)(node_bf + (size_t)(row0 + rlo) * HP + kk);
#pragma unroll
        for (int ct = 0; ct < 5; ++ct)
            b[ct] = *(const bf16x8*)(Bt + (size_t)(c0 + ct * 16 + rlo) * HP + kk);
#pragma unroll
        for (int ct = 0; ct < 5; ++ct)
            acc[ct] = __builtin_amdgcn_mfma_f32_16x16x32_bf16(a, b[ct], acc[ct], 0, 0, 0);
    }
    int rhi = lane >> 4;
#pragma unroll
    for (int ct = 0; ct < 5; ++ct) {
        int col = c0 + ct * 16 + rlo;
        if (col >= H) continue;
        float bv = bias[col];
#pragma unroll
        for (int j = 0; j < 4; ++j) {
            int r = row0 + rhi * 4 + j;
            out[(size_t)r * H + col] = acc[ct][j] + bv;
        }
    }
}

// ------ K2: edge gate GEMM: 1000 blocks x 4 waves, block = 32 edges x 320 cols.
// A (32x320, 20KB) staged ONCE in LDS, XOR-swizzled. B from global in K-packed
// WtK layout (contiguous 256B segments per fragment load).
__global__ __launch_bounds__(256) void gemm_edge(const bf16* __restrict__ edge_bf,
                                                 const bf16* __restrict__ WtK_l,
                                                 const float* __restrict__ nodeU,
                                                 const int* __restrict__ src,
                                                 const int* __restrict__ dst,
                                                 bf16* __restrict__ gate_bf,
                                                 float* __restrict__ REc) {
    __shared__ bf16 smA[32 * 320];         // 20 KB
    int tid = threadIdx.x;
    int bx = blockIdx.x;                   // 0..999
    int wave = tid >> 6, lane = tid & 63;
    int row0 = bx * 32;
    int c0 = wave * 80;
    int rlo = lane & 15, khi = lane >> 4, rhi = lane >> 4;

    // hoist src/dst index loads (epilogue gathers can issue early)
    int se_[8], de_[8];
#pragma unroll
    for (int rt = 0; rt < 2; ++rt)
#pragma unroll
        for (int j = 0; j < 4; ++j) {
            int r = row0 + rt * 16 + rhi * 4 + j;
            se_[rt * 4 + j] = src[r];
            de_[rt * 4 + j] = dst[r];
        }

    // stage A: 1280 uint4 chunks, fully coalesced (20480B contiguous)
    const uint4* Ag = (const uint4*)(edge_bf + (size_t)row0 * HP);
#pragma unroll
    for (int it = 0; it < 5; ++it) {
        int cid = it * 256 + tid;          // 0..1279
        int row = cid / 40, ch = cid % 40;
        uint4 v = Ag[cid];
        *(uint4*)(smA + row * 320 + ((ch ^ (row & 7)) << 3)) = v;
    }
    __syncthreads();

    const bf16* Bw = WtK_l + (size_t)wave * 25600;   // this wave's 80-col K-packed slice
    f32x4 acc[2][5];
#pragma unroll
    for (int rt = 0; rt < 2; ++rt)
#pragma unroll
        for (int ct = 0; ct < 5; ++ct) acc[rt][ct] = (f32x4)0.f;
#pragma unroll 2
    for (int ks = 0; ks < 10; ++ks) {
        int c = ks * 4 + khi;              // A chunk 0..39
        int kcb = (ks * 4 + khi) * 80;     // B row base (bf16x8 units)
        bf16x8 a[2], b[5];
#pragma unroll
        for (int rt = 0; rt < 2; ++rt) {
            int row = rt * 16 + rlo;
            a[rt] = *(const bf16x8*)(smA + row * 320 + ((c ^ (row & 7)) << 3));
        }
#pragma unroll
        for (int ct = 0; ct < 5; ++ct)
            b[ct] = *(const bf16x8*)(Bw + (size_t)(kcb + ct * 16 + rlo) * 8);
#pragma unroll
        for (int rt = 0; rt < 2; ++rt)
#pragma unroll
            for (int ct = 0; ct < 5; ++ct)
                acc[rt][ct] = __builtin_amdgcn_mfma_f32_16x16x32_bf16(a[rt], b[ct], acc[rt][ct], 0, 0, 0);
    }
    float csum[5], csq[5];
#pragma unroll
    for (int ct = 0; ct < 5; ++ct) { csum[ct] = 0.f; csq[ct] = 0.f; }
#pragma unroll
    for (int rt = 0; rt < 2; ++rt)
#pragma unroll
        for (int j = 0; j < 4; ++j) {
            int r = row0 + rt * 16 + rhi * 4 + j;
            int se = se_[rt * 4 + j], de = de_[rt * 4 + j];
#pragma unroll
            for (int ct = 0; ct < 5; ++ct) {
                int col = c0 + ct * 16 + rlo;
                if (col < H) {
                    float g = acc[rt][ct][j] + nodeU[(size_t)se * H + col] + nodeU[(size_t)de * H + col];
                    gate_bf[(size_t)r * H + col] = __float2bfloat16(g);
                    csum[ct] += g;
                    csq[ct] += g * g;
                }
            }
        }
#pragma unroll
    for (int ct = 0; ct < 5; ++ct) {
        csum[ct] += __shfl_xor(csum[ct], 16, 64);
        csum[ct] += __shfl_xor(csum[ct], 32, 64);
        csq[ct]  += __shfl_xor(csq[ct], 16, 64);
        csq[ct]  += __shfl_xor(csq[ct], 32, 64);
    }
    if (khi == 0) {
        float* re = REc + (size_t)(bx & (NREP - 1)) * RSTRIDE;
#pragma unroll
        for (int ct = 0; ct < 5; ++ct) {
            int col = c0 + ct * 16 + rlo;
            if (col < H) {
                atomicAdd(&re[col], csum[ct]);
                atomicAdd(&re[SSTRIDE + col], csq[ct]);
            }
        }
    }
}

// ------------- K3: CSR gather (2 nodes/block), uses precomputed invS
__global__ __launch_bounds__(320) void node_msg(const bf16* __restrict__ edge_bf,
                                                const float* __restrict__ nodeV,
                                                const float* __restrict__ nodeUn,
                                                const int* __restrict__ offs,
                                                const int* __restrict__ eidx,
                                                const int* __restrict__ msrc,
                                                const float* __restrict__ invS,
                                                float* __restrict__ RN,
                                                float* __restrict__ aggv) {
    int t = threadIdx.x;
    int bx = blockIdx.x;
    if (t >= H) return;
    float inv = invS[t];
    float st1 = 0.f, st2 = 0.f;
    int n0 = bx * 2;
#pragma unroll
    for (int k = 0; k < 2; ++k) {
        int n = n0 + k;
        int beg = offs[n], end = offs[n + 1];
        float a = 0.f;
        for (int i = beg; i < end; ++i) {
            int e = eidx[i];
            int s = msrc[i];
            a += sigm(__bfloat162float(edge_bf[(size_t)e * HP + t])) * nodeV[(size_t)s * H + t];
        }
        float v = nodeUn[(size_t)n * H + t] + a * inv;
        aggv[(size_t)n * H + t] = v;
        st1 += v; st2 += v * v;
    }
    float* rn = RN + (size_t)(bx & (NREP - 1)) * RSTRIDE;
    atomicAdd(&rn[t], st1);
    atomicAdd(&rn[SSTRIDE + t], st2);
}

// ------------- K4: edge_finalize (bx<NEB) || node_update (bx>=NEB), bf16 residual
__global__ __launch_bounds__(256) void fused_final(bf16* __restrict__ edge_bf,
                                                   const bf16* __restrict__ gate_bf,
                                                   const float* __restrict__ REc,
                                                   float* __restrict__ REo,
                                                   const float* __restrict__ RNc,
                                                   float* __restrict__ RNo,
                                                   float* __restrict__ RSnext,
                                                   const float* __restrict__ eg,
                                                   const float* __restrict__ ebt,
                                                   const float* __restrict__ ng,
                                                   const float* __restrict__ nbt,
                                                   float* __restrict__ node,
                                                   bf16* __restrict__ node_bf,
                                                   const float* __restrict__ aggv) {
    __shared__ float sc_s[SSTRIDE], of_s[SSTRIDE], s_s[SSTRIDE];
    int bx = blockIdx.x, t = threadIdx.x;
    if (bx < NEB) {
        const float invE = 1.f / N_EDGES;
        for (int i = t; i < SSTRIDE; i += 256) {
            s_s[i] = 0.f;
            if (i < H) {
                float gs = 0.f, gq = 0.f;
#pragma unroll 8
                for (int r = 0; r < NREP; ++r) {
                    gs += REc[r * RSTRIDE + i];
                    gq += REc[r * RSTRIDE + SSTRIDE + i];
                }
                float mean = gs * invE;
                float var = fmaxf(gq * invE - mean * mean, 0.f);
                float rstd = rsqrtf(var + 1e-5f);
                float sc = rstd * eg[i];
                sc_s[i] = sc;
                of_s[i] = ebt[i] - mean * sc;
            }
        }
        __syncthreads();
        int hc = t % 80, rgrp = t / 80;
        bool act = (hc < CH) && (rgrp < 3);
        float ss[4] = {0.f, 0.f, 0.f, 0.f};
        int col0 = hc * 4;
        if (act) {
            float sc[4], of[4];
#pragma unroll
            for (int j = 0; j < 4; ++j) { sc[j] = sc_s[col0 + j]; of[j] = of_s[col0 + j]; }
            int e0 = bx * 64;
            for (int r = rgrp; r < 64; r += 3) {
                int e = e0 + r;
                union { ushort4 u; bf16 b[4]; } eb, gv, ob;
                eb.u = *(const ushort4*)(edge_bf + (size_t)e * HP + col0);
                gv.u = *(const ushort4*)(gate_bf + (size_t)e * H + col0);
#pragma unroll
                for (int j = 0; j < 4; ++j) {
                    float g = __bfloat162float(gv.b[j]);
                    float val = fmaxf(fmaf(g, sc[j], of[j]), 0.f);
                    float nv = __bfloat162float(eb.b[j]) + val;
                    ob.b[j] = __float2bfloat16(nv);
                    ss[j] += sigm(__bfloat162float(ob.b[j]));
                }
                *(ushort4*)(edge_bf + (size_t)e * HP + col0) = ob.u;
            }
#pragma unroll
            for (int j = 0; j < 4; ++j) atomicAdd(&s_s[col0 + j], ss[j]);
        }
        __syncthreads();
        float* rs = RSnext + (size_t)(bx & (NREP - 1)) * SSTRIDE;
        for (int i = t; i < H; i += 256) atomicAdd(&rs[i], s_s[i]);
    } else {
        int idx = bx - NEB;                // 0..NUB-1
        if (idx < NREP) {
            for (int i = t; i < RSTRIDE; i += 256) {
                REo[(size_t)idx * RSTRIDE + i] = 0.f;
                RNo[(size_t)idx * RSTRIDE + i] = 0.f;
            }
        }
        const float invN = 1.f / N_NODES;
        for (int i = t; i < H; i += 256) {
            float ns = 0.f, nq = 0.f;
#pragma unroll 8
            for (int r = 0; r < NREP; ++r) {
                ns += RNc[r * RSTRIDE + i];
                nq += RNc[r * RSTRIDE + SSTRIDE + i];
            }
            float mean = ns * invN;
            float var = fmaxf(nq * invN - mean * mean, 0.f);
            float rstd = rsqrtf(var + 1e-5f);
            float sc = rstd * ng[i];
            sc_s[i] = sc;
            of_s[i] = nbt[i] - mean * sc;
        }
        __syncthreads();
#pragma unroll
        for (int it = 0; it < 4; ++it) {
            int c = idx * 1024 + it * 256 + t;
            if (c >= NH / 4) break;
            int n = c / CH, hc = c % CH, col0 = hc * 4;
            float4 v4 = ((const float4*)aggv)[c];
            float4 nd = ((const float4*)node)[c];
            const float* v4p = (const float*)&v4;
            const float* ndp = (const float*)&nd;
            union { ushort4 u; bf16 b[4]; } ob;
            float outv[4];
#pragma unroll
            for (int j = 0; j < 4; ++j) {
                float g = fmaf(v4p[j], sc_s[col0 + j], of_s[col0 + j]);
                outv[j] = ndp[j] + fmaxf(g, 0.f);
                ob.b[j] = __float2bfloat16(outv[j]);
            }
            ((float4*)node)[c] = make_float4(outv[0], outv[1], outv[2], outv[3]);
            *(ushort4*)(node_bf + (size_t)n * HP + col0) = ob.u;
        }
    }
}

// ----------------- classifier + loss: 4 lanes/edge, vectorized, clsW in regs
__global__ __launch_bounds__(256) void classify_loss(const bf16* __restrict__ edge_bf,
                                                     const float* __restrict__ clsW,
                                                     const float* __restrict__ clsb,
                                                     const int* __restrict__ src,
                                                     const int* __restrict__ dst,
                                                     const float* __restrict__ y,
                                                     float* __restrict__ out) {
    __shared__ float wl[4];
    int lane = threadIdx.x & 63;
    int wid = threadIdx.x >> 6;
    int quad = lane >> 2;              // edge index within 16-edge group
    int ql = lane & 3;                 // 80-col chunk
    float w[80];
#pragma unroll
    for (int j = 0; j < 80; ++j) {
        int col = ql * 80 + j;
        w[j] = (col < H) ? clsW[col] : 0.f;
    }
    int g = blockIdx.x * 4 + wid;      // 0..1999, one 16-edge group per wave
    int e = g * 16 + quad;
    const bf16* row = edge_bf + (size_t)e * HP + ql * 80;   // pad cols are 0
    float acc = 0.f;
#pragma unroll
    for (int v = 0; v < 10; ++v) {
        bf16x8 bv = *(const bf16x8*)(row + v * 8);
#pragma unroll
        for (int j = 0; j < 8; ++j)
            acc += __bfloat162float(((const bf16*)&bv)[j]) * w[v * 8 + j];
    }
    acc += __shfl_xor(acc, 1, 64);
    acc += __shfl_xor(acc, 2, 64);
    float lsum = 0.f;
    if (ql == 0) {
        float z = acc + clsb[0];
        float p = 1.f / (1.f + __expf(-z));
        atomicAdd(&out[(size_t)src[e] * N_NODES + dst[e]], p);
        float pc = fminf(fmaxf(p, 1e-7f), 1.f - 1e-7f);
        lsum = -(y[e] * __logf(pc) + (1.f - y[e]) * log1pf(-pc));
    }
#pragma unroll
    for (int off = 32; off > 0; off >>= 1) lsum += __shfl_down(lsum, off, 64);
    if (lane == 0) wl[wid] = lsum;
    __syncthreads();
    if (threadIdx.x == 0) {
        float tt = wl[0] + wl[1] + wl[2] + wl[3];
        atomicAdd(&out[(size_t)N_NODES * N_NODES], tt * (1.f / N_EDGES));
    }
}

// ---------------------------------------------------------------- launcher
extern "C" void kernel_launch(void* const* d_in, const int* in_sizes, int n_in,
                              void* d_out, int out_size, void* d_ws, size_t ws_size,
                              hipStream_t stream) {
    const float* x          = (const float*)d_in[0];
    const float* edge_attr  = (const float*)d_in[1];
    const int*   edge_index = (const int*)d_in[2];
    const float* y          = (const float*)d_in[3];
    const float* node_emb_W = (const float*)d_in[4];
    const float* node_emb_b = (const float*)d_in[5];
    const float* edge_d_W   = (const float*)d_in[6];
    const float* edge_d_b   = (const float*)d_in[7];
    const float* edge_t_W   = (const float*)d_in[8];
    const float* edge_t_b   = (const float*)d_in[9];
    const float* eU_W = (const float*)d_in[10];
    const float* eU_b = (const float*)d_in[11];
    const float* eW_W = (const float*)d_in[12];
    const float* nU_W = (const float*)d_in[14];
    const float* nU_b = (const float*)d_in[15];
    const float* nV_W = (const float*)d_in[16];
    const float* nV_b = (const float*)d_in[17];
    const float* bn_e_g = (const float*)d_in[18];
    const float* bn_e_b = (const float*)d_in[19];
    const float* bn_n_g = (const float*)d_in[20];
    const float* bn_n_b = (const float*)d_in[21];
    const float* cls_W = (const float*)d_in[22];
    const float* cls_b = (const float*)d_in[23];

    const int* src = edge_index;
    const int* dst = edge_index + N_EDGES;

    float* ws     = (float*)d_ws;
    float* node   = ws;                  // NH
    float* nodeU  = node + NH;           // NH
    float* nodeV  = nodeU + NH;          // NH
    float* nodeUn = nodeV + NH;          // NH
    float* aggv   = nodeUn + NH;         // NH
    float* RE2    = aggv + NH;           // 2 x 32*608   <-- zero region start
    float* RN2    = RE2 + 2 * NREP * RSTRIDE;
    float* RS2    = RN2 + 2 * NREP * RSTRIDE;  // 2 x 32*304
    float* invS   = RS2 + 2 * NREP * SSTRIDE;  // 304
    bf16* node_bf = (bf16*)(invS + SSTRIDE);              // 2048*320
    bf16* edge_bf = node_bf + (size_t)NODE_ROWS_PAD * HP; // 32000*320
    bf16* gate_bf = edge_bf + (size_t)N_EDGES * HP;       // 32000*300 (not zeroed)
    bf16* Wt_all  = gate_bf + (size_t)N_EDGES * H;        // 120*102400
    bf16* WtK_all = Wt_all + (size_t)120 * WMAT;          // 30*102400
    int* csr_counts = (int*)(WtK_all + (size_t)30 * WMAT);
    int* csr_offs   = csr_counts + 2048;
    int* csr_woff   = csr_offs + 2048;
    int* csr_eidx   = csr_woff + 2048;
    int* csr_msrc   = csr_eidx + N_EDGES;

    float* out = (float*)d_out;

    // zero: out, [RE2 | RN2 | RS2 | invS | node_bf | edge_bf], csr_counts
    int zstats = 4 * NREP * RSTRIDE + 2 * NREP * SSTRIDE + SSTRIDE;
    int zlen = zstats + (NODE_ROWS_PAD * HP + N_EDGES * HP) / 2;
    zero_buf<<<(N_NODES * N_NODES + 1 + 255) / 256, 256, 0, stream>>>(out, N_NODES * N_NODES + 1);
    zero_buf<<<(zlen + 255) / 256, 256, 0, stream>>>(RE2, zlen);
    zero_buf<<<8, 256, 0, stream>>>((float*)csr_counts, 2048);

    convert_weights_t<<<12000, 256, 0, stream>>>(eU_W, eW_W, nU_W, nV_W, Wt_all);
    convert_wtk<<<(30 * WMAT + 255) / 256, 256, 0, stream>>>(Wt_all, WtK_all);
    csr_hist<<<(N_EDGES + 255) / 256, 256, 0, stream>>>(dst, csr_counts);
    csr_scan<<<1, 256, 0, stream>>>(csr_counts, csr_offs, csr_woff);
    csr_scatter<<<(N_EDGES + 255) / 256, 256, 0, stream>>>(src, dst, csr_woff, csr_eidx, csr_msrc);
    node_embed<<<(NH + 255) / 256, 256, 0, stream>>>(x, node_emb_W, node_emb_b, node, node_bf);
    edge_embed<<<NEB, 256, 0, stream>>>(edge_attr, edge_d_W, edge_d_b,
                                        edge_t_W, edge_t_b, edge_bf, RS2);

    for (int l = 0; l < NLAYERS; ++l) {
        float* REc = RE2 + (size_t)(l & 1) * NREP * RSTRIDE;
        float* REo = RE2 + (size_t)((l + 1) & 1) * NREP * RSTRIDE;
        float* RNc = RN2 + (size_t)(l & 1) * NREP * RSTRIDE;
        float* RNo = RN2 + (size_t)((l + 1) & 1) * NREP * RSTRIDE;
        float* RScur = RS2 + (size_t)(l & 1) * NREP * SSTRIDE;
        float* RSnxt = RS2 + (size_t)((l + 1) & 1) * NREP * SSTRIDE;
        const bf16* WtK_l = WtK_all + (size_t)l * WMAT;

        gemm_node<<<1505, 64, 0, stream>>>(node_bf, Wt_all, eU_b, nV_b, nU_b, l,
                                           nodeU, nodeV, nodeUn, RScur, RSnxt, invS);
        gemm_edge<<<1000, 256, 0, stream>>>(edge_bf, WtK_l, nodeU, src, dst,
                                            gate_bf, REc);
        node_msg<<<N_NODES / 2, 320, 0, stream>>>(edge_bf, nodeV, nodeUn,
                                                  csr_offs, csr_eidx, csr_msrc,
                                                  invS, RNc, aggv);
        fused_final<<<NEB + NUB, 256, 0, stream>>>(edge_bf, gate_bf,
                                                   REc, REo, RNc, RNo, RSnxt,
                                                   bn_e_g + l * H, bn_e_b + l * H,
                                                   bn_n_g + l * H, bn_n_b + l * H,
                                                   node, node_bf, aggv);
    }

    classify_loss<<<500, 256, 0, stream>>>(edge_bf, cls_W, cls_b, src, dst, y, out);
}

// Round 15
// 2407.491 us; speedup vs baseline: 1.3455x; 1.0577x over previous
//
#include <hip/hip_runtime.h>
#include <hip/hip_bf16.h>
#include <math.h>

#define N_NODES 2000
#define N_EDGES 32000
#define H 300
#define CH 75             // H/4 float4 chunks per row
#define HP 320            // padded H for MFMA K/N
#define NLAYERS 30
#define NH (N_NODES * H)     // 600000
#define NODE_ROWS_PAD 2048
#define WMAT (HP * HP)       // 102400 per K-packed matrix
#define NREP 32              // stat replicas
#define RSTRIDE 608          // replica row stride (sum | sumsq at +304)
#define SSTRIDE 304
#define NEB 500              // edge-finalize blocks (32000/64)
#define NUB 147              // node_update blocks (1024 chunks each)

typedef short bf16x8 __attribute__((ext_vector_type(8)));
typedef float f32x4 __attribute__((ext_vector_type(4)));
typedef __hip_bfloat16 bf16;

__device__ __forceinline__ float sigm(float x) { return 1.f / (1.f + __expf(-x)); }

// ---------------------------------------------------------------- utilities
__global__ __launch_bounds__(256) void zero_buf(float* __restrict__ p, int n) {
    int i = blockIdx.x * blockDim.x + threadIdx.x;
    if (i < n) p[i] = 0.f;
}

// ---- weights -> bf16, K-packed: WtK[m][ct4][kc][c][j] = W_m[k=kc*8+j][n=ct4*80+c]
// single pass, LDS 32x32 tile; reads and writes both coalesced
__global__ __launch_bounds__(256) void convert_weights_k(const float* __restrict__ eU,
                                                         const float* __restrict__ eW,
                                                         const float* __restrict__ nU,
                                                         const float* __restrict__ nV,
                                                         bf16* __restrict__ WtK) {
    __shared__ float tile[32][33];
    int b = blockIdx.x;                 // 120 mats x 100 tiles
    int m = b / 100;
    int rem = b % 100;
    int kt = rem / 10, nt = rem % 10;
    int k0 = kt * 32, n0 = nt * 32;
    int grp = m / NLAYERS, l = m % NLAYERS;
    const float* S = (grp == 0) ? eU : (grp == 1) ? eW : (grp == 2) ? nU : nV;
    const float* Sl = S + (size_t)l * H * H;
    int t = threadIdx.x;
    int tn = t & 31, tk = t >> 5;
#pragma unroll
    for (int p = 0; p < 4; ++p) {
        int k = tk + p * 8;
        int gk = k0 + k, gn = n0 + tn;
        tile[k][tn] = (gk < H && gn < H) ? Sl[(size_t)gk * H + gn] : 0.f;
    }
    __syncthreads();
    bf16* D = WtK + (size_t)m * WMAT;
    int nn = t >> 3, j8 = t & 7;
    int n = n0 + nn;
    int ct4 = n / 80, c = n % 80;
#pragma unroll
    for (int p = 0; p < 4; ++p) {
        int kc = (k0 >> 3) + p;
        D[(size_t)ct4 * 25600 + (size_t)kc * 640 + c * 8 + j8] =
            __float2bfloat16(tile[p * 8 + j8][nn]);
    }
}

// ------------------------------------------------------------- CSR by dst
__global__ __launch_bounds__(256) void csr_hist(const int* __restrict__ dst,
                                                int* __restrict__ counts) {
    int i = blockIdx.x * 256 + threadIdx.x;
    if (i < N_EDGES) atomicAdd(&counts[dst[i]], 1);
}

__global__ __launch_bounds__(256) void csr_scan(const int* __restrict__ counts,
                                                int* __restrict__ offs,
                                                int* __restrict__ woff) {
    __shared__ int part[256];
    int t = threadIdx.x;
    int base = t * 8;
    int local[8];
    int s = 0;
#pragma unroll
    for (int j = 0; j < 8; ++j) {
        int c = (base + j < N_NODES) ? counts[base + j] : 0;
        local[j] = s;
        s += c;
    }
    part[t] = s;
    __syncthreads();
    for (int off = 1; off < 256; off <<= 1) {
        int v = (t >= off) ? part[t - off] : 0;
        __syncthreads();
        part[t] += v;
        __syncthreads();
    }
    int pre = (t == 0) ? 0 : part[t - 1];
#pragma unroll
    for (int j = 0; j < 8; ++j) {
        int idx = base + j;
        if (idx < N_NODES) { int v = pre + local[j]; offs[idx] = v; woff[idx] = v; }
    }
    if (t == 255) offs[N_NODES] = part[255];
}

__global__ __launch_bounds__(256) void csr_scatter(const int* __restrict__ src,
                                                   const int* __restrict__ dst,
                                                   int* __restrict__ woff,
                                                   int* __restrict__ eidx,
                                                   int* __restrict__ msrc) {
    int i = blockIdx.x * 256 + threadIdx.x;
    if (i < N_EDGES) {
        int p = atomicAdd(&woff[dst[i]], 1);
        eidx[p] = i;
        msrc[p] = src[i];
    }
}

// ---------------------------------------------------------------- embeddings
__global__ __launch_bounds__(256) void node_embed(const float* __restrict__ x,
                                                  const float* __restrict__ W,
                                                  const float* __restrict__ b,
                                                  float* __restrict__ node,
                                                  bf16* __restrict__ node_bf) {
    int i = blockIdx.x * blockDim.x + threadIdx.x;
    if (i >= NH) return;
    int n = i / H, h = i % H;
    float acc = b[h];
#pragma unroll
    for (int k = 0; k < 4; ++k) acc += x[n * 4 + k] * W[k * H + h];
    node[i] = acc;
    node_bf[(size_t)n * HP + h] = __float2bfloat16(acc);
}

// edge embedding, bf16 only, col-chunk ownership; sigmoid colsum -> RS0
__global__ __launch_bounds__(256) void edge_embed(const float* __restrict__ ea,
                                                  const float* __restrict__ dW,
                                                  const float* __restrict__ db,
                                                  const float* __restrict__ tW,
                                                  const float* __restrict__ tb,
                                                  bf16* __restrict__ edge_bf,
                                                  float* __restrict__ RS0) {
    __shared__ float s_s[SSTRIDE];
    int t = threadIdx.x;
    for (int i = t; i < SSTRIDE; i += 256) s_s[i] = 0.f;
    __syncthreads();
    int hc = t % 80, rgrp = t / 80;
    int col0 = hc * 4;
    float ss[4] = {0.f, 0.f, 0.f, 0.f};
    if (hc < CH && rgrp < 3) {
        float wv[4], bv[4];
#pragma unroll
        for (int j = 0; j < 4; ++j) {
            int col = col0 + j;
            wv[j] = (col < 150) ? dW[col] : tW[col - 150];
            bv[j] = (col < 150) ? db[col] : tb[col - 150];
        }
        int e0 = blockIdx.x * 64;
        for (int r = rgrp; r < 64; r += 3) {
            int e = e0 + r;
            float d = ea[2 * e], tt = ea[2 * e + 1];
            union { ushort4 u; bf16 b[4]; } ob;
#pragma unroll
            for (int j = 0; j < 4; ++j) {
                int col = col0 + j;
                float v = ((col < 150) ? d : tt) * wv[j] + bv[j];
                ob.b[j] = __float2bfloat16(v);
                ss[j] += sigm(__bfloat162float(ob.b[j]));
            }
            *(ushort4*)(edge_bf + (size_t)e * HP + col0) = ob.u;
        }
#pragma unroll
        for (int j = 0; j < 4; ++j) atomicAdd(&s_s[col0 + j], ss[j]);
    }
    __syncthreads();
    float* rs = RS0 + (size_t)(blockIdx.x & (NREP - 1)) * SSTRIDE;
    for (int i = t; i < H; i += 256) atomicAdd(&rs[i], s_s[i]);
}

// ---- K1: node GEMMs (1500 one-wave blocks, K-packed B) + 5 housekeeping blocks
__global__ __launch_bounds__(64) void gemm_node(const bf16* __restrict__ node_bf,
                                                const bf16* __restrict__ WtK_all,
                                                const float* __restrict__ eU_b,
                                                const float* __restrict__ nV_b,
                                                const float* __restrict__ nU_b,
                                                int layer,
                                                float* __restrict__ nodeU,
                                                float* __restrict__ nodeV,
                                                float* __restrict__ nodeUn,
                                                const float* __restrict__ RScur,
                                                float* __restrict__ RSnxt,
                                                float* __restrict__ invS) {
    int bx = blockIdx.x;
    int lane = threadIdx.x;
    if (bx >= 1500) {
        int idx = bx - 1500;               // 0..4
        int c = idx * 64 + lane;           // 0..319
        if (c < H) {
            float ssr = 0.f;
#pragma unroll 8
            for (int r = 0; r < NREP; ++r) ssr += RScur[r * SSTRIDE + c];
            invS[c] = 1.f / (ssr + 1e-20f);
        }
        for (int i = idx * 64 + lane; i < NREP * SSTRIDE; i += 320) RSnxt[i] = 0.f;
        return;
    }
    int mat = bx / 500;
    int rem = bx % 500;
    int rt0 = rem >> 2, ct4 = rem & 3;
    int m; const float* bias; float* out;
    if (mat == 0)      { m = layer;      bias = eU_b + layer * H; out = nodeU; }
    else if (mat == 1) { m = 90 + layer; bias = nV_b + layer * H; out = nodeV; }
    else               { m = 60 + layer; bias = nU_b + layer * H; out = nodeUn; }
    const bf16* Bw = WtK_all + (size_t)m * WMAT + (size_t)ct4 * 25600;
    int row0 = rt0 * 16, c0 = ct4 * 80;
    int rlo = lane & 15, khi = lane >> 4;
    f32x4 acc[5];
#pragma unroll
    for (int ct = 0; ct < 5; ++ct) acc[ct] = (f32x4)0.f;
#pragma unroll 2
    for (int ks = 0; ks < 10; ++ks) {
        int kk = ks * 32 + khi * 8;
        int kcb = (ks * 4 + khi) * 80;
        bf16x8 a, b[5];
        a = *(const bf16x8*)(node_bf + (size_t)(row0 + rlo) * HP + kk);
#pragma unroll
        for (int ct = 0; ct < 5; ++ct)
            b[ct] = *(const bf16x8*)(Bw + (size_t)(kcb + ct * 16 + rlo) * 8);
#pragma unroll
        for (int ct = 0; ct < 5; ++ct)
            acc[ct] = __builtin_amdgcn_mfma_f32_16x16x32_bf16(a, b[ct], acc[ct], 0, 0, 0);
    }
    int rhi = lane >> 4;
#pragma unroll
    for (int ct = 0; ct < 5; ++ct) {
        int col = c0 + ct * 16 + rlo;
        if (col >= H) continue;
        float bv = bias[col];
#pragma unroll
        for (int j = 0; j < 4; ++j) {
            int r = row0 + rhi * 4 + j;
            out[(size_t)r * H + col] = acc[ct][j] + bv;
        }
    }
}

// ---- K2 fused: edge gate GEMM (bx<1000, LDS-A + K-packed B) || CSR gather (bx>=1000)
__global__ __launch_bounds__(256) void fused_mid(const bf16* __restrict__ edge_bf,
                                                 const bf16* __restrict__ WtK_l,
                                                 const float* __restrict__ nodeU,
                                                 const int* __restrict__ src,
                                                 const int* __restrict__ dst,
                                                 bf16* __restrict__ gate_bf,
                                                 float* __restrict__ REc,
                                                 const float* __restrict__ nodeV,
                                                 const float* __restrict__ nodeUn,
                                                 const int* __restrict__ offs,
                                                 const int* __restrict__ eidx,
                                                 const int* __restrict__ msrc,
                                                 const float* __restrict__ invS,
                                                 float* __restrict__ RNc,
                                                 float* __restrict__ aggv) {
    __shared__ bf16 smA[32 * 320];         // 20 KB
    int tid = threadIdx.x;
    int bx = blockIdx.x;
    if (bx < 1000) {
        int wave = tid >> 6, lane = tid & 63;
        int row0 = bx * 32;
        int c0 = wave * 80;
        int rlo = lane & 15, khi = lane >> 4, rhi = lane >> 4;

        // hoist src/dst index loads
        int se_[8], de_[8];
#pragma unroll
        for (int rt = 0; rt < 2; ++rt)
#pragma unroll
            for (int j = 0; j < 4; ++j) {
                int r = row0 + rt * 16 + rhi * 4 + j;
                se_[rt * 4 + j] = src[r];
                de_[rt * 4 + j] = dst[r];
            }

        // stage A: fully coalesced 20480B contiguous span, XOR-swizzled
        const uint4* Ag = (const uint4*)(edge_bf + (size_t)row0 * HP);
#pragma unroll
        for (int it = 0; it < 5; ++it) {
            int cid = it * 256 + tid;      // 0..1279
            int row = cid / 40, ch = cid % 40;
            uint4 v = Ag[cid];
            *(uint4*)(smA + row * 320 + ((ch ^ (row & 7)) << 3)) = v;
        }
        __syncthreads();

        const bf16* Bw = WtK_l + (size_t)wave * 25600;
        f32x4 acc[2][5];
#pragma unroll
        for (int rt = 0; rt < 2; ++rt)
#pragma unroll
            for (int ct = 0; ct < 5; ++ct) acc[rt][ct] = (f32x4)0.f;
#pragma unroll 2
        for (int ks = 0; ks < 10; ++ks) {
            int c = ks * 4 + khi;
            int kcb = (ks * 4 + khi) * 80;
            bf16x8 a[2], b[5];
#pragma unroll
            for (int rt = 0; rt < 2; ++rt) {
                int row = rt * 16 + rlo;
                a[rt] = *(const bf16x8*)(smA + row * 320 + ((c ^ (row & 7)) << 3));
            }
#pragma unroll
            for (int ct = 0; ct < 5; ++ct)
                b[ct] = *(const bf16x8*)(Bw + (size_t)(kcb + ct * 16 + rlo) * 8);
#pragma unroll
            for (int rt = 0; rt < 2; ++rt)
#pragma unroll
                for (int ct = 0; ct < 5; ++ct)
                    acc[rt][ct] = __builtin_amdgcn_mfma_f32_16x16x32_bf16(a[rt], b[ct], acc[rt][ct], 0, 0, 0);
        }
        float csum[5], csq[5];
#pragma unroll
        for (int ct = 0; ct < 5; ++ct) { csum[ct] = 0.f; csq[ct] = 0.f; }
#pragma unroll
        for (int rt = 0; rt < 2; ++rt)
#pragma unroll
            for (int j = 0; j < 4; ++j) {
                int r = row0 + rt * 16 + rhi * 4 + j;
                int se = se_[rt * 4 + j], de = de_[rt * 4 + j];
#pragma unroll
                for (int ct = 0; ct < 5; ++ct) {
                    int col = c0 + ct * 16 + rlo;
                    if (col < H) {
                        float g = acc[rt][ct][j] + nodeU[(size_t)se * H + col] + nodeU[(size_t)de * H + col];
                        gate_bf[(size_t)r * H + col] = __float2bfloat16(g);
                        csum[ct] += g;
                        csq[ct] += g * g;
                    }
                }
            }
#pragma unroll
        for (int ct = 0; ct < 5; ++ct) {
            csum[ct] += __shfl_xor(csum[ct], 16, 64);
            csum[ct] += __shfl_xor(csum[ct], 32, 64);
            csq[ct]  += __shfl_xor(csq[ct], 16, 64);
            csq[ct]  += __shfl_xor(csq[ct], 32, 64);
        }
        if (khi == 0) {
            float* re = REc + (size_t)(bx & (NREP - 1)) * RSTRIDE;
#pragma unroll
            for (int ct = 0; ct < 5; ++ct) {
                int col = c0 + ct * 16 + rlo;
                if (col < H) {
                    atomicAdd(&re[col], csum[ct]);
                    atomicAdd(&re[SSTRIDE + col], csq[ct]);
                }
            }
        }
    } else {
        // ------- CSR gather: 2 nodes/block, 256 threads (h and h+256)
        int nb = bx - 1000;                // 0..999
        int h0 = tid;
        bool has1 = (tid < H - 256);
        int h1 = 256 + tid;
        float inv0 = invS[h0];
        float inv1 = has1 ? invS[h1] : 0.f;
        float st10 = 0.f, st20 = 0.f, st11 = 0.f, st21 = 0.f;
        int n0 = nb * 2;
#pragma unroll
        for (int k = 0; k < 2; ++k) {
            int n = n0 + k;
            int beg = offs[n], end = offs[n + 1];
            float a0 = 0.f, a1 = 0.f;
            for (int i = beg; i < end; ++i) {
                int e = eidx[i];
                int s = msrc[i];
                const bf16* er = edge_bf + (size_t)e * HP;
                const float* vr = nodeV + (size_t)s * H;
                a0 += sigm(__bfloat162float(er[h0])) * vr[h0];
                if (has1) a1 += sigm(__bfloat162float(er[h1])) * vr[h1];
            }
            size_t nbase = (size_t)n * H;
            float v0 = nodeUn[nbase + h0] + a0 * inv0;
            aggv[nbase + h0] = v0;
            st10 += v0; st20 += v0 * v0;
            if (has1) {
                float v1 = nodeUn[nbase + h1] + a1 * inv1;
                aggv[nbase + h1] = v1;
                st11 += v1; st21 += v1 * v1;
            }
        }
        float* rn = RNc + (size_t)(nb & (NREP - 1)) * RSTRIDE;
        atomicAdd(&rn[h0], st10);
        atomicAdd(&rn[SSTRIDE + h0], st20);
        if (has1) {
            atomicAdd(&rn[h1], st11);
            atomicAdd(&rn[SSTRIDE + h1], st21);
        }
    }
}

// ------------- K3: edge_finalize (bx<NEB) || node_update (bx>=NEB), bf16 residual
__global__ __launch_bounds__(256) void fused_final(bf16* __restrict__ edge_bf,
                                                   const bf16* __restrict__ gate_bf,
                                                   const float* __restrict__ REc,
                                                   float* __restrict__ REo,
                                                   const float* __restrict__ RNc,
                                                   float* __restrict__ RNo,
                                                   float* __restrict__ RSnext,
                                                   const float* __restrict__ eg,
                                                   const float* __restrict__ ebt,
                                                   const float* __restrict__ ng,
                                                   const float* __restrict__ nbt,
                                                   float* __restrict__ node,
                                                   bf16* __restrict__ node_bf,
                                                   const float* __restrict__ aggv) {
    __shared__ float sc_s[SSTRIDE], of_s[SSTRIDE], s_s[SSTRIDE];
    int bx = blockIdx.x, t = threadIdx.x;
    if (bx < NEB) {
        const float invE = 1.f / N_EDGES;
        for (int i = t; i < SSTRIDE; i += 256) {
            s_s[i] = 0.f;
            if (i < H) {
                float gs = 0.f, gq = 0.f;
#pragma unroll 8
                for (int r = 0; r < NREP; ++r) {
                    gs += REc[r * RSTRIDE + i];
                    gq += REc[r * RSTRIDE + SSTRIDE + i];
                }
                float mean = gs * invE;
                float var = fmaxf(gq * invE - mean * mean, 0.f);
                float rstd = rsqrtf(var + 1e-5f);
                float sc = rstd * eg[i];
                sc_s[i] = sc;
                of_s[i] = ebt[i] - mean * sc;
            }
        }
        __syncthreads();
        int hc = t % 80, rgrp = t / 80;
        bool act = (hc < CH) && (rgrp < 3);
        float ss[4] = {0.f, 0.f, 0.f, 0.f};
        int col0 = hc * 4;
        if (act) {
            float sc[4], of[4];
#pragma unroll
            for (int j = 0; j < 4; ++j) { sc[j] = sc_s[col0 + j]; of[j] = of_s[col0 + j]; }
            int e0 = bx * 64;
            for (int r = rgrp; r < 64; r += 3) {
                int e = e0 + r;
                union { ushort4 u; bf16 b[4]; } eb, gv, ob;
                eb.u = *(const ushort4*)(edge_bf + (size_t)e * HP + col0);
                gv.u = *(const ushort4*)(gate_bf + (size_t)e * H + col0);
#pragma unroll
                for (int j = 0; j < 4; ++j) {
                    float g = __bfloat162float(gv.b[j]);
                    float val = fmaxf(fmaf(g, sc[j], of[j]), 0.f);
                    float nv = __bfloat162float(eb.b[j]) + val;
                    ob.b[j] = __float2bfloat16(nv);
                    ss[j] += sigm(__bfloat162float(ob.b[j]));
                }
                *(ushort4*)(edge_bf + (size_t)e * HP + col0) = ob.u;
            }
#pragma unroll
            for (int j = 0; j < 4; ++j) atomicAdd(&s_s[col0 + j], ss[j]);
        }
        __syncthreads();
        float* rs = RSnext + (size_t)(bx & (NREP - 1)) * SSTRIDE;
        for (int i = t; i < H; i += 256) atomicAdd(&rs[i], s_s[i]);
    } else {
        int idx = bx - NEB;                // 0..NUB-1
        if (idx < NREP) {
            for (int i = t; i < RSTRIDE; i += 256) {
                REo[(size_t)idx * RSTRIDE + i] = 0.f;
                RNo[(size_t)idx * RSTRIDE + i] = 0.f;
            }
        }
        const float invN = 1.f / N_NODES;
        for (int i = t; i < H; i += 256) {
            float ns = 0.f, nq = 0.f;
#pragma unroll 8
            for (int r = 0; r < NREP; ++r) {
                ns += RNc[r * RSTRIDE + i];
                nq += RNc[r * RSTRIDE + SSTRIDE + i];
            }
            float mean = ns * invN;
            float var = fmaxf(nq * invN - mean * mean, 0.f);
            float rstd = rsqrtf(var + 1e-5f);
            float sc = rstd * ng[i];
            sc_s[i] = sc;
            of_s[i] = nbt[i] - mean * sc;
        }
        __syncthreads();
#pragma unroll
        for (int it = 0; it < 4; ++it) {
            int c = idx * 1024 + it * 256 + t;
            if (c >= NH / 4) break;
            int n = c / CH, hc = c % CH, col0 = hc * 4;
            float4 v4 = ((const float4*)aggv)[c];
            float4 nd = ((const float4*)node)[c];
            const float* v4p = (const float*)&v4;
            const float* ndp = (const float*)&nd;
            union { ushort4 u; bf16 b[4]; } ob;
            float outv[4];
#pragma unroll
            for (int j = 0; j < 4; ++j) {
                float g = fmaf(v4p[j], sc_s[col0 + j], of_s[col0 + j]);
                outv[j] = ndp[j] + fmaxf(g, 0.f);
                ob.b[j] = __float2bfloat16(outv[j]);
            }
            ((float4*)node)[c] = make_float4(outv[0], outv[1], outv[2], outv[3]);
            *(ushort4*)(node_bf + (size_t)n * HP + col0) = ob.u;
        }
    }
}

// ----------------- classifier + loss: 4 lanes/edge, vectorized, clsW in regs
__global__ __launch_bounds__(256) void classify_loss(const bf16* __restrict__ edge_bf,
                                                     const float* __restrict__ clsW,
                                                     const float* __restrict__ clsb,
                                                     const int* __restrict__ src,
                                                     const int* __restrict__ dst,
                                                     const float* __restrict__ y,
                                                     float* __restrict__ out) {
    __shared__ float wl[4];
    int lane = threadIdx.x & 63;
    int wid = threadIdx.x >> 6;
    int quad = lane >> 2;
    int ql = lane & 3;
    float w[80];
#pragma unroll
    for (int j = 0; j < 80; ++j) {
        int col = ql * 80 + j;
        w[j] = (col < H) ? clsW[col] : 0.f;
    }
    int g = blockIdx.x * 4 + wid;
    int e = g * 16 + quad;
    const bf16* row = edge_bf + (size_t)e * HP + ql * 80;
    float acc = 0.f;
#pragma unroll
    for (int v = 0; v < 10; ++v) {
        bf16x8 bv = *(const bf16x8*)(row + v * 8);
#pragma unroll
        for (int j = 0; j < 8; ++j)
            acc += __bfloat162float(((const bf16*)&bv)[j]) * w[v * 8 + j];
    }
    acc += __shfl_xor(acc, 1, 64);
    acc += __shfl_xor(acc, 2, 64);
    float lsum = 0.f;
    if (ql == 0) {
        float z = acc + clsb[0];
        float p = 1.f / (1.f + __expf(-z));
        atomicAdd(&out[(size_t)src[e] * N_NODES + dst[e]], p);
        float pc = fminf(fmaxf(p, 1e-7f), 1.f - 1e-7f);
        lsum = -(y[e] * __logf(pc) + (1.f - y[e]) * log1pf(-pc));
    }
#pragma unroll
    for (int off = 32; off > 0; off >>= 1) lsum += __shfl_down(lsum, off, 64);
    if (lane == 0) wl[wid] = lsum;
    __syncthreads();
    if (threadIdx.x == 0) {
        float tt = wl[0] + wl[1] + wl[2] + wl[3];
        atomicAdd(&out[(size_t)N_NODES * N_NODES], tt * (1.f / N_EDGES));
    }
}

// ---------------------------------------------------------------- launcher
extern "C" void kernel_launch(void* const* d_in, const int* in_sizes, int n_in,
                              void* d_out, int out_size, void* d_ws, size_t ws_size,
                              hipStream_t stream) {
    const float* x          = (const float*)d_in[0];
    const float* edge_attr  = (const float*)d_in[1];
    const int*   edge_index = (const int*)d_in[2];
    const float* y          = (const float*)d_in[3];
    const float* node_emb_W = (const float*)d_in[4];
    const float* node_emb_b = (const float*)d_in[5];
    const float* edge_d_W   = (const float*)d_in[6];
    const float* edge_d_b   = (const float*)d_in[7];
    const float* edge_t_W   = (const float*)d_in[8];
    const float* edge_t_b   = (const float*)d_in[9];
    const float* eU_W = (const float*)d_in[10];
    const float* eU_b = (const float*)d_in[11];
    const float* eW_W = (const float*)d_in[12];
    const float* nU_W = (const float*)d_in[14];
    const float* nU_b = (const float*)d_in[15];
    const float* nV_W = (const float*)d_in[16];
    const float* nV_b = (const float*)d_in[17];
    const float* bn_e_g = (const float*)d_in[18];
    const float* bn_e_b = (const float*)d_in[19];
    const float* bn_n_g = (const float*)d_in[20];
    const float* bn_n_b = (const float*)d_in[21];
    const float* cls_W = (const float*)d_in[22];
    const float* cls_b = (const float*)d_in[23];

    const int* src = edge_index;
    const int* dst = edge_index + N_EDGES;

    float* ws     = (float*)d_ws;
    float* node   = ws;                  // NH
    float* nodeU  = node + NH;           // NH
    float* nodeV  = nodeU + NH;          // NH
    float* nodeUn = nodeV + NH;          // NH
    float* aggv   = nodeUn + NH;         // NH
    float* RE2    = aggv + NH;           // 2 x 32*608   <-- zero region start
    float* RN2    = RE2 + 2 * NREP * RSTRIDE;
    float* RS2    = RN2 + 2 * NREP * RSTRIDE;  // 2 x 32*304
    float* invS   = RS2 + 2 * NREP * SSTRIDE;  // 304
    bf16* node_bf = (bf16*)(invS + SSTRIDE);              // 2048*320
    bf16* edge_bf = node_bf + (size_t)NODE_ROWS_PAD * HP; // 32000*320
    bf16* gate_bf = edge_bf + (size_t)N_EDGES * HP;       // 32000*300 (not zeroed)
    bf16* WtK_all = gate_bf + (size_t)N_EDGES * H;        // 120*102400 (K-packed)
    int* csr_counts = (int*)(WtK_all + (size_t)120 * WMAT);
    int* csr_offs   = csr_counts + 2048;
    int* csr_woff   = csr_offs + 2048;
    int* csr_eidx   = csr_woff + 2048;
    int* csr_msrc   = csr_eidx + N_EDGES;

    float* out = (float*)d_out;

    // zero: out, [RE2 | RN2 | RS2 | invS | node_bf | edge_bf], csr_counts
    int zstats = 4 * NREP * RSTRIDE + 2 * NREP * SSTRIDE + SSTRIDE;
    int zlen = zstats + (NODE_ROWS_PAD * HP + N_EDGES * HP) / 2;
    zero_buf<<<(N_NODES * N_NODES + 1 + 255) / 256, 256, 0, stream>>>(out, N_NODES * N_NODES + 1);
    zero_buf<<<(zlen + 255) / 256, 256, 0, stream>>>(RE2, zlen);
    zero_buf<<<8, 256, 0, stream>>>((float*)csr_counts, 2048);

    convert_weights_k<<<12000, 256, 0, stream>>>(eU_W, eW_W, nU_W, nV_W, WtK_all);
    csr_hist<<<(N_EDGES + 255) / 256, 256, 0, stream>>>(dst, csr_counts);
    csr_scan<<<1, 256, 0, stream>>>(csr_counts, csr_offs, csr_woff);
    csr_scatter<<<(N_EDGES + 255) / 256, 256, 0, stream>>>(src, dst, csr_woff, csr_eidx, csr_msrc);
    node_embed<<<(NH + 255) / 256, 256, 0, stream>>>(x, node_emb_W, node_emb_b, node, node_bf);
    edge_embed<<<NEB, 256, 0, stream>>>(edge_attr, edge_d_W, edge_d_b,
                                        edge_t_W, edge_t_b, edge_bf, RS2);

    for (int l = 0; l < NLAYERS; ++l) {
        float* REc = RE2 + (size_t)(l & 1) * NREP * RSTRIDE;
        float* REo = RE2 + (size_t)((l + 1) & 1) * NREP * RSTRIDE;
        float* RNc = RN2 + (size_t)(l & 1) * NREP * RSTRIDE;
        float* RNo = RN2 + (size_t)((l + 1) & 1) * NREP * RSTRIDE;
        float* RScur = RS2 + (size_t)(l & 1) * NREP * SSTRIDE;
        float* RSnxt = RS2 + (size_t)((l + 1) & 1) * NREP * SSTRIDE;
        const bf16* WtK_e = WtK_all + (size_t)(30 + l) * WMAT;

        gemm_node<<<1505, 64, 0, stream>>>(node_bf, WtK_all, eU_b, nV_b, nU_b, l,
                                           nodeU, nodeV, nodeUn, RScur, RSnxt, invS);
        fused_mid<<<2000, 256, 0, stream>>>(edge_bf, WtK_e, nodeU, src, dst,
                                            gate_bf, REc,
                                            nodeV, nodeUn, csr_offs, csr_eidx, csr_msrc,
                                            invS, RNc, aggv);
        fused_final<<<NEB + NUB, 256, 0, stream>>>(edge_bf, gate_bf,
                                                   REc, REo, RNc, RNo, RSnxt,
                                                   bn_e_g + l * H, bn_e_b + l * H,
                                                   bn_n_g + l * H, bn_n_b + l * H,
                                                   node, node_bf, aggv);
    }

    classify_loss<<<500, 256, 0, stream>>>(edge_bf, cls_W, cls_b, src, dst, y, out);
}

// Round 16
// 2368.009 us; speedup vs baseline: 1.3680x; 1.0167x over previous
//
#include <hip/hip_runtime.h>
#include <hip/hip_bf16.h>
#include <math.h>

#define N_NODES 2000
#define N_EDGES 32000
#define H 300
#define CH 75             // H/4 float4 chunks per row
#define HP 320            // padded H for MFMA K/N
#define NLAYERS 30
#define NH (N_NODES * H)     // 600000
#define NODE_ROWS_PAD 2048
#define WMAT (HP * HP)       // 102400 per K-packed matrix
#define NREP 32              // stat replicas
#define RSTRIDE 608          // replica row stride (sum | sumsq at +304)
#define SSTRIDE 304
#define NEB 500              // edge blocks (32000/64)
#define NUB 147              // node_update blocks (1024 chunks each)

typedef short bf16x8 __attribute__((ext_vector_type(8)));
typedef float f32x4 __attribute__((ext_vector_type(4)));
typedef __hip_bfloat16 bf16;

__device__ __forceinline__ float sigm(float x) { return 1.f / (1.f + __expf(-x)); }

// ---------------------------------------------------------------- utilities
__global__ __launch_bounds__(256) void zero_buf(float* __restrict__ p, int n) {
    int i = blockIdx.x * blockDim.x + threadIdx.x;
    if (i < n) p[i] = 0.f;
}

// ---- weights -> bf16, K-packed: WtK[m][ct4][kc][c][j] = W_m[k=kc*8+j][n=ct4*80+c]
__global__ __launch_bounds__(256) void convert_weights_k(const float* __restrict__ eU,
                                                         const float* __restrict__ eW,
                                                         const float* __restrict__ nU,
                                                         const float* __restrict__ nV,
                                                         bf16* __restrict__ WtK) {
    __shared__ float tile[32][33];
    int b = blockIdx.x;                 // 120 mats x 100 tiles
    int m = b / 100;
    int rem = b % 100;
    int kt = rem / 10, nt = rem % 10;
    int k0 = kt * 32, n0 = nt * 32;
    int grp = m / NLAYERS, l = m % NLAYERS;
    const float* S = (grp == 0) ? eU : (grp == 1) ? eW : (grp == 2) ? nU : nV;
    const float* Sl = S + (size_t)l * H * H;
    int t = threadIdx.x;
    int tn = t & 31, tk = t >> 5;
#pragma unroll
    for (int p = 0; p < 4; ++p) {
        int k = tk + p * 8;
        int gk = k0 + k, gn = n0 + tn;
        tile[k][tn] = (gk < H && gn < H) ? Sl[(size_t)gk * H + gn] : 0.f;
    }
    __syncthreads();
    bf16* D = WtK + (size_t)m * WMAT;
    int nn = t >> 3, j8 = t & 7;
    int n = n0 + nn;
    int ct4 = n / 80, c = n % 80;
#pragma unroll
    for (int p = 0; p < 4; ++p) {
        int kc = (k0 >> 3) + p;
        D[(size_t)ct4 * 25600 + (size_t)kc * 640 + c * 8 + j8] =
            __float2bfloat16(tile[p * 8 + j8][nn]);
    }
}

// ------------------------------------------------------------- CSR by dst
__global__ __launch_bounds__(256) void csr_hist(const int* __restrict__ dst,
                                                int* __restrict__ counts) {
    int i = blockIdx.x * 256 + threadIdx.x;
    if (i < N_EDGES) atomicAdd(&counts[dst[i]], 1);
}

__global__ __launch_bounds__(256) void csr_scan(const int* __restrict__ counts,
                                                int* __restrict__ offs,
                                                int* __restrict__ woff) {
    __shared__ int part[256];
    int t = threadIdx.x;
    int base = t * 8;
    int local[8];
    int s = 0;
#pragma unroll
    for (int j = 0; j < 8; ++j) {
        int c = (base + j < N_NODES) ? counts[base + j] : 0;
        local[j] = s;
        s += c;
    }
    part[t] = s;
    __syncthreads();
    for (int off = 1; off < 256; off <<= 1) {
        int v = (t >= off) ? part[t - off] : 0;
        __syncthreads();
        part[t] += v;
        __syncthreads();
    }
    int pre = (t == 0) ? 0 : part[t - 1];
#pragma unroll
    for (int j = 0; j < 8; ++j) {
        int idx = base + j;
        if (idx < N_NODES) { int v = pre + local[j]; offs[idx] = v; woff[idx] = v; }
    }
    if (t == 255) offs[N_NODES] = part[255];
}

// sorted position p <- original edge i; store perm and permuted src/dst
__global__ __launch_bounds__(256) void csr_scatter(const int* __restrict__ src,
                                                   const int* __restrict__ dst,
                                                   int* __restrict__ woff,
                                                   int* __restrict__ eidx,
                                                   int* __restrict__ msrc,
                                                   int* __restrict__ mdst) {
    int i = blockIdx.x * 256 + threadIdx.x;
    if (i < N_EDGES) {
        int d = dst[i];
        int p = atomicAdd(&woff[d], 1);
        eidx[p] = i;
        msrc[p] = src[i];
        mdst[p] = d;
    }
}

// ---------------------------------------------------------------- embeddings
__global__ __launch_bounds__(256) void node_embed(const float* __restrict__ x,
                                                  const float* __restrict__ W,
                                                  const float* __restrict__ b,
                                                  float* __restrict__ node,
                                                  bf16* __restrict__ node_bf) {
    int i = blockIdx.x * blockDim.x + threadIdx.x;
    if (i >= NH) return;
    int n = i / H, h = i % H;
    float acc = b[h];
#pragma unroll
    for (int k = 0; k < 4; ++k) acc += x[n * 4 + k] * W[k * H + h];
    node[i] = acc;
    node_bf[(size_t)n * HP + h] = __float2bfloat16(acc);
}

// edge embedding into SORTED order (row q holds original edge eidx[q])
__global__ __launch_bounds__(256) void edge_embed(const float* __restrict__ ea,
                                                  const int* __restrict__ eidx,
                                                  const float* __restrict__ dW,
                                                  const float* __restrict__ db,
                                                  const float* __restrict__ tW,
                                                  const float* __restrict__ tb,
                                                  bf16* __restrict__ edge_bf,
                                                  float* __restrict__ RS0) {
    __shared__ float s_s[SSTRIDE];
    int t = threadIdx.x;
    for (int i = t; i < SSTRIDE; i += 256) s_s[i] = 0.f;
    __syncthreads();
    int hc = t % 80, rgrp = t / 80;
    int col0 = hc * 4;
    float ss[4] = {0.f, 0.f, 0.f, 0.f};
    if (hc < CH && rgrp < 3) {
        float wv[4], bv[4];
#pragma unroll
        for (int j = 0; j < 4; ++j) {
            int col = col0 + j;
            wv[j] = (col < 150) ? dW[col] : tW[col - 150];
            bv[j] = (col < 150) ? db[col] : tb[col - 150];
        }
        int q0 = blockIdx.x * 64;
        for (int r = rgrp; r < 64; r += 3) {
            int q = q0 + r;
            int e = eidx[q];
            float d = ea[2 * e], tt = ea[2 * e + 1];
            union { ushort4 u; bf16 b[4]; } ob;
#pragma unroll
            for (int j = 0; j < 4; ++j) {
                int col = col0 + j;
                float v = ((col < 150) ? d : tt) * wv[j] + bv[j];
                ob.b[j] = __float2bfloat16(v);
                ss[j] += sigm(__bfloat162float(ob.b[j]));
            }
            *(ushort4*)(edge_bf + (size_t)q * HP + col0) = ob.u;
        }
#pragma unroll
        for (int j = 0; j < 4; ++j) atomicAdd(&s_s[col0 + j], ss[j]);
    }
    __syncthreads();
    float* rs = RS0 + (size_t)(blockIdx.x & (NREP - 1)) * SSTRIDE;
    for (int i = t; i < H; i += 256) atomicAdd(&rs[i], s_s[i]);
}

// ---- K1: node GEMMs (1500 one-wave blocks, K-packed B) + 5 housekeeping blocks
__global__ __launch_bounds__(64) void gemm_node(const bf16* __restrict__ node_bf,
                                                const bf16* __restrict__ WtK_all,
                                                const float* __restrict__ eU_b,
                                                const float* __restrict__ nV_b,
                                                const float* __restrict__ nU_b,
                                                int layer,
                                                float* __restrict__ nodeU,
                                                float* __restrict__ nodeV,
                                                float* __restrict__ nodeUn,
                                                const float* __restrict__ RScur,
                                                float* __restrict__ RSnxt,
                                                float* __restrict__ invS) {
    int bx = blockIdx.x;
    int lane = threadIdx.x;
    if (bx >= 1500) {
        int idx = bx - 1500;               // 0..4
        int c = idx * 64 + lane;           // 0..319
        if (c < H) {
            float ssr = 0.f;
#pragma unroll 8
            for (int r = 0; r < NREP; ++r) ssr += RScur[r * SSTRIDE + c];
            invS[c] = 1.f / (ssr + 1e-20f);
        }
        for (int i = idx * 64 + lane; i < NREP * SSTRIDE; i += 320) RSnxt[i] = 0.f;
        return;
    }
    int mat = bx / 500;
    int rem = bx % 500;
    int rt0 = rem >> 2, ct4 = rem & 3;
    int m; const float* bias; float* out;
    if (mat == 0)      { m = layer;      bias = eU_b + layer * H; out = nodeU; }
    else if (mat == 1) { m = 90 + layer; bias = nV_b + layer * H; out = nodeV; }
    else               { m = 60 + layer; bias = nU_b + layer * H; out = nodeUn; }
    const bf16* Bw = WtK_all + (size_t)m * WMAT + (size_t)ct4 * 25600;
    int row0 = rt0 * 16, c0 = ct4 * 80;
    int rlo = lane & 15, khi = lane >> 4;
    f32x4 acc[5];
#pragma unroll
    for (int ct = 0; ct < 5; ++ct) acc[ct] = (f32x4)0.f;
#pragma unroll 2
    for (int ks = 0; ks < 10; ++ks) {
        int kk = ks * 32 + khi * 8;
        int kcb = (ks * 4 + khi) * 80;
        bf16x8 a, b[5];
        a = *(const bf16x8*)(node_bf + (size_t)(row0 + rlo) * HP + kk);
#pragma unroll
        for (int ct = 0; ct < 5; ++ct)
            b[ct] = *(const bf16x8*)(Bw + (size_t)(kcb + ct * 16 + rlo) * 8);
#pragma unroll
        for (int ct = 0; ct < 5; ++ct)
            acc[ct] = __builtin_amdgcn_mfma_f32_16x16x32_bf16(a, b[ct], acc[ct], 0, 0, 0);
    }
    int rhi = lane >> 4;
#pragma unroll
    for (int ct = 0; ct < 5; ++ct) {
        int col = c0 + ct * 16 + rlo;
        if (col >= H) continue;
        float bv = bias[col];
#pragma unroll
        for (int j = 0; j < 4; ++j) {
            int r = row0 + rhi * 4 + j;
            out[(size_t)r * H + col] = acc[ct][j] + bv;
        }
    }
}

// ---- K2 fused: edge gate GEMM (bx<1000) || CSR gather (bx>=1000, SEQUENTIAL rows)
__global__ __launch_bounds__(256) void fused_mid(const bf16* __restrict__ edge_bf,
                                                 const bf16* __restrict__ WtK_l,
                                                 const float* __restrict__ nodeU,
                                                 const int* __restrict__ msrc,
                                                 const int* __restrict__ mdst,
                                                 bf16* __restrict__ gate_bf,
                                                 float* __restrict__ REc,
                                                 const float* __restrict__ nodeV,
                                                 const float* __restrict__ nodeUn,
                                                 const int* __restrict__ offs,
                                                 const float* __restrict__ invS,
                                                 float* __restrict__ RNc,
                                                 float* __restrict__ aggv) {
    __shared__ bf16 smA[32 * 320];         // 20 KB
    int tid = threadIdx.x;
    int bx = blockIdx.x;
    if (bx < 1000) {
        int wave = tid >> 6, lane = tid & 63;
        int row0 = bx * 32;
        int c0 = wave * 80;
        int rlo = lane & 15, khi = lane >> 4, rhi = lane >> 4;

        // hoist permuted src/dst loads (coalesced)
        int se_[8], de_[8];
#pragma unroll
        for (int rt = 0; rt < 2; ++rt)
#pragma unroll
            for (int j = 0; j < 4; ++j) {
                int r = row0 + rt * 16 + rhi * 4 + j;
                se_[rt * 4 + j] = msrc[r];
                de_[rt * 4 + j] = mdst[r];
            }

        // stage A: fully coalesced 20480B contiguous span, XOR-swizzled
        const uint4* Ag = (const uint4*)(edge_bf + (size_t)row0 * HP);
#pragma unroll
        for (int it = 0; it < 5; ++it) {
            int cid = it * 256 + tid;      // 0..1279
            int row = cid / 40, ch = cid % 40;
            uint4 v = Ag[cid];
            *(uint4*)(smA + row * 320 + ((ch ^ (row & 7)) << 3)) = v;
        }
        __syncthreads();

        const bf16* Bw = WtK_l + (size_t)wave * 25600;
        f32x4 acc[2][5];
#pragma unroll
        for (int rt = 0; rt < 2; ++rt)
#pragma unroll
            for (int ct = 0; ct < 5; ++ct) acc[rt][ct] = (f32x4)0.f;
#pragma unroll 2
        for (int ks = 0; ks < 10; ++ks) {
            int c = ks * 4 + khi;
            int kcb = (ks * 4 + khi) * 80;
            bf16x8 a[2], b[5];
#pragma unroll
            for (int rt = 0; rt < 2; ++rt) {
                int row = rt * 16 + rlo;
                a[rt] = *(const bf16x8*)(smA + row * 320 + ((c ^ (row & 7)) << 3));
            }
#pragma unroll
            for (int ct = 0; ct < 5; ++ct)
                b[ct] = *(const bf16x8*)(Bw + (size_t)(kcb + ct * 16 + rlo) * 8);
#pragma unroll
            for (int rt = 0; rt < 2; ++rt)
#pragma unroll
                for (int ct = 0; ct < 5; ++ct)
                    acc[rt][ct] = __builtin_amdgcn_mfma_f32_16x16x32_bf16(a[rt], b[ct], acc[rt][ct], 0, 0, 0);
        }
        float csum[5], csq[5];
#pragma unroll
        for (int ct = 0; ct < 5; ++ct) { csum[ct] = 0.f; csq[ct] = 0.f; }
#pragma unroll
        for (int rt = 0; rt < 2; ++rt)
#pragma unroll
            for (int j = 0; j < 4; ++j) {
                int r = row0 + rt * 16 + rhi * 4 + j;
                int se = se_[rt * 4 + j], de = de_[rt * 4 + j];
#pragma unroll
                for (int ct = 0; ct < 5; ++ct) {
                    int col = c0 + ct * 16 + rlo;
                    if (col < H) {
                        float g = acc[rt][ct][j] + nodeU[(size_t)se * H + col] + nodeU[(size_t)de * H + col];
                        gate_bf[(size_t)r * H + col] = __float2bfloat16(g);
                        csum[ct] += g;
                        csq[ct] += g * g;
                    }
                }
            }
#pragma unroll
        for (int ct = 0; ct < 5; ++ct) {
            csum[ct] += __shfl_xor(csum[ct], 16, 64);
            csum[ct] += __shfl_xor(csum[ct], 32, 64);
            csq[ct]  += __shfl_xor(csq[ct], 16, 64);
            csq[ct]  += __shfl_xor(csq[ct], 32, 64);
        }
        if (khi == 0) {
            float* re = REc + (size_t)(bx & (NREP - 1)) * RSTRIDE;
#pragma unroll
            for (int ct = 0; ct < 5; ++ct) {
                int col = c0 + ct * 16 + rlo;
                if (col < H) {
                    atomicAdd(&re[col], csum[ct]);
                    atomicAdd(&re[SSTRIDE + col], csq[ct]);
                }
            }
        }
    } else {
        // ------- CSR gather: 2 nodes/block; edge rows are CONTIGUOUS (sorted)
        int nb = bx - 1000;                // 0..999
        int h0 = tid;
        bool has1 = (tid < H - 256);
        int h1 = 256 + tid;
        float inv0 = invS[h0];
        float inv1 = has1 ? invS[h1] : 0.f;
        float st10 = 0.f, st20 = 0.f, st11 = 0.f, st21 = 0.f;
        int n0 = nb * 2;
#pragma unroll
        for (int k = 0; k < 2; ++k) {
            int n = n0 + k;
            int beg = offs[n], end = offs[n + 1];
            float a0 = 0.f, a1 = 0.f;
            for (int i = beg; i < end; ++i) {
                int s = msrc[i];
                const bf16* er = edge_bf + (size_t)i * HP;
                const float* vr = nodeV + (size_t)s * H;
                a0 += sigm(__bfloat162float(er[h0])) * vr[h0];
                if (has1) a1 += sigm(__bfloat162float(er[h1])) * vr[h1];
            }
            size_t nbase = (size_t)n * H;
            float v0 = nodeUn[nbase + h0] + a0 * inv0;
            aggv[nbase + h0] = v0;
            st10 += v0; st20 += v0 * v0;
            if (has1) {
                float v1 = nodeUn[nbase + h1] + a1 * inv1;
                aggv[nbase + h1] = v1;
                st11 += v1; st21 += v1 * v1;
            }
        }
        float* rn = RNc + (size_t)(nb & (NREP - 1)) * RSTRIDE;
        atomicAdd(&rn[h0], st10);
        atomicAdd(&rn[SSTRIDE + h0], st20);
        if (has1) {
            atomicAdd(&rn[h1], st11);
            atomicAdd(&rn[SSTRIDE + h1], st21);
        }
    }
}

// ------------- K3: edge_finalize (bx<NEB) || node_update (bx>=NEB), bf16 residual
__global__ __launch_bounds__(256) void fused_final(bf16* __restrict__ edge_bf,
                                                   const bf16* __restrict__ gate_bf,
                                                   const float* __restrict__ REc,
                                                   float* __restrict__ REo,
                                                   const float* __restrict__ RNc,
                                                   float* __restrict__ RNo,
                                                   float* __restrict__ RSnext,
                                                   const float* __restrict__ eg,
                                                   const float* __restrict__ ebt,
                                                   const float* __restrict__ ng,
                                                   const float* __restrict__ nbt,
                                                   float* __restrict__ node,
                                                   bf16* __restrict__ node_bf,
                                                   const float* __restrict__ aggv) {
    __shared__ float sc_s[SSTRIDE], of_s[SSTRIDE], s_s[SSTRIDE];
    int bx = blockIdx.x, t = threadIdx.x;
    if (bx < NEB) {
        const float invE = 1.f / N_EDGES;
        for (int i = t; i < SSTRIDE; i += 256) {
            s_s[i] = 0.f;
            if (i < H) {
                float gs = 0.f, gq = 0.f;
#pragma unroll 8
                for (int r = 0; r < NREP; ++r) {
                    gs += REc[r * RSTRIDE + i];
                    gq += REc[r * RSTRIDE + SSTRIDE + i];
                }
                float mean = gs * invE;
                float var = fmaxf(gq * invE - mean * mean, 0.f);
                float rstd = rsqrtf(var + 1e-5f);
                float sc = rstd * eg[i];
                sc_s[i] = sc;
                of_s[i] = ebt[i] - mean * sc;
            }
        }
        __syncthreads();
        int hc = t % 80, rgrp = t / 80;
        bool act = (hc < CH) && (rgrp < 3);
        float ss[4] = {0.f, 0.f, 0.f, 0.f};
        int col0 = hc * 4;
        if (act) {
            float sc[4], of[4];
#pragma unroll
            for (int j = 0; j < 4; ++j) { sc[j] = sc_s[col0 + j]; of[j] = of_s[col0 + j]; }
            int e0 = bx * 64;
            for (int r = rgrp; r < 64; r += 3) {
                int e = e0 + r;
                union { ushort4 u; bf16 b[4]; } eb, gv, ob;
                eb.u = *(const ushort4*)(edge_bf + (size_t)e * HP + col0);
                gv.u = *(const ushort4*)(gate_bf + (size_t)e * H + col0);
#pragma unroll
                for (int j = 0; j < 4; ++j) {
                    float g = __bfloat162float(gv.b[j]);
                    float val = fmaxf(fmaf(g, sc[j], of[j]), 0.f);
                    float nv = __bfloat162float(eb.b[j]) + val;
                    ob.b[j] = __float2bfloat16(nv);
                    ss[j] += sigm(__bfloat162float(ob.b[j]));
                }
                *(ushort4*)(edge_bf + (size_t)e * HP + col0) = ob.u;
            }
#pragma unroll
            for (int j = 0; j < 4; ++j) atomicAdd(&s_s[col0 + j], ss[j]);
        }
        __syncthreads();
        float* rs = RSnext + (size_t)(bx & (NREP - 1)) * SSTRIDE;
        for (int i = t; i < H; i += 256) atomicAdd(&rs[i], s_s[i]);
    } else {
        int idx = bx - NEB;                // 0..NUB-1
        if (idx < NREP) {
            for (int i = t; i < RSTRIDE; i += 256) {
                REo[(size_t)idx * RSTRIDE + i] = 0.f;
                RNo[(size_t)idx * RSTRIDE + i] = 0.f;
            }
        }
        const float invN = 1.f / N_NODES;
        for (int i = t; i < H; i += 256) {
            float ns = 0.f, nq = 0.f;
#pragma unroll 8
            for (int r = 0; r < NREP; ++r) {
                ns += RNc[r * RSTRIDE + i];
                nq += RNc[r * RSTRIDE + SSTRIDE + i];
            }
            float mean = ns * invN;
            float var = fmaxf(nq * invN - mean * mean, 0.f);
            float rstd = rsqrtf(var + 1e-5f);
            float sc = rstd * ng[i];
            sc_s[i] = sc;
            of_s[i] = nbt[i] - mean * sc;
        }
        __syncthreads();
#pragma unroll
        for (int it = 0; it < 4; ++it) {
            int c = idx * 1024 + it * 256 + t;
            if (c >= NH / 4) break;
            int n = c / CH, hc = c % CH, col0 = hc * 4;
            float4 v4 = ((const float4*)aggv)[c];
            float4 nd = ((const float4*)node)[c];
            const float* v4p = (const float*)&v4;
            const float* ndp = (const float*)&nd;
            union { ushort4 u; bf16 b[4]; } ob;
            float outv[4];
#pragma unroll
            for (int j = 0; j < 4; ++j) {
                float g = fmaf(v4p[j], sc_s[col0 + j], of_s[col0 + j]);
                outv[j] = ndp[j] + fmaxf(g, 0.f);
                ob.b[j] = __float2bfloat16(outv[j]);
            }
            ((float4*)node)[c] = make_float4(outv[0], outv[1], outv[2], outv[3]);
            *(ushort4*)(node_bf + (size_t)n * HP + col0) = ob.u;
        }
    }
}

// ----------------- classifier + loss (sorted rows; map back via eidx)
__global__ __launch_bounds__(256) void classify_loss(const bf16* __restrict__ edge_bf,
                                                     const float* __restrict__ clsW,
                                                     const float* __restrict__ clsb,
                                                     const int* __restrict__ eidx,
                                                     const int* __restrict__ msrc,
                                                     const int* __restrict__ mdst,
                                                     const float* __restrict__ y,
                                                     float* __restrict__ out) {
    __shared__ float wl[4];
    int lane = threadIdx.x & 63;
    int wid = threadIdx.x >> 6;
    int quad = lane >> 2;
    int ql = lane & 3;
    float w[80];
#pragma unroll
    for (int j = 0; j < 80; ++j) {
        int col = ql * 80 + j;
        w[j] = (col < H) ? clsW[col] : 0.f;
    }
    int g = blockIdx.x * 4 + wid;
    int q = g * 16 + quad;             // sorted row index
    const bf16* row = edge_bf + (size_t)q * HP + ql * 80;
    float acc = 0.f;
#pragma unroll
    for (int v = 0; v < 10; ++v) {
        bf16x8 bv = *(const bf16x8*)(row + v * 8);
#pragma unroll
        for (int j = 0; j < 8; ++j)
            acc += __bfloat162float(((const bf16*)&bv)[j]) * w[v * 8 + j];
    }
    acc += __shfl_xor(acc, 1, 64);
    acc += __shfl_xor(acc, 2, 64);
    float lsum = 0.f;
    if (ql == 0) {
        float z = acc + clsb[0];
        float p = 1.f / (1.f + __expf(-z));
        atomicAdd(&out[(size_t)msrc[q] * N_NODES + mdst[q]], p);
        float yv = y[eidx[q]];
        float pc = fminf(fmaxf(p, 1e-7f), 1.f - 1e-7f);
        lsum = -(yv * __logf(pc) + (1.f - yv) * log1pf(-pc));
    }
#pragma unroll
    for (int off = 32; off > 0; off >>= 1) lsum += __shfl_down(lsum, off, 64);
    if (lane == 0) wl[wid] = lsum;
    __syncthreads();
    if (threadIdx.x == 0) {
        float tt = wl[0] + wl[1] + wl[2] + wl[3];
        atomicAdd(&out[(size_t)N_NODES * N_NODES], tt * (1.f / N_EDGES));
    }
}

// ---------------------------------------------------------------- launcher
extern "C" void kernel_launch(void* const* d_in, const int* in_sizes, int n_in,
                              void* d_out, int out_size, void* d_ws, size_t ws_size,
                              hipStream_t stream) {
    const float* x          = (const float*)d_in[0];
    const float* edge_attr  = (const float*)d_in[1];
    const int*   edge_index = (const int*)d_in[2];
    const float* y          = (const float*)d_in[3];
    const float* node_emb_W = (const float*)d_in[4];
    const float* node_emb_b = (const float*)d_in[5];
    const float* edge_d_W   = (const float*)d_in[6];
    const float* edge_d_b   = (const float*)d_in[7];
    const float* edge_t_W   = (const float*)d_in[8];
    const float* edge_t_b   = (const float*)d_in[9];
    const float* eU_W = (const float*)d_in[10];
    const float* eU_b = (const float*)d_in[11];
    const float* eW_W = (const float*)d_in[12];
    const float* nU_W = (const float*)d_in[14];
    const float* nU_b = (const float*)d_in[15];
    const float* nV_W = (const float*)d_in[16];
    const float* nV_b = (const float*)d_in[17];
    const float* bn_e_g = (const float*)d_in[18];
    const float* bn_e_b = (const float*)d_in[19];
    const float* bn_n_g = (const float*)d_in[20];
    const float* bn_n_b = (const float*)d_in[21];
    const float* cls_W = (const float*)d_in[22];
    const float* cls_b = (const float*)d_in[23];

    const int* src = edge_index;
    const int* dst = edge_index + N_EDGES;

    float* ws     = (float*)d_ws;
    float* node   = ws;                  // NH
    float* nodeU  = node + NH;           // NH
    float* nodeV  = nodeU + NH;          // NH
    float* nodeUn = nodeV + NH;          // NH
    float* aggv   = nodeUn + NH;         // NH
    float* RE2    = aggv + NH;           // 2 x 32*608   <-- zero region start
    float* RN2    = RE2 + 2 * NREP * RSTRIDE;
    float* RS2    = RN2 + 2 * NREP * RSTRIDE;  // 2 x 32*304
    float* invS   = RS2 + 2 * NREP * SSTRIDE;  // 304
    bf16* node_bf = (bf16*)(invS + SSTRIDE);              // 2048*320
    bf16* edge_bf = node_bf + (size_t)NODE_ROWS_PAD * HP; // 32000*320 (sorted order)
    bf16* gate_bf = edge_bf + (size_t)N_EDGES * HP;       // 32000*300 (not zeroed)
    bf16* WtK_all = gate_bf + (size_t)N_EDGES * H;        // 120*102400 (K-packed)
    int* csr_counts = (int*)(WtK_all + (size_t)120 * WMAT);
    int* csr_offs   = csr_counts + 2048;
    int* csr_woff   = csr_offs + 2048;
    int* csr_eidx   = csr_woff + 2048;                     // 32000
    int* csr_msrc   = csr_eidx + N_EDGES;                  // 32000
    int* csr_mdst   = csr_msrc + N_EDGES;                  // 32000

    float* out = (float*)d_out;

    // zero: out, [RE2 | RN2 | RS2 | invS | node_bf | edge_bf], csr_counts
    int zstats = 4 * NREP * RSTRIDE + 2 * NREP * SSTRIDE + SSTRIDE;
    int zlen = zstats + (NODE_ROWS_PAD * HP + N_EDGES * HP) / 2;
    zero_buf<<<(N_NODES * N_NODES + 1 + 255) / 256, 256, 0, stream>>>(out, N_NODES * N_NODES + 1);
    zero_buf<<<(zlen + 255) / 256, 256, 0, stream>>>(RE2, zlen);
    zero_buf<<<8, 256, 0, stream>>>((float*)csr_counts, 2048);

    convert_weights_k<<<12000, 256, 0, stream>>>(eU_W, eW_W, nU_W, nV_W, WtK_all);
    csr_hist<<<(N_EDGES + 255) / 256, 256, 0, stream>>>(dst, csr_counts);
    csr_scan<<<1, 256, 0, stream>>>(csr_counts, csr_offs, csr_woff);
    csr_scatter<<<(N_EDGES + 255) / 256, 256, 0, stream>>>(src, dst, csr_woff,
                                                           csr_eidx, csr_msrc, csr_mdst);
    node_embed<<<(NH + 255) / 256, 256, 0, stream>>>(x, node_emb_W, node_emb_b, node, node_bf);
    edge_embed<<<NEB, 256, 0, stream>>>(edge_attr, csr_eidx, edge_d_W, edge_d_b,
                                        edge_t_W, edge_t_b, edge_bf, RS2);

    for (int l = 0; l < NLAYERS; ++l) {
        float* REc = RE2 + (size_t)(l & 1) * NREP * RSTRIDE;
        float* REo = RE2 + (size_t)((l + 1) & 1) * NREP * RSTRIDE;
        float* RNc = RN2 + (size_t)(l & 1) * NREP * RSTRIDE;
        float* RNo = RN2 + (size_t)((l + 1) & 1) * NREP * RSTRIDE;
        float* RScur = RS2 + (size_t)(l & 1) * NREP * SSTRIDE;
        float* RSnxt = RS2 + (size_t)((l + 1) & 1) * NREP * SSTRIDE;
        const bf16* WtK_e = WtK_all + (size_t)(30 + l) * WMAT;

        gemm_node<<<1505, 64, 0, stream>>>(node_bf, WtK_all, eU_b, nV_b, nU_b, l,
                                           nodeU, nodeV, nodeUn, RScur, RSnxt, invS);
        fused_mid<<<2000, 256, 0, stream>>>(edge_bf, WtK_e, nodeU, csr_msrc, csr_mdst,
                                            gate_bf, REc,
                                            nodeV, nodeUn, csr_offs,
                                            invS, RNc, aggv);
        fused_final<<<NEB + NUB, 256, 0, stream>>>(edge_bf, gate_bf,
                                                   REc, REo, RNc, RNo, RSnxt,
                                                   bn_e_g + l * H, bn_e_b + l * H,
                                                   bn_n_g + l * H, bn_n_b + l * H,
                                                   node, node_bf, aggv);
    }

    classify_loss<<<500, 256, 0, stream>>>(edge_bf, cls_W, cls_b,
                                           csr_eidx, csr_msrc, csr_mdst, y, out);
}

// Round 17
// 2145.423 us; speedup vs baseline: 1.5099x; 1.1037x over previous
//
#include <hip/hip_runtime.h>
#include <hip/hip_bf16.h>
#include <math.h>

#define N_NODES 2000
#define N_EDGES 32000
#define H 300
#define CH 75             // H/4 float4 chunks per row
#define HP 320            // padded H for MFMA K/N
#define NLAYERS 30
#define NH (N_NODES * H)     // 600000
#define NODE_ROWS_PAD 2048
#define WMAT (HP * HP)       // 102400 per K-packed matrix
#define NREP 32              // stat replicas
#define RSTRIDE 608          // replica row stride (sum | sumsq at +304)
#define SSTRIDE 304
#define NEB 500              // edge blocks (32000/64)
#define NUB 147              // node_update blocks (1024 chunks each)

typedef short bf16x8 __attribute__((ext_vector_type(8)));
typedef float f32x4 __attribute__((ext_vector_type(4)));
typedef __hip_bfloat16 bf16;

__device__ __forceinline__ float sigm(float x) { return 1.f / (1.f + __expf(-x)); }

// ---------------------------------------------------------------- utilities
__global__ __launch_bounds__(256) void zero_buf(float* __restrict__ p, int n) {
    int i = blockIdx.x * blockDim.x + threadIdx.x;
    if (i < n) p[i] = 0.f;
}

// ---- weights -> bf16, K-packed: WtK[m][ct4][kc][c][j] = W_m[k=kc*8+j][n=ct4*80+c]
__global__ __launch_bounds__(256) void convert_weights_k(const float* __restrict__ eU,
                                                         const float* __restrict__ eW,
                                                         const float* __restrict__ nU,
                                                         const float* __restrict__ nV,
                                                         bf16* __restrict__ WtK) {
    __shared__ float tile[32][33];
    int b = blockIdx.x;                 // 120 mats x 100 tiles
    int m = b / 100;
    int rem = b % 100;
    int kt = rem / 10, nt = rem % 10;
    int k0 = kt * 32, n0 = nt * 32;
    int grp = m / NLAYERS, l = m % NLAYERS;
    const float* S = (grp == 0) ? eU : (grp == 1) ? eW : (grp == 2) ? nU : nV;
    const float* Sl = S + (size_t)l * H * H;
    int t = threadIdx.x;
    int tn = t & 31, tk = t >> 5;
#pragma unroll
    for (int p = 0; p < 4; ++p) {
        int k = tk + p * 8;
        int gk = k0 + k, gn = n0 + tn;
        tile[k][tn] = (gk < H && gn < H) ? Sl[(size_t)gk * H + gn] : 0.f;
    }
    __syncthreads();
    bf16* D = WtK + (size_t)m * WMAT;
    int nn = t >> 3, j8 = t & 7;
    int n = n0 + nn;
    int ct4 = n / 80, c = n % 80;
#pragma unroll
    for (int p = 0; p < 4; ++p) {
        int kc = (k0 >> 3) + p;
        D[(size_t)ct4 * 25600 + (size_t)kc * 640 + c * 8 + j8] =
            __float2bfloat16(tile[p * 8 + j8][nn]);
    }
}

// ------------------------------------------------------------- CSR by dst
__global__ __launch_bounds__(256) void csr_hist(const int* __restrict__ dst,
                                                int* __restrict__ counts) {
    int i = blockIdx.x * 256 + threadIdx.x;
    if (i < N_EDGES) atomicAdd(&counts[dst[i]], 1);
}

__global__ __launch_bounds__(256) void csr_scan(const int* __restrict__ counts,
                                                int* __restrict__ offs,
                                                int* __restrict__ woff) {
    __shared__ int part[256];
    int t = threadIdx.x;
    int base = t * 8;
    int local[8];
    int s = 0;
#pragma unroll
    for (int j = 0; j < 8; ++j) {
        int c = (base + j < N_NODES) ? counts[base + j] : 0;
        local[j] = s;
        s += c;
    }
    part[t] = s;
    __syncthreads();
    for (int off = 1; off < 256; off <<= 1) {
        int v = (t >= off) ? part[t - off] : 0;
        __syncthreads();
        part[t] += v;
        __syncthreads();
    }
    int pre = (t == 0) ? 0 : part[t - 1];
#pragma unroll
    for (int j = 0; j < 8; ++j) {
        int idx = base + j;
        if (idx < N_NODES) { int v = pre + local[j]; offs[idx] = v; woff[idx] = v; }
    }
    if (t == 255) offs[N_NODES] = part[255];
}

// sorted position p <- original edge i; store perm and permuted src/dst
__global__ __launch_bounds__(256) void csr_scatter(const int* __restrict__ src,
                                                   const int* __restrict__ dst,
                                                   int* __restrict__ woff,
                                                   int* __restrict__ eidx,
                                                   int* __restrict__ msrc,
                                                   int* __restrict__ mdst) {
    int i = blockIdx.x * 256 + threadIdx.x;
    if (i < N_EDGES) {
        int d = dst[i];
        int p = atomicAdd(&woff[d], 1);
        eidx[p] = i;
        msrc[p] = src[i];
        mdst[p] = d;
    }
}

// ---------------------------------------------------------------- embeddings
__global__ __launch_bounds__(256) void node_embed(const float* __restrict__ x,
                                                  const float* __restrict__ W,
                                                  const float* __restrict__ b,
                                                  float* __restrict__ node,
                                                  bf16* __restrict__ node_bf) {
    int i = blockIdx.x * blockDim.x + threadIdx.x;
    if (i >= NH) return;
    int n = i / H, h = i % H;
    float acc = b[h];
#pragma unroll
    for (int k = 0; k < 4; ++k) acc += x[n * 4 + k] * W[k * H + h];
    node[i] = acc;
    node_bf[(size_t)n * HP + h] = __float2bfloat16(acc);
}

// edge embedding into SORTED order (row q holds original edge eidx[q])
__global__ __launch_bounds__(256) void edge_embed(const float* __restrict__ ea,
                                                  const int* __restrict__ eidx,
                                                  const float* __restrict__ dW,
                                                  const float* __restrict__ db,
                                                  const float* __restrict__ tW,
                                                  const float* __restrict__ tb,
                                                  bf16* __restrict__ edge_bf,
                                                  float* __restrict__ RS0) {
    __shared__ float s_s[SSTRIDE];
    int t = threadIdx.x;
    for (int i = t; i < SSTRIDE; i += 256) s_s[i] = 0.f;
    __syncthreads();
    int hc = t % 80, rgrp = t / 80;
    int col0 = hc * 4;
    float ss[4] = {0.f, 0.f, 0.f, 0.f};
    if (hc < CH && rgrp < 3) {
        float wv[4], bv[4];
#pragma unroll
        for (int j = 0; j < 4; ++j) {
            int col = col0 + j;
            wv[j] = (col < 150) ? dW[col] : tW[col - 150];
            bv[j] = (col < 150) ? db[col] : tb[col - 150];
        }
        int q0 = blockIdx.x * 64;
        for (int r = rgrp; r < 64; r += 3) {
            int q = q0 + r;
            int e = eidx[q];
            float d = ea[2 * e], tt = ea[2 * e + 1];
            union { ushort4 u; bf16 b[4]; } ob;
#pragma unroll
            for (int j = 0; j < 4; ++j) {
                int col = col0 + j;
                float v = ((col < 150) ? d : tt) * wv[j] + bv[j];
                ob.b[j] = __float2bfloat16(v);
                ss[j] += sigm(__bfloat162float(ob.b[j]));
            }
            *(ushort4*)(edge_bf + (size_t)q * HP + col0) = ob.u;
        }
#pragma unroll
        for (int j = 0; j < 4; ++j) atomicAdd(&s_s[col0 + j], ss[j]);
    }
    __syncthreads();
    float* rs = RS0 + (size_t)(blockIdx.x & (NREP - 1)) * SSTRIDE;
    for (int i = t; i < H; i += 256) atomicAdd(&rs[i], s_s[i]);
}

// ---- K1: node GEMMs (1500 one-wave blocks, K-packed B) + 5 housekeeping blocks
__global__ __launch_bounds__(64) void gemm_node(const bf16* __restrict__ node_bf,
                                                const bf16* __restrict__ WtK_all,
                                                const float* __restrict__ eU_b,
                                                const float* __restrict__ nV_b,
                                                const float* __restrict__ nU_b,
                                                int layer,
                                                float* __restrict__ nodeU,
                                                float* __restrict__ nodeV,
                                                float* __restrict__ nodeUn,
                                                const float* __restrict__ RScur,
                                                float* __restrict__ RSnxt,
                                                float* __restrict__ invS) {
    int bx = blockIdx.x;
    int lane = threadIdx.x;
    if (bx >= 1500) {
        int idx = bx - 1500;               // 0..4
        int c = idx * 64 + lane;           // 0..319
        if (c < H) {
            float ssr = 0.f;
#pragma unroll 8
            for (int r = 0; r < NREP; ++r) ssr += RScur[r * SSTRIDE + c];
            invS[c] = 1.f / (ssr + 1e-20f);
        }
        for (int i = idx * 64 + lane; i < NREP * SSTRIDE; i += 320) RSnxt[i] = 0.f;
        return;
    }
    int mat = bx / 500;
    int rem = bx % 500;
    int rt0 = rem >> 2, ct4 = rem & 3;
    int m; const float* bias; float* out;
    if (mat == 0)      { m = layer;      bias = eU_b + layer * H; out = nodeU; }
    else if (mat == 1) { m = 90 + layer; bias = nV_b + layer * H; out = nodeV; }
    else               { m = 60 + layer; bias = nU_b + layer * H; out = nodeUn; }
    const bf16* Bw = WtK_all + (size_t)m * WMAT + (size_t)ct4 * 25600;
    int row0 = rt0 * 16, c0 = ct4 * 80;
    int rlo = lane & 15, khi = lane >> 4;
    f32x4 acc[5];
#pragma unroll
    for (int ct = 0; ct < 5; ++ct) acc[ct] = (f32x4)0.f;
#pragma unroll 2
    for (int ks = 0; ks < 10; ++ks) {
        int kk = ks * 32 + khi * 8;
        int kcb = (ks * 4 + khi) * 80;
        bf16x8 a, b[5];
        a = *(const bf16x8*)(node_bf + (size_t)(row0 + rlo) * HP + kk);
#pragma unroll
        for (int ct = 0; ct < 5; ++ct)
            b[ct] = *(const bf16x8*)(Bw + (size_t)(kcb + ct * 16 + rlo) * 8);
#pragma unroll
        for (int ct = 0; ct < 5; ++ct)
            acc[ct] = __builtin_amdgcn_mfma_f32_16x16x32_bf16(a, b[ct], acc[ct], 0, 0, 0);
    }
    int rhi = lane >> 4;
#pragma unroll
    for (int ct = 0; ct < 5; ++ct) {
        int col = c0 + ct * 16 + rlo;
        if (col >= H) continue;
        float bv = bias[col];
#pragma unroll
        for (int j = 0; j < 4; ++j) {
            int r = row0 + rhi * 4 + j;
            out[(size_t)r * H + col] = acc[ct][j] + bv;
        }
    }
}

// ---- K2 fused: edge gate GEMM (bx<1000) || CSR gather (bx>=1000, 4x unrolled)
__global__ __launch_bounds__(256) void fused_mid(const bf16* __restrict__ edge_bf,
                                                 const bf16* __restrict__ WtK_l,
                                                 const float* __restrict__ nodeU,
                                                 const int* __restrict__ msrc,
                                                 const int* __restrict__ mdst,
                                                 bf16* __restrict__ gate_bf,
                                                 float* __restrict__ REc,
                                                 const float* __restrict__ nodeV,
                                                 const float* __restrict__ nodeUn,
                                                 const int* __restrict__ offs,
                                                 const float* __restrict__ invS,
                                                 float* __restrict__ RNc,
                                                 float* __restrict__ aggv) {
    __shared__ bf16 smA[32 * 320];         // 20 KB
    int tid = threadIdx.x;
    int bx = blockIdx.x;
    if (bx < 1000) {
        int wave = tid >> 6, lane = tid & 63;
        int row0 = bx * 32;
        int c0 = wave * 80;
        int rlo = lane & 15, khi = lane >> 4, rhi = lane >> 4;

        // hoist permuted src/dst loads (coalesced)
        int se_[8], de_[8];
#pragma unroll
        for (int rt = 0; rt < 2; ++rt)
#pragma unroll
            for (int j = 0; j < 4; ++j) {
                int r = row0 + rt * 16 + rhi * 4 + j;
                se_[rt * 4 + j] = msrc[r];
                de_[rt * 4 + j] = mdst[r];
            }

        // stage A: fully coalesced 20480B contiguous span, XOR-swizzled
        const uint4* Ag = (const uint4*)(edge_bf + (size_t)row0 * HP);
#pragma unroll
        for (int it = 0; it < 5; ++it) {
            int cid = it * 256 + tid;      // 0..1279
            int row = cid / 40, ch = cid % 40;
            uint4 v = Ag[cid];
            *(uint4*)(smA + row * 320 + ((ch ^ (row & 7)) << 3)) = v;
        }
        __syncthreads();

        const bf16* Bw = WtK_l + (size_t)wave * 25600;
        f32x4 acc[2][5];
#pragma unroll
        for (int rt = 0; rt < 2; ++rt)
#pragma unroll
            for (int ct = 0; ct < 5; ++ct) acc[rt][ct] = (f32x4)0.f;
#pragma unroll 2
        for (int ks = 0; ks < 10; ++ks) {
            int c = ks * 4 + khi;
            int kcb = (ks * 4 + khi) * 80;
            bf16x8 a[2], b[5];
#pragma unroll
            for (int rt = 0; rt < 2; ++rt) {
                int row = rt * 16 + rlo;
                a[rt] = *(const bf16x8*)(smA + row * 320 + ((c ^ (row & 7)) << 3));
            }
#pragma unroll
            for (int ct = 0; ct < 5; ++ct)
                b[ct] = *(const bf16x8*)(Bw + (size_t)(kcb + ct * 16 + rlo) * 8);
#pragma unroll
            for (int rt = 0; rt < 2; ++rt)
#pragma unroll
                for (int ct = 0; ct < 5; ++ct)
                    acc[rt][ct] = __builtin_amdgcn_mfma_f32_16x16x32_bf16(a[rt], b[ct], acc[rt][ct], 0, 0, 0);
        }
        float csum[5], csq[5];
#pragma unroll
        for (int ct = 0; ct < 5; ++ct) { csum[ct] = 0.f; csq[ct] = 0.f; }
#pragma unroll
        for (int rt = 0; rt < 2; ++rt)
#pragma unroll
            for (int j = 0; j < 4; ++j) {
                int r = row0 + rt * 16 + rhi * 4 + j;
                int se = se_[rt * 4 + j], de = de_[rt * 4 + j];
#pragma unroll
                for (int ct = 0; ct < 5; ++ct) {
                    int col = c0 + ct * 16 + rlo;
                    if (col < H) {
                        float g = acc[rt][ct][j] + nodeU[(size_t)se * H + col] + nodeU[(size_t)de * H + col];
                        gate_bf[(size_t)r * H + col] = __float2bfloat16(g);
                        csum[ct] += g;
                        csq[ct] += g * g;
                    }
                }
            }
#pragma unroll
        for (int ct = 0; ct < 5; ++ct) {
            csum[ct] += __shfl_xor(csum[ct], 16, 64);
            csum[ct] += __shfl_xor(csum[ct], 32, 64);
            csq[ct]  += __shfl_xor(csq[ct], 16, 64);
            csq[ct]  += __shfl_xor(csq[ct], 32, 64);
        }
        if (khi == 0) {
            float* re = REc + (size_t)(bx & (NREP - 1)) * RSTRIDE;
#pragma unroll
            for (int ct = 0; ct < 5; ++ct) {
                int col = c0 + ct * 16 + rlo;
                if (col < H) {
                    atomicAdd(&re[col], csum[ct]);
                    atomicAdd(&re[SSTRIDE + col], csq[ct]);
                }
            }
        }
    } else {
        // ------- CSR gather: 2 nodes/block; contiguous rows; 4x unrolled ILP
        int nb = bx - 1000;                // 0..999
        int h0 = tid;
        bool has1 = (tid < H - 256);
        int h1 = 256 + tid;
        float inv0 = invS[h0];
        float inv1 = has1 ? invS[h1] : 0.f;
        float st10 = 0.f, st20 = 0.f, st11 = 0.f, st21 = 0.f;
        int n0 = nb * 2;
#pragma unroll
        for (int k = 0; k < 2; ++k) {
            int n = n0 + k;
            int beg = offs[n], end = offs[n + 1];
            float a0 = 0.f, a1 = 0.f, a2 = 0.f, a3 = 0.f;
            float b0 = 0.f, b1 = 0.f, b2 = 0.f, b3 = 0.f;
            int i = beg;
            for (; i + 4 <= end; i += 4) {
                int s0 = msrc[i], s1 = msrc[i + 1], s2 = msrc[i + 2], s3 = msrc[i + 3];
                const bf16* e0 = edge_bf + (size_t)(i + 0) * HP;
                const bf16* e1 = edge_bf + (size_t)(i + 1) * HP;
                const bf16* e2 = edge_bf + (size_t)(i + 2) * HP;
                const bf16* e3 = edge_bf + (size_t)(i + 3) * HP;
                const float* v0 = nodeV + (size_t)s0 * H;
                const float* v1 = nodeV + (size_t)s1 * H;
                const float* v2 = nodeV + (size_t)s2 * H;
                const float* v3 = nodeV + (size_t)s3 * H;
                float x0 = __bfloat162float(e0[h0]);
                float x1 = __bfloat162float(e1[h0]);
                float x2 = __bfloat162float(e2[h0]);
                float x3 = __bfloat162float(e3[h0]);
                float w0 = v0[h0], w1 = v1[h0], w2 = v2[h0], w3 = v3[h0];
                a0 += sigm(x0) * w0;
                a1 += sigm(x1) * w1;
                a2 += sigm(x2) * w2;
                a3 += sigm(x3) * w3;
                if (has1) {
                    float y0 = __bfloat162float(e0[h1]);
                    float y1 = __bfloat162float(e1[h1]);
                    float y2 = __bfloat162float(e2[h1]);
                    float y3 = __bfloat162float(e3[h1]);
                    b0 += sigm(y0) * v0[h1];
                    b1 += sigm(y1) * v1[h1];
                    b2 += sigm(y2) * v2[h1];
                    b3 += sigm(y3) * v3[h1];
                }
            }
            for (; i < end; ++i) {
                int s = msrc[i];
                const bf16* er = edge_bf + (size_t)i * HP;
                const float* vr = nodeV + (size_t)s * H;
                a0 += sigm(__bfloat162float(er[h0])) * vr[h0];
                if (has1) b0 += sigm(__bfloat162float(er[h1])) * vr[h1];
            }
            float a = (a0 + a1) + (a2 + a3);
            size_t nbase = (size_t)n * H;
            float v0s = nodeUn[nbase + h0] + a * inv0;
            aggv[nbase + h0] = v0s;
            st10 += v0s; st20 += v0s * v0s;
            if (has1) {
                float bsum = (b0 + b1) + (b2 + b3);
                float v1s = nodeUn[nbase + h1] + bsum * inv1;
                aggv[nbase + h1] = v1s;
                st11 += v1s; st21 += v1s * v1s;
            }
        }
        float* rn = RNc + (size_t)(nb & (NREP - 1)) * RSTRIDE;
        atomicAdd(&rn[h0], st10);
        atomicAdd(&rn[SSTRIDE + h0], st20);
        if (has1) {
            atomicAdd(&rn[h1], st11);
            atomicAdd(&rn[SSTRIDE + h1], st21);
        }
    }
}

// ------------- K3: edge_finalize (bx<NEB) || node_update (bx>=NEB), bf16 residual
__global__ __launch_bounds__(256) void fused_final(bf16* __restrict__ edge_bf,
                                                   const bf16* __restrict__ gate_bf,
                                                   const float* __restrict__ REc,
                                                   float* __restrict__ REo,
                                                   const float* __restrict__ RNc,
                                                   float* __restrict__ RNo,
                                                   float* __restrict__ RSnext,
                                                   const float* __restrict__ eg,
                                                   const float* __restrict__ ebt,
                                                   const float* __restrict__ ng,
                                                   const float* __restrict__ nbt,
                                                   float* __restrict__ node,
                                                   bf16* __restrict__ node_bf,
                                                   const float* __restrict__ aggv) {
    __shared__ float sc_s[SSTRIDE], of_s[SSTRIDE], s_s[SSTRIDE];
    int bx = blockIdx.x, t = threadIdx.x;
    if (bx < NEB) {
        const float invE = 1.f / N_EDGES;
        for (int i = t; i < SSTRIDE; i += 256) {
            s_s[i] = 0.f;
            if (i < H) {
                float gs = 0.f, gq = 0.f;
#pragma unroll 8
                for (int r = 0; r < NREP; ++r) {
                    gs += REc[r * RSTRIDE + i];
                    gq += REc[r * RSTRIDE + SSTRIDE + i];
                }
                float mean = gs * invE;
                float var = fmaxf(gq * invE - mean * mean, 0.f);
                float rstd = rsqrtf(var + 1e-5f);
                float sc = rstd * eg[i];
                sc_s[i] = sc;
                of_s[i] = ebt[i] - mean * sc;
            }
        }
        __syncthreads();
        int hc = t % 80, rgrp = t / 80;
        bool act = (hc < CH) && (rgrp < 3);
        float ss[4] = {0.f, 0.f, 0.f, 0.f};
        int col0 = hc * 4;
        if (act) {
            float sc[4], of[4];
#pragma unroll
            for (int j = 0; j < 4; ++j) { sc[j] = sc_s[col0 + j]; of[j] = of_s[col0 + j]; }
            int e0 = bx * 64;
            for (int r = rgrp; r < 64; r += 3) {
                int e = e0 + r;
                union { ushort4 u; bf16 b[4]; } eb, gv, ob;
                eb.u = *(const ushort4*)(edge_bf + (size_t)e * HP + col0);
                gv.u = *(const ushort4*)(gate_bf + (size_t)e * H + col0);
#pragma unroll
                for (int j = 0; j < 4; ++j) {
                    float g = __bfloat162float(gv.b[j]);
                    float val = fmaxf(fmaf(g, sc[j], of[j]), 0.f);
                    float nv = __bfloat162float(eb.b[j]) + val;
                    ob.b[j] = __float2bfloat16(nv);
                    ss[j] += sigm(__bfloat162float(ob.b[j]));
                }
                *(ushort4*)(edge_bf + (size_t)e * HP + col0) = ob.u;
            }
#pragma unroll
            for (int j = 0; j < 4; ++j) atomicAdd(&s_s[col0 + j], ss[j]);
        }
        __syncthreads();
        float* rs = RSnext + (size_t)(bx & (NREP - 1)) * SSTRIDE;
        for (int i = t; i < H; i += 256) atomicAdd(&rs[i], s_s[i]);
    } else {
        int idx = bx - NEB;                // 0..NUB-1
        if (idx < NREP) {
            for (int i = t; i < RSTRIDE; i += 256) {
                REo[(size_t)idx * RSTRIDE + i] = 0.f;
                RNo[(size_t)idx * RSTRIDE + i] = 0.f;
            }
        }
        const float invN = 1.f / N_NODES;
        for (int i = t; i < H; i += 256) {
            float ns = 0.f, nq = 0.f;
#pragma unroll 8
            for (int r = 0; r < NREP; ++r) {
                ns += RNc[r * RSTRIDE + i];
                nq += RNc[r * RSTRIDE + SSTRIDE + i];
            }
            float mean = ns * invN;
            float var = fmaxf(nq * invN - mean * mean, 0.f);
            float rstd = rsqrtf(var + 1e-5f);
            float sc = rstd * ng[i];
            sc_s[i] = sc;
            of_s[i] = nbt[i] - mean * sc;
        }
        __syncthreads();
#pragma unroll
        for (int it = 0; it < 4; ++it) {
            int c = idx * 1024 + it * 256 + t;
            if (c >= NH / 4) break;
            int n = c / CH, hc = c % CH, col0 = hc * 4;
            float4 v4 = ((const float4*)aggv)[c];
            float4 nd = ((const float4*)node)[c];
            const float* v4p = (const float*)&v4;
            const float* ndp = (const float*)&nd;
            union { ushort4 u; bf16 b[4]; } ob;
            float outv[4];
#pragma unroll
            for (int j = 0; j < 4; ++j) {
                float g = fmaf(v4p[j], sc_s[col0 + j], of_s[col0 + j]);
                outv[j] = ndp[j] + fmaxf(g, 0.f);
                ob.b[j] = __float2bfloat16(outv[j]);
            }
            ((float4*)node)[c] = make_float4(outv[0], outv[1], outv[2], outv[3]);
            *(ushort4*)(node_bf + (size_t)n * HP + col0) = ob.u;
        }
    }
}

// ----------------- classifier + loss (sorted rows; map back via eidx)
__global__ __launch_bounds__(256) void classify_loss(const bf16* __restrict__ edge_bf,
                                                     const float* __restrict__ clsW,
                                                     const float* __restrict__ clsb,
                                                     const int* __restrict__ eidx,
                                                     const int* __restrict__ msrc,
                                                     const int* __restrict__ mdst,
                                                     const float* __restrict__ y,
                                                     float* __restrict__ out) {
    __shared__ float wl[4];
    int lane = threadIdx.x & 63;
    int wid = threadIdx.x >> 6;
    int quad = lane >> 2;
    int ql = lane & 3;
    float w[80];
#pragma unroll
    for (int j = 0; j < 80; ++j) {
        int col = ql * 80 + j;
        w[j] = (col < H) ? clsW[col] : 0.f;
    }
    int g = blockIdx.x * 4 + wid;
    int q = g * 16 + quad;             // sorted row index
    const bf16* row = edge_bf + (size_t)q * HP + ql * 80;
    float acc = 0.f;
#pragma unroll
    for (int v = 0; v < 10; ++v) {
        bf16x8 bv = *(const bf16x8*)(row + v * 8);
#pragma unroll
        for (int j = 0; j < 8; ++j)
            acc += __bfloat162float(((const bf16*)&bv)[j]) * w[v * 8 + j];
    }
    acc += __shfl_xor(acc, 1, 64);
    acc += __shfl_xor(acc, 2, 64);
    float lsum = 0.f;
    if (ql == 0) {
        float z = acc + clsb[0];
        float p = 1.f / (1.f + __expf(-z));
        atomicAdd(&out[(size_t)msrc[q] * N_NODES + mdst[q]], p);
        float yv = y[eidx[q]];
        float pc = fminf(fmaxf(p, 1e-7f), 1.f - 1e-7f);
        lsum = -(yv * __logf(pc) + (1.f - yv) * log1pf(-pc));
    }
#pragma unroll
    for (int off = 32; off > 0; off >>= 1) lsum += __shfl_down(lsum, off, 64);
    if (lane == 0) wl[wid] = lsum;
    __syncthreads();
    if (threadIdx.x == 0) {
        float tt = wl[0] + wl[1] + wl[2] + wl[3];
        atomicAdd(&out[(size_t)N_NODES * N_NODES], tt * (1.f / N_EDGES));
    }
}

// ---------------------------------------------------------------- launcher
extern "C" void kernel_launch(void* const* d_in, const int* in_sizes, int n_in,
                              void* d_out, int out_size, void* d_ws, size_t ws_size,
                              hipStream_t stream) {
    const float* x          = (const float*)d_in[0];
    const float* edge_attr  = (const float*)d_in[1];
    const int*   edge_index = (const int*)d_in[2];
    const float* y          = (const float*)d_in[3];
    const float* node_emb_W = (const float*)d_in[4];
    const float* node_emb_b = (const float*)d_in[5];
    const float* edge_d_W   = (const float*)d_in[6];
    const float* edge_d_b   = (const float*)d_in[7];
    const float* edge_t_W   = (const float*)d_in[8];
    const float* edge_t_b   = (const float*)d_in[9];
    const float* eU_W = (const float*)d_in[10];
    const float* eU_b = (const float*)d_in[11];
    const float* eW_W = (const float*)d_in[12];
    const float* nU_W = (const float*)d_in[14];
    const float* nU_b = (const float*)d_in[15];
    const float* nV_W = (const float*)d_in[16];
    const float* nV_b = (const float*)d_in[17];
    const float* bn_e_g = (const float*)d_in[18];
    const float* bn_e_b = (const float*)d_in[19];
    const float* bn_n_g = (const float*)d_in[20];
    const float* bn_n_b = (const float*)d_in[21];
    const float* cls_W = (const float*)d_in[22];
    const float* cls_b = (const float*)d_in[23];

    const int* src = edge_index;
    const int* dst = edge_index + N_EDGES;

    float* ws     = (float*)d_ws;
    float* node   = ws;                  // NH
    float* nodeU  = node + NH;           // NH
    float* nodeV  = nodeU + NH;          // NH
    float* nodeUn = nodeV + NH;          // NH
    float* aggv   = nodeUn + NH;         // NH
    float* RE2    = aggv + NH;           // 2 x 32*608   <-- zero region start
    float* RN2    = RE2 + 2 * NREP * RSTRIDE;
    float* RS2    = RN2 + 2 * NREP * RSTRIDE;  // 2 x 32*304
    float* invS   = RS2 + 2 * NREP * SSTRIDE;  // 304
    bf16* node_bf = (bf16*)(invS + SSTRIDE);              // 2048*320
    bf16* edge_bf = node_bf + (size_t)NODE_ROWS_PAD * HP; // 32000*320 (sorted order)
    bf16* gate_bf = edge_bf + (size_t)N_EDGES * HP;       // 32000*300 (not zeroed)
    bf16* WtK_all = gate_bf + (size_t)N_EDGES * H;        // 120*102400 (K-packed)
    int* csr_counts = (int*)(WtK_all + (size_t)120 * WMAT);
    int* csr_offs   = csr_counts + 2048;
    int* csr_woff   = csr_offs + 2048;
    int* csr_eidx   = csr_woff + 2048;                     // 32000
    int* csr_msrc   = csr_eidx + N_EDGES;                  // 32000
    int* csr_mdst   = csr_msrc + N_EDGES;                  // 32000

    float* out = (float*)d_out;

    // zero: out, [RE2 | RN2 | RS2 | invS | node_bf | edge_bf], csr_counts
    int zstats = 4 * NREP * RSTRIDE + 2 * NREP * SSTRIDE + SSTRIDE;
    int zlen = zstats + (NODE_ROWS_PAD * HP + N_EDGES * HP) / 2;
    zero_buf<<<(N_NODES * N_NODES + 1 + 255) / 256, 256, 0, stream>>>(out, N_NODES * N_NODES + 1);
    zero_buf<<<(zlen + 255) / 256, 256, 0, stream>>>(RE2, zlen);
    zero_buf<<<8, 256, 0, stream>>>((float*)csr_counts, 2048);

    convert_weights_k<<<12000, 256, 0, stream>>>(eU_W, eW_W, nU_W, nV_W, WtK_all);
    csr_hist<<<(N_EDGES + 255) / 256, 256, 0, stream>>>(dst, csr_counts);
    csr_scan<<<1, 256, 0, stream>>>(csr_counts, csr_offs, csr_woff);
    csr_scatter<<<(N_EDGES + 255) / 256, 256, 0, stream>>>(src, dst, csr_woff,
                                                           csr_eidx, csr_msrc, csr_mdst);
    node_embed<<<(NH + 255) / 256, 256, 0, stream>>>(x, node_emb_W, node_emb_b, node, node_bf);
    edge_embed<<<NEB, 256, 0, stream>>>(edge_attr, csr_eidx, edge_d_W, edge_d_b,
                                        edge_t_W, edge_t_b, edge_bf, RS2);

    for (int l = 0; l < NLAYERS; ++l) {
        float* REc = RE2 + (size_t)(l & 1) * NREP * RSTRIDE;
        float* REo = RE2 + (size_t)((l + 1) & 1) * NREP * RSTRIDE;
        float* RNc = RN2 + (size_t)(l & 1) * NREP * RSTRIDE;
        float* RNo = RN2 + (size_t)((l + 1) & 1) * NREP * RSTRIDE;
        float* RScur = RS2 + (size_t)(l & 1) * NREP * SSTRIDE;
        float* RSnxt = RS2 + (size_t)((l + 1) & 1) * NREP * SSTRIDE;
        const bf16* WtK_e = WtK_all + (size_t)(30 + l) * WMAT;

        gemm_node<<<1505, 64, 0, stream>>>(node_bf, WtK_all, eU_b, nV_b, nU_b, l,
                                           nodeU, nodeV, nodeUn, RScur, RSnxt, invS);
        fused_mid<<<2000, 256, 0, stream>>>(edge_bf, WtK_e, nodeU, csr_msrc, csr_mdst,
                                            gate_bf, REc,
                                            nodeV, nodeUn, csr_offs,
                                            invS, RNc, aggv);
        fused_final<<<NEB + NUB, 256, 0, stream>>>(edge_bf, gate_bf,
                                                   REc, REo, RNc, RNo, RSnxt,
                                                   bn_e_g + l * H, bn_e_b + l * H,
                                                   bn_n_g + l * H, bn_n_b + l * H,
                                                   node, node_bf, aggv);
    }

    classify_loss<<<500, 256, 0, stream>>>(edge_bf, cls_W, cls_b,
                                           csr_eidx, csr_msrc, csr_mdst, y, out);
}